// Round 1
// baseline (355.048 us; speedup 1.0000x reference)
//
#include <hip/hip_runtime.h>
#include <hip/hip_bf16.h>

// Problem constants: B=2, C=512, H=W=64 -> N=4096, G=32 (16 ch/group), EPS=1e-6.

typedef float f32x4 __attribute__((ext_vector_type(4)));
typedef __bf16 bf16x8 __attribute__((ext_vector_type(8)));

// ---------------- GroupNorm statistics: one block per (b,g) ----------------
__global__ __launch_bounds__(256) void gn_stats_k(const float* __restrict__ x,
                                                  float* __restrict__ stats) {
  int bg = blockIdx.x;  // 0..63  (b*32+g); group = 16 contiguous channels
  const float4* p = (const float4*)(x + (size_t)bg * 65536);
  float s = 0.f, s2 = 0.f;
  for (int i = threadIdx.x; i < 16384; i += 256) {
    float4 v = p[i];
    s  += v.x + v.y + v.z + v.w;
    s2 += v.x * v.x + v.y * v.y + v.z * v.z + v.w * v.w;
  }
#pragma unroll
  for (int off = 32; off > 0; off >>= 1) {
    s  += __shfl_xor(s, off);
    s2 += __shfl_xor(s2, off);
  }
  __shared__ float rs[4], rs2[4];
  int wid = threadIdx.x >> 6, lane = threadIdx.x & 63;
  if (lane == 0) { rs[wid] = s; rs2[wid] = s2; }
  __syncthreads();
  if (threadIdx.x == 0) {
    float S  = rs[0] + rs[1] + rs[2] + rs[3];
    float S2 = rs2[0] + rs2[1] + rs2[2] + rs2[3];
    float mean = S * (1.f / 65536.f);
    float var  = S2 * (1.f / 65536.f) - mean * mean;
    stats[bg * 2]     = mean;
    stats[bg * 2 + 1] = rsqrtf(var + 1e-6f);
  }
}

// ------- GroupNorm apply + transpose [b][c][n] -> hf bf16 [b][n][c] --------
__global__ __launch_bounds__(256) void gn_apply_k(const float* __restrict__ x,
                                                  const float* __restrict__ stats,
                                                  const float* __restrict__ gw,
                                                  const float* __restrict__ gb,
                                                  __hip_bfloat16* __restrict__ hf) {
  int c0 = blockIdx.x * 64, n0 = blockIdx.y * 64, b = blockIdx.z;
  __shared__ float tile[64][65];
  int tx = threadIdx.x & 63, ty = threadIdx.x >> 6;
  const float* xb = x + ((size_t)(b * 512 + c0)) * 4096 + n0;
#pragma unroll
  for (int i = 0; i < 64; i += 4) {
    int cl = i + ty;
    int c  = c0 + cl;
    float mean = stats[(b * 32 + (c >> 4)) * 2];
    float rstd = stats[(b * 32 + (c >> 4)) * 2 + 1];
    float v = xb[(size_t)cl * 4096 + tx];
    tile[cl][tx] = (v - mean) * rstd * gw[c] + gb[c];
  }
  __syncthreads();
  __hip_bfloat16* o = hf + ((size_t)(b * 4096 + n0)) * 512 + c0;
#pragma unroll
  for (int i = 0; i < 64; i += 4) {
    int nl = i + ty;
    o[(size_t)nl * 512 + tx] = __float2bfloat16(tile[tx][nl]);
  }
}

// ---------------- fp32 -> bf16 weight conversion ----------------
__global__ __launch_bounds__(256) void cvt_k(const float* __restrict__ w,
                                             __hip_bfloat16* __restrict__ o, int n) {
  int i = blockIdx.x * 256 + threadIdx.x;
  if (i < n) o[i] = __float2bfloat16(w[i]);
}

// ---------------- bf16 GEMM, B^T form: D[m][n] = sum_k A[m][k]*Bm[n][k] ----
// 128x128 tile, 4 waves, each wave 64x64 via 4x4 MFMA 16x16x32 tiles.
// MODE 0: out bf16 [m][n] (+bias[n])
// MODE 1: out bf16 transposed vT[(b*512+n)][t], m=b*4096+t (+bias[n])
// MODE 2: out fp32 [m][n] * scale
// MODE 3: out bf16 [m][n]
// MODE 4: out fp32 at [(b*512+n)][t] = resid + acc + bias[n]
template <int MODE>
__global__ __launch_bounds__(256, 2) void gemm_bt_k(
    const __hip_bfloat16* __restrict__ A, const __hip_bfloat16* __restrict__ Bm,
    void* __restrict__ Cout, const float* __restrict__ bias,
    const float* __restrict__ resid, int K, int lda, int ldb, int ldc,
    float scale, long sAz, long sBz, long sCz) {
  int z = blockIdx.z;
  A  += (size_t)z * sAz;
  Bm += (size_t)z * sBz;
  size_t cbase = (size_t)z * sCz;
  int m0 = blockIdx.y * 128, n0 = blockIdx.x * 128;

  __shared__ __hip_bfloat16 As[128][40];  // +8 pad: 2-way LDS aliasing only
  __shared__ __hip_bfloat16 Bs[128][40];

  int tid  = threadIdx.x;
  int wid  = tid >> 6, lane = tid & 63;
  int wr   = (wid >> 1) * 64, wc = (wid & 1) * 64;
  int quad = lane >> 4, l16 = lane & 15;

  f32x4 acc[4][4] = {};

  int srow = tid >> 2, scol = (tid & 3) * 8;  // 4 threads/row, 16B each

  for (int k0 = 0; k0 < K; k0 += 32) {
    uint4 a0 = *(const uint4*)&A[(size_t)(m0 + srow) * lda + k0 + scol];
    uint4 a1 = *(const uint4*)&A[(size_t)(m0 + srow + 64) * lda + k0 + scol];
    uint4 b0 = *(const uint4*)&Bm[(size_t)(n0 + srow) * ldb + k0 + scol];
    uint4 b1 = *(const uint4*)&Bm[(size_t)(n0 + srow + 64) * ldb + k0 + scol];
    __syncthreads();  // protect LDS from previous iteration's readers
    *(uint4*)&As[srow][scol]      = a0;
    *(uint4*)&As[srow + 64][scol] = a1;
    *(uint4*)&Bs[srow][scol]      = b0;
    *(uint4*)&Bs[srow + 64][scol] = b1;
    __syncthreads();

    bf16x8 af[4], bfr[4];
#pragma unroll
    for (int i = 0; i < 4; i++)
      af[i] = *(const bf16x8*)&As[wr + i * 16 + l16][quad * 8];
#pragma unroll
    for (int j = 0; j < 4; j++)
      bfr[j] = *(const bf16x8*)&Bs[wc + j * 16 + l16][quad * 8];
#pragma unroll
    for (int i = 0; i < 4; i++)
#pragma unroll
      for (int j = 0; j < 4; j++)
        acc[i][j] = __builtin_amdgcn_mfma_f32_16x16x32_bf16(af[i], bfr[j],
                                                            acc[i][j], 0, 0, 0);
  }

  // Epilogue. C/D layout (verified m89/m91): col = lane&15, row = quad*4 + reg.
#pragma unroll
  for (int i = 0; i < 4; i++) {
#pragma unroll
    for (int j = 0; j < 4; j++) {
#pragma unroll
      for (int r = 0; r < 4; r++) {
        int m = m0 + wr + i * 16 + quad * 4 + r;
        int n = n0 + wc + j * 16 + l16;
        float v = acc[i][j][r];
        if (MODE == 0) {
          ((__hip_bfloat16*)Cout)[cbase + (size_t)m * ldc + n] =
              __float2bfloat16(v + bias[n]);
        } else if (MODE == 1) {
          int b = m >> 12, t = m & 4095;
          ((__hip_bfloat16*)Cout)[((size_t)(b * 512 + n)) * 4096 + t] =
              __float2bfloat16(v + bias[n]);
        } else if (MODE == 2) {
          ((float*)Cout)[cbase + (size_t)m * ldc + n] = v * scale;
        } else if (MODE == 3) {
          ((__hip_bfloat16*)Cout)[cbase + (size_t)m * ldc + n] =
              __float2bfloat16(v);
        } else {  // MODE 4
          int b = m >> 12, t = m & 4095;
          size_t idx = ((size_t)(b * 512 + n)) * 4096 + t;
          ((float*)Cout)[idx] = resid[idx] + v + bias[n];
        }
      }
    }
  }
}

// ---------------- row softmax: fp32 in, bf16 out, one block per row --------
__global__ __launch_bounds__(256) void softmax_k(const float* __restrict__ S,
                                                 __hip_bfloat16* __restrict__ P) {
  size_t row = blockIdx.x;
  const float* s = S + row * 4096;
  float v[16];
  float m = -1e30f;
#pragma unroll
  for (int i = 0; i < 16; i++) {
    v[i] = s[threadIdx.x + i * 256];
    m = fmaxf(m, v[i]);
  }
#pragma unroll
  for (int off = 32; off > 0; off >>= 1) m = fmaxf(m, __shfl_xor(m, off));
  __shared__ float red[4];
  __shared__ float red2[4];
  int wid = threadIdx.x >> 6, lane = threadIdx.x & 63;
  if (lane == 0) red[wid] = m;
  __syncthreads();
  m = fmaxf(fmaxf(red[0], red[1]), fmaxf(red[2], red[3]));
  float sum = 0.f;
#pragma unroll
  for (int i = 0; i < 16; i++) {
    v[i] = __expf(v[i] - m);
    sum += v[i];
  }
#pragma unroll
  for (int off = 32; off > 0; off >>= 1) sum += __shfl_xor(sum, off);
  if (lane == 0) red2[wid] = sum;
  __syncthreads();
  sum = red2[0] + red2[1] + red2[2] + red2[3];
  float inv = 1.f / sum;
  __hip_bfloat16* p = P + row * 4096;
#pragma unroll
  for (int i = 0; i < 16; i++)
    p[threadIdx.x + i * 256] = __float2bfloat16(v[i] * inv);
}

extern "C" void kernel_launch(void* const* d_in, const int* in_sizes, int n_in,
                              void* d_out, int out_size, void* d_ws,
                              size_t ws_size, hipStream_t stream) {
  const float* xp  = (const float*)d_in[0];
  const float* gwp = (const float*)d_in[1];
  const float* gbp = (const float*)d_in[2];
  const float* wqp = (const float*)d_in[3];
  const float* bqp = (const float*)d_in[4];
  const float* wkp = (const float*)d_in[5];
  const float* bkp = (const float*)d_in[6];
  const float* wvp = (const float*)d_in[7];
  const float* bvp = (const float*)d_in[8];
  const float* wop = (const float*)d_in[9];
  const float* bop = (const float*)d_in[10];
  float* outp = (float*)d_out;

  char* w = (char*)d_ws;
  size_t off = 0;
  auto alloc = [&](size_t bytes) {
    void* p = w + off;
    off += (bytes + 255) & ~(size_t)255;
    return p;
  };
  float* stats         = (float*)alloc(64 * 2 * sizeof(float));
  __hip_bfloat16* hf   = (__hip_bfloat16*)alloc((size_t)2 * 4096 * 512 * 2);
  __hip_bfloat16* wqb  = (__hip_bfloat16*)alloc((size_t)512 * 512 * 2);
  __hip_bfloat16* wkb  = (__hip_bfloat16*)alloc((size_t)512 * 512 * 2);
  __hip_bfloat16* wvb  = (__hip_bfloat16*)alloc((size_t)512 * 512 * 2);
  __hip_bfloat16* wob  = (__hip_bfloat16*)alloc((size_t)512 * 512 * 2);
  __hip_bfloat16* qb   = (__hip_bfloat16*)alloc((size_t)2 * 4096 * 512 * 2);
  __hip_bfloat16* kb   = (__hip_bfloat16*)alloc((size_t)2 * 4096 * 512 * 2);
  __hip_bfloat16* vT   = (__hip_bfloat16*)alloc((size_t)2 * 512 * 4096 * 2);
  __hip_bfloat16* obuf = (__hip_bfloat16*)alloc((size_t)2 * 4096 * 512 * 2);
  float* Sbuf          = (float*)alloc((size_t)4096 * 4096 * 4);     // per-batch reuse
  __hip_bfloat16* Pbuf = (__hip_bfloat16*)alloc((size_t)2 * 4096 * 4096 * 2);

  gn_stats_k<<<64, 256, 0, stream>>>(xp, stats);
  gn_apply_k<<<dim3(8, 64, 2), 256, 0, stream>>>(xp, stats, gwp, gbp, hf);
  cvt_k<<<1024, 256, 0, stream>>>(wqp, wqb, 262144);
  cvt_k<<<1024, 256, 0, stream>>>(wkp, wkb, 262144);
  cvt_k<<<1024, 256, 0, stream>>>(wvp, wvb, 262144);
  cvt_k<<<1024, 256, 0, stream>>>(wop, wob, 262144);

  // Q, K: [8192x512] = hf * W^T + b
  gemm_bt_k<0><<<dim3(4, 64, 1), 256, 0, stream>>>(hf, wqb, qb, bqp, nullptr,
                                                   512, 512, 512, 512, 1.f, 0, 0, 0);
  gemm_bt_k<0><<<dim3(4, 64, 1), 256, 0, stream>>>(hf, wkb, kb, bkp, nullptr,
                                                   512, 512, 512, 512, 1.f, 0, 0, 0);
  // V: stored transposed vT[b][c][n]
  gemm_bt_k<1><<<dim3(4, 64, 1), 256, 0, stream>>>(hf, wvb, vT, bvp, nullptr,
                                                   512, 512, 512, 0, 1.f, 0, 0, 0);

  for (int b = 0; b < 2; b++) {
    // S = Q K^T * scale  (fp32, 4096x4096)
    gemm_bt_k<2><<<dim3(32, 32, 1), 256, 0, stream>>>(
        qb + (size_t)b * 4096 * 512, kb + (size_t)b * 4096 * 512, Sbuf, nullptr,
        nullptr, 512, 512, 512, 4096, 0.044194173824159216f, 0, 0, 0);
    softmax_k<<<4096, 256, 0, stream>>>(Sbuf, Pbuf + (size_t)b * 4096 * 4096);
  }

  // O = P * V  (A = P bf16 [4096][4096], B = vT [512][4096]) -> obuf [b][n][c]
  gemm_bt_k<3><<<dim3(4, 32, 2), 256, 0, stream>>>(
      Pbuf, vT, obuf, nullptr, nullptr, 4096, 4096, 4096, 512, 1.f,
      (long)4096 * 4096, (long)512 * 4096, (long)4096 * 512);

  // out = x + Wo*O + bo, stored [b][c][n]
  gemm_bt_k<4><<<dim3(4, 64, 1), 256, 0, stream>>>(obuf, wob, outp, bop, xp,
                                                   512, 512, 512, 0, 1.f, 0, 0, 0);
}

// Round 2
// 351.807 us; speedup vs baseline: 1.0092x; 1.0092x over previous
//
#include <hip/hip_runtime.h>
#include <hip/hip_bf16.h>

// Problem constants: B=2, C=512, H=W=64 -> N=4096, G=32 (16 ch/group), EPS=1e-6.

typedef float f32x4 __attribute__((ext_vector_type(4)));
typedef __bf16 bf16x8 __attribute__((ext_vector_type(8)));

typedef const __attribute__((address_space(1))) unsigned char* gas_p;
typedef __attribute__((address_space(3))) unsigned char* las_p;

__device__ __forceinline__ void gload_lds16(const void* g, void* l) {
  // async DMA: each lane contributes 16B; LDS dst = wave-uniform base + lane*16
  __builtin_amdgcn_global_load_lds((gas_p)g, (las_p)l, 16, 0, 0);
}

// ---------------- GroupNorm statistics: one block per (b,g) ----------------
__global__ __launch_bounds__(256) void gn_stats_k(const float* __restrict__ x,
                                                  float* __restrict__ stats) {
  int bg = blockIdx.x;  // 0..63  (b*32+g); group = 16 contiguous channels
  const float4* p = (const float4*)(x + (size_t)bg * 65536);
  float s = 0.f, s2 = 0.f;
  for (int i = threadIdx.x; i < 16384; i += 256) {
    float4 v = p[i];
    s  += v.x + v.y + v.z + v.w;
    s2 += v.x * v.x + v.y * v.y + v.z * v.z + v.w * v.w;
  }
#pragma unroll
  for (int off = 32; off > 0; off >>= 1) {
    s  += __shfl_xor(s, off);
    s2 += __shfl_xor(s2, off);
  }
  __shared__ float rs[4], rs2[4];
  int wid = threadIdx.x >> 6, lane = threadIdx.x & 63;
  if (lane == 0) { rs[wid] = s; rs2[wid] = s2; }
  __syncthreads();
  if (threadIdx.x == 0) {
    float S  = rs[0] + rs[1] + rs[2] + rs[3];
    float S2 = rs2[0] + rs2[1] + rs2[2] + rs2[3];
    float mean = S * (1.f / 65536.f);
    float var  = S2 * (1.f / 65536.f) - mean * mean;
    stats[bg * 2]     = mean;
    stats[bg * 2 + 1] = rsqrtf(var + 1e-6f);
  }
}

// ------- GroupNorm apply + transpose [b][c][n] -> hf bf16 [b][n][c] --------
__global__ __launch_bounds__(256) void gn_apply_k(const float* __restrict__ x,
                                                  const float* __restrict__ stats,
                                                  const float* __restrict__ gw,
                                                  const float* __restrict__ gb,
                                                  __hip_bfloat16* __restrict__ hf) {
  int c0 = blockIdx.x * 64, n0 = blockIdx.y * 64, b = blockIdx.z;
  __shared__ float tile[64][65];
  int tx = threadIdx.x & 63, ty = threadIdx.x >> 6;
  const float* xb = x + ((size_t)(b * 512 + c0)) * 4096 + n0;
#pragma unroll
  for (int i = 0; i < 64; i += 4) {
    int cl = i + ty;
    int c  = c0 + cl;
    float mean = stats[(b * 32 + (c >> 4)) * 2];
    float rstd = stats[(b * 32 + (c >> 4)) * 2 + 1];
    float v = xb[(size_t)cl * 4096 + tx];
    tile[cl][tx] = (v - mean) * rstd * gw[c] + gb[c];
  }
  __syncthreads();
  __hip_bfloat16* o = hf + ((size_t)(b * 4096 + n0)) * 512 + c0;
#pragma unroll
  for (int i = 0; i < 64; i += 4) {
    int nl = i + ty;
    o[(size_t)nl * 512 + tx] = __float2bfloat16(tile[tx][nl]);
  }
}

// ---------------- fp32 -> bf16 weight conversion ----------------
__global__ __launch_bounds__(256) void cvt_k(const float* __restrict__ w,
                                             __hip_bfloat16* __restrict__ o, int n) {
  int i = blockIdx.x * 256 + threadIdx.x;
  if (i < n) o[i] = __float2bfloat16(w[i]);
}

// ---------------- bf16 GEMM, B^T form: D[m][n] = sum_k A[m][k]*Bm[n][k] ----
// 128x128 tile, 4 waves, each wave 64x64 via 4x4 MFMA 16x16x32 tiles.
// Staging: async global_load_lds width=16 into unpadded [128][32] LDS tiles.
// MODE 0: out bf16 [m][n] + bias[n]          (Q, K)
// MODE 2: out fp32 [m][n] * scale            (QK^T)
// MODE 3: out bf16 [m][n]                    (PV)
// MODE 5: out bf16 [m][n] + bias[m]          (V with A=Wv -> vT, coalesced)
// MODE 6: out fp32 [m][n] + bias[m] + resid  (out-proj with A=Wo, coalesced)
template <int MODE>
__global__ __launch_bounds__(256, 3) void gemm_bt_k(
    const __hip_bfloat16* __restrict__ A, const __hip_bfloat16* __restrict__ Bm,
    void* __restrict__ Cout, const float* __restrict__ bias,
    const float* __restrict__ resid, int K, int lda, int ldb, int ldc,
    float scale, long sAz, long sBz, long sCz) {
  int z = blockIdx.z;
  A  += (size_t)z * sAz;
  Bm += (size_t)z * sBz;
  size_t cbase = (size_t)z * sCz;
  int m0 = blockIdx.y * 128, n0 = blockIdx.x * 128;

  __shared__ __hip_bfloat16 As[128 * 32];  // row-major, 64B rows (DMA layout)
  __shared__ __hip_bfloat16 Bs[128 * 32];

  int tid  = threadIdx.x;
  int wv   = tid >> 6, lane = tid & 63;
  int wr   = (wv >> 1) * 64, wc = (wv & 1) * 64;
  int quad = lane >> 4, l16 = lane & 15;

  // DMA source mapping: instruction c of wave wv covers rows wv*32+16c..+15;
  // lane l -> row + l/4, k-chunk (l%4)*8.
  int srow = wv * 32 + (lane >> 2);
  int scol = (lane & 3) * 8;
  const __hip_bfloat16* gA0 = A  + (size_t)(m0 + srow) * lda + scol;
  const __hip_bfloat16* gA1 = gA0 + (size_t)16 * lda;
  const __hip_bfloat16* gB0 = Bm + (size_t)(n0 + srow) * ldb + scol;
  const __hip_bfloat16* gB1 = gB0 + (size_t)16 * ldb;
  __hip_bfloat16* lA0 = &As[wv * 1024];        // wave-uniform LDS bases
  __hip_bfloat16* lA1 = &As[wv * 1024 + 512];
  __hip_bfloat16* lB0 = &Bs[wv * 1024];
  __hip_bfloat16* lB1 = &Bs[wv * 1024 + 512];

  f32x4 acc[4][4] = {};

  for (int k0 = 0; k0 < K; k0 += 32) {
    __syncthreads();  // all waves done reading LDS before DMA overwrites it
    gload_lds16(gA0 + k0, lA0);
    gload_lds16(gA1 + k0, lA1);
    gload_lds16(gB0 + k0, lB0);
    gload_lds16(gB1 + k0, lB1);
    __syncthreads();  // drains vmcnt -> DMA data visible in LDS

    bf16x8 af[4], bfr[4];
#pragma unroll
    for (int i = 0; i < 4; i++)
      af[i] = *(const bf16x8*)&As[(wr + i * 16 + l16) * 32 + quad * 8];
#pragma unroll
    for (int j = 0; j < 4; j++)
      bfr[j] = *(const bf16x8*)&Bs[(wc + j * 16 + l16) * 32 + quad * 8];
#pragma unroll
    for (int i = 0; i < 4; i++)
#pragma unroll
      for (int j = 0; j < 4; j++)
        acc[i][j] = __builtin_amdgcn_mfma_f32_16x16x32_bf16(af[i], bfr[j],
                                                            acc[i][j], 0, 0, 0);
  }

  // Epilogue. C/D layout (verified m89/m91): col = lane&15, row = quad*4 + reg.
#pragma unroll
  for (int i = 0; i < 4; i++) {
#pragma unroll
    for (int j = 0; j < 4; j++) {
#pragma unroll
      for (int r = 0; r < 4; r++) {
        int m = m0 + wr + i * 16 + quad * 4 + r;
        int n = n0 + wc + j * 16 + l16;
        float v = acc[i][j][r];
        size_t idx = cbase + (size_t)m * ldc + n;
        if (MODE == 0) {
          ((__hip_bfloat16*)Cout)[idx] = __float2bfloat16(v + bias[n]);
        } else if (MODE == 2) {
          ((float*)Cout)[idx] = v * scale;
        } else if (MODE == 3) {
          ((__hip_bfloat16*)Cout)[idx] = __float2bfloat16(v);
        } else if (MODE == 5) {
          ((__hip_bfloat16*)Cout)[idx] = __float2bfloat16(v + bias[m]);
        } else {  // MODE 6
          ((float*)Cout)[idx] = resid[idx] + v + bias[m];
        }
      }
    }
  }
}

// ---------------- row softmax: fp32 in, bf16 out, one block per row --------
__global__ __launch_bounds__(256) void softmax_k(const float* __restrict__ S,
                                                 __hip_bfloat16* __restrict__ P) {
  size_t row = blockIdx.x;
  const float* s = S + row * 4096;
  float v[16];
  float m = -1e30f;
#pragma unroll
  for (int i = 0; i < 16; i++) {
    v[i] = s[threadIdx.x + i * 256];
    m = fmaxf(m, v[i]);
  }
#pragma unroll
  for (int off = 32; off > 0; off >>= 1) m = fmaxf(m, __shfl_xor(m, off));
  __shared__ float red[4];
  __shared__ float red2[4];
  int wid = threadIdx.x >> 6, lane = threadIdx.x & 63;
  if (lane == 0) red[wid] = m;
  __syncthreads();
  m = fmaxf(fmaxf(red[0], red[1]), fmaxf(red[2], red[3]));
  float sum = 0.f;
#pragma unroll
  for (int i = 0; i < 16; i++) {
    v[i] = __expf(v[i] - m);
    sum += v[i];
  }
#pragma unroll
  for (int off = 32; off > 0; off >>= 1) sum += __shfl_xor(sum, off);
  if (lane == 0) red2[wid] = sum;
  __syncthreads();
  sum = red2[0] + red2[1] + red2[2] + red2[3];
  float inv = 1.f / sum;
  __hip_bfloat16* p = P + row * 4096;
#pragma unroll
  for (int i = 0; i < 16; i++)
    p[threadIdx.x + i * 256] = __float2bfloat16(v[i] * inv);
}

extern "C" void kernel_launch(void* const* d_in, const int* in_sizes, int n_in,
                              void* d_out, int out_size, void* d_ws,
                              size_t ws_size, hipStream_t stream) {
  const float* xp  = (const float*)d_in[0];
  const float* gwp = (const float*)d_in[1];
  const float* gbp = (const float*)d_in[2];
  const float* wqp = (const float*)d_in[3];
  const float* bqp = (const float*)d_in[4];
  const float* wkp = (const float*)d_in[5];
  const float* bkp = (const float*)d_in[6];
  const float* wvp = (const float*)d_in[7];
  const float* bvp = (const float*)d_in[8];
  const float* wop = (const float*)d_in[9];
  const float* bop = (const float*)d_in[10];
  float* outp = (float*)d_out;

  char* w = (char*)d_ws;
  size_t off = 0;
  auto alloc = [&](size_t bytes) {
    void* p = w + off;
    off += (bytes + 255) & ~(size_t)255;
    return p;
  };
  float* stats         = (float*)alloc(64 * 2 * sizeof(float));
  __hip_bfloat16* hf   = (__hip_bfloat16*)alloc((size_t)2 * 4096 * 512 * 2);
  __hip_bfloat16* wqb  = (__hip_bfloat16*)alloc((size_t)512 * 512 * 2);
  __hip_bfloat16* wkb  = (__hip_bfloat16*)alloc((size_t)512 * 512 * 2);
  __hip_bfloat16* wvb  = (__hip_bfloat16*)alloc((size_t)512 * 512 * 2);
  __hip_bfloat16* wob  = (__hip_bfloat16*)alloc((size_t)512 * 512 * 2);
  __hip_bfloat16* qb   = (__hip_bfloat16*)alloc((size_t)2 * 4096 * 512 * 2);
  __hip_bfloat16* kb   = (__hip_bfloat16*)alloc((size_t)2 * 4096 * 512 * 2);
  __hip_bfloat16* vT   = (__hip_bfloat16*)alloc((size_t)2 * 512 * 4096 * 2);
  __hip_bfloat16* obuf = (__hip_bfloat16*)alloc((size_t)2 * 4096 * 512 * 2);
  float* Sbuf          = (float*)alloc((size_t)4096 * 4096 * 4);     // per-batch reuse
  __hip_bfloat16* Pbuf = (__hip_bfloat16*)alloc((size_t)2 * 4096 * 4096 * 2);

  gn_stats_k<<<64, 256, 0, stream>>>(xp, stats);
  gn_apply_k<<<dim3(8, 64, 2), 256, 0, stream>>>(xp, stats, gwp, gbp, hf);
  cvt_k<<<1024, 256, 0, stream>>>(wqp, wqb, 262144);
  cvt_k<<<1024, 256, 0, stream>>>(wkp, wkb, 262144);
  cvt_k<<<1024, 256, 0, stream>>>(wvp, wvb, 262144);
  cvt_k<<<1024, 256, 0, stream>>>(wop, wob, 262144);

  // Q, K: [8192x512] = hf * W^T + b   (out [t][c], coalesced)
  gemm_bt_k<0><<<dim3(4, 64, 1), 256, 0, stream>>>(hf, wqb, qb, bqp, nullptr,
                                                   512, 512, 512, 512, 1.f, 0, 0, 0);
  gemm_bt_k<0><<<dim3(4, 64, 1), 256, 0, stream>>>(hf, wkb, kb, bkp, nullptr,
                                                   512, 512, 512, 512, 1.f, 0, 0, 0);
  // V transposed: vT[b][o][t] = sum_c Wv[o][c]*hf[b][t][c] + bv[o]
  // A = Wv (m=o), B = hf[b] (n=t)  -> coalesced row store
  gemm_bt_k<5><<<dim3(32, 4, 2), 256, 0, stream>>>(
      wvb, hf, vT, bvp, nullptr, 512, 512, 512, 4096, 1.f,
      0, (long)4096 * 512, (long)512 * 4096);

  for (int b = 0; b < 2; b++) {
    // S = Q K^T * scale  (fp32, 4096x4096)
    gemm_bt_k<2><<<dim3(32, 32, 1), 256, 0, stream>>>(
        qb + (size_t)b * 4096 * 512, kb + (size_t)b * 4096 * 512, Sbuf, nullptr,
        nullptr, 512, 512, 512, 4096, 0.044194173824159216f, 0, 0, 0);
    softmax_k<<<4096, 256, 0, stream>>>(Sbuf, Pbuf + (size_t)b * 4096 * 4096);
  }

  // O = P * V  (A = P bf16 [4096][4096], B = vT [512][4096]) -> obuf [b][n][c]
  gemm_bt_k<3><<<dim3(4, 32, 2), 256, 0, stream>>>(
      Pbuf, vT, obuf, nullptr, nullptr, 4096, 4096, 4096, 512, 1.f,
      (long)4096 * 4096, (long)512 * 4096, (long)4096 * 512);

  // out[b][c][t] = x + Wo*O + bo   (A = Wo, m=c -> coalesced fp32 row store)
  gemm_bt_k<6><<<dim3(32, 4, 2), 256, 0, stream>>>(
      wob, obuf, outp, bop, xp, 512, 512, 512, 4096, 1.f,
      0, (long)4096 * 512, (long)512 * 4096);
}

// Round 4
// 336.049 us; speedup vs baseline: 1.0565x; 1.0469x over previous
//
#include <hip/hip_runtime.h>
#include <hip/hip_bf16.h>

// Problem constants: B=2, C=512, H=W=64 -> N=4096, G=32 (16 ch/group), EPS=1e-6.

typedef float f32x4 __attribute__((ext_vector_type(4)));
typedef __bf16 bf16x8 __attribute__((ext_vector_type(8)));

typedef const __attribute__((address_space(1))) unsigned char* gas_p;
typedef __attribute__((address_space(3))) unsigned char* las_p;

__device__ __forceinline__ void gload_lds16(const void* g, void* l) {
  // async DMA: each lane contributes 16B; LDS dst = wave-uniform base + lane*16
  __builtin_amdgcn_global_load_lds((gas_p)g, (las_p)l, 16, 0, 0);
}

// ---------------- GroupNorm statistics: one block per (b,g) ----------------
__global__ __launch_bounds__(256) void gn_stats_k(const float* __restrict__ x,
                                                  float* __restrict__ stats) {
  int bg = blockIdx.x;  // 0..63  (b*32+g); group = 16 contiguous channels
  const float4* p = (const float4*)(x + (size_t)bg * 65536);
  float s = 0.f, s2 = 0.f;
  for (int i = threadIdx.x; i < 16384; i += 256) {
    float4 v = p[i];
    s  += v.x + v.y + v.z + v.w;
    s2 += v.x * v.x + v.y * v.y + v.z * v.z + v.w * v.w;
  }
#pragma unroll
  for (int off = 32; off > 0; off >>= 1) {
    s  += __shfl_xor(s, off);
    s2 += __shfl_xor(s2, off);
  }
  __shared__ float rs[4], rs2[4];
  int wid = threadIdx.x >> 6, lane = threadIdx.x & 63;
  if (lane == 0) { rs[wid] = s; rs2[wid] = s2; }
  __syncthreads();
  if (threadIdx.x == 0) {
    float S  = rs[0] + rs[1] + rs[2] + rs[3];
    float S2 = rs2[0] + rs2[1] + rs2[2] + rs2[3];
    float mean = S * (1.f / 65536.f);
    float var  = S2 * (1.f / 65536.f) - mean * mean;
    stats[bg * 2]     = mean;
    stats[bg * 2 + 1] = rsqrtf(var + 1e-6f);
  }
}

// ------- GroupNorm apply + transpose [b][c][n] -> hf bf16 [b][n][c] --------
__global__ __launch_bounds__(256) void gn_apply_k(const float* __restrict__ x,
                                                  const float* __restrict__ stats,
                                                  const float* __restrict__ gw,
                                                  const float* __restrict__ gb,
                                                  __hip_bfloat16* __restrict__ hf) {
  int c0 = blockIdx.x * 64, n0 = blockIdx.y * 64, b = blockIdx.z;
  __shared__ float tile[64][65];
  int tx = threadIdx.x & 63, ty = threadIdx.x >> 6;
  const float* xb = x + ((size_t)(b * 512 + c0)) * 4096 + n0;
#pragma unroll
  for (int i = 0; i < 64; i += 4) {
    int cl = i + ty;
    int c  = c0 + cl;
    float mean = stats[(b * 32 + (c >> 4)) * 2];
    float rstd = stats[(b * 32 + (c >> 4)) * 2 + 1];
    float v = xb[(size_t)cl * 4096 + tx];
    tile[cl][tx] = (v - mean) * rstd * gw[c] + gb[c];
  }
  __syncthreads();
  __hip_bfloat16* o = hf + ((size_t)(b * 4096 + n0)) * 512 + c0;
#pragma unroll
  for (int i = 0; i < 64; i += 4) {
    int nl = i + ty;
    o[(size_t)nl * 512 + tx] = __float2bfloat16(tile[tx][nl]);
  }
}

// ---------------- fp32 -> bf16 weight conversion ----------------
__global__ __launch_bounds__(256) void cvt_k(const float* __restrict__ w,
                                             __hip_bfloat16* __restrict__ o, int n) {
  int i = blockIdx.x * 256 + threadIdx.x;
  if (i < n) o[i] = __float2bfloat16(w[i]);
}

__global__ __launch_bounds__(256) void bcat_k(const float* __restrict__ bq,
                                              const float* __restrict__ bk,
                                              float* __restrict__ bqk) {
  int i = blockIdx.x * 256 + threadIdx.x;
  if (i < 512) bqk[i] = bq[i];
  else if (i < 1024) bqk[i] = bk[i - 512];
}

// ============ fused QKV: one dispatch, 768 blocks ============
// bx<8 : QK GEMM  qk[t][o] (o<1024) = sum_c hf[t][c]*Wqk[o][c] + bqk[o]
// bx>=8: V GEMM   vT[b][o][t]       = sum_c Wv[o][c]*hf[t][c] + bv[o]
__global__ __launch_bounds__(256, 4) void qkv_k(
    const __hip_bfloat16* __restrict__ hf, const __hip_bfloat16* __restrict__ wqk,
    const __hip_bfloat16* __restrict__ wv, const float* __restrict__ bqk,
    const float* __restrict__ bv, __hip_bfloat16* __restrict__ qk,
    __hip_bfloat16* __restrict__ vT) {
  bool isV = blockIdx.x >= 8;
  int m0 = isV ? (blockIdx.x - 8) * 128 : blockIdx.y * 128;
  int n0 = isV ? blockIdx.y * 128 : blockIdx.x * 128;
  const __hip_bfloat16* A  = isV ? wv : hf;   // [m][512]
  const __hip_bfloat16* Bm = isV ? hf : wqk;  // [n][512]

  __shared__ __hip_bfloat16 As[128 * 32];
  __shared__ __hip_bfloat16 Bs[128 * 32];

  int tid  = threadIdx.x;
  int wvx  = tid >> 6, lane = tid & 63;
  int wr   = (wvx >> 1) * 64, wc = (wvx & 1) * 64;
  int quad = lane >> 4, l16 = lane & 15;

  int srow = wvx * 32 + (lane >> 2);
  int scol = (lane & 3) * 8;
  const __hip_bfloat16* gA0 = A  + (size_t)(m0 + srow) * 512 + scol;
  const __hip_bfloat16* gA1 = gA0 + (size_t)16 * 512;
  const __hip_bfloat16* gB0 = Bm + (size_t)(n0 + srow) * 512 + scol;
  const __hip_bfloat16* gB1 = gB0 + (size_t)16 * 512;
  __hip_bfloat16* lA0 = &As[wvx * 1024];
  __hip_bfloat16* lA1 = &As[wvx * 1024 + 512];
  __hip_bfloat16* lB0 = &Bs[wvx * 1024];
  __hip_bfloat16* lB1 = &Bs[wvx * 1024 + 512];

  f32x4 acc[4][4] = {};
  for (int k0 = 0; k0 < 512; k0 += 32) {
    __syncthreads();
    gload_lds16(gA0 + k0, lA0);
    gload_lds16(gA1 + k0, lA1);
    gload_lds16(gB0 + k0, lB0);
    gload_lds16(gB1 + k0, lB1);
    __syncthreads();
    bf16x8 af[4], bfr[4];
#pragma unroll
    for (int i = 0; i < 4; i++)
      af[i] = *(const bf16x8*)&As[(wr + i * 16 + l16) * 32 + quad * 8];
#pragma unroll
    for (int j = 0; j < 4; j++)
      bfr[j] = *(const bf16x8*)&Bs[(wc + j * 16 + l16) * 32 + quad * 8];
#pragma unroll
    for (int i = 0; i < 4; i++)
#pragma unroll
      for (int j = 0; j < 4; j++)
        acc[i][j] = __builtin_amdgcn_mfma_f32_16x16x32_bf16(af[i], bfr[j],
                                                            acc[i][j], 0, 0, 0);
  }
#pragma unroll
  for (int i = 0; i < 4; i++)
#pragma unroll
    for (int j = 0; j < 4; j++)
#pragma unroll
      for (int r = 0; r < 4; r++) {
        int m = m0 + wr + i * 16 + quad * 4 + r;
        int n = n0 + wc + j * 16 + l16;
        float v = acc[i][j][r];
        if (!isV) {
          qk[(size_t)m * 1024 + n] = __float2bfloat16(v + bqk[n]);
        } else {
          int b = n >> 12, t = n & 4095;
          vT[((size_t)(b * 512 + m)) * 4096 + t] = __float2bfloat16(v + bv[m]);
        }
      }
}

// ---------------- bf16 GEMM, B^T form: D[m][n] = sum_k A[m][k]*Bm[n][k] ----
// z decodes (bb, ks): bb = z/kspl, ks = z%kspl; A,B advance bb*s?z + ks*Kc.
// MODE 2: out fp32 [m][n] * scale           (QK^T)
// MODE 3: out bf16 [m][n]                   (PV split-K partials)
// MODE 6: out fp32 [m][n] + bias[m] + resid (out-proj)
template <int MODE>
__global__ __launch_bounds__(256, 4) void gemm_bt_k(
    const __hip_bfloat16* __restrict__ A, const __hip_bfloat16* __restrict__ Bm,
    void* __restrict__ Cout, const float* __restrict__ bias,
    const float* __restrict__ resid, int Kc, int lda, int ldb, int ldc,
    float scale, long sAz, long sBz, long sCz, int kspl) {
  int z  = blockIdx.z;
  int bb = z / kspl, ks = z - bb * kspl;
  A  += (size_t)bb * sAz + (size_t)ks * Kc;
  Bm += (size_t)bb * sBz + (size_t)ks * Kc;
  size_t cbase = (size_t)z * sCz;
  int m0 = blockIdx.y * 128, n0 = blockIdx.x * 128;

  __shared__ __hip_bfloat16 As[128 * 32];
  __shared__ __hip_bfloat16 Bs[128 * 32];

  int tid  = threadIdx.x;
  int wv   = tid >> 6, lane = tid & 63;
  int wr   = (wv >> 1) * 64, wc = (wv & 1) * 64;
  int quad = lane >> 4, l16 = lane & 15;

  int srow = wv * 32 + (lane >> 2);
  int scol = (lane & 3) * 8;
  const __hip_bfloat16* gA0 = A  + (size_t)(m0 + srow) * lda + scol;
  const __hip_bfloat16* gA1 = gA0 + (size_t)16 * lda;
  const __hip_bfloat16* gB0 = Bm + (size_t)(n0 + srow) * ldb + scol;
  const __hip_bfloat16* gB1 = gB0 + (size_t)16 * ldb;
  __hip_bfloat16* lA0 = &As[wv * 1024];
  __hip_bfloat16* lA1 = &As[wv * 1024 + 512];
  __hip_bfloat16* lB0 = &Bs[wv * 1024];
  __hip_bfloat16* lB1 = &Bs[wv * 1024 + 512];

  f32x4 acc[4][4] = {};
  for (int k0 = 0; k0 < Kc; k0 += 32) {
    __syncthreads();
    gload_lds16(gA0 + k0, lA0);
    gload_lds16(gA1 + k0, lA1);
    gload_lds16(gB0 + k0, lB0);
    gload_lds16(gB1 + k0, lB1);
    __syncthreads();
    bf16x8 af[4], bfr[4];
#pragma unroll
    for (int i = 0; i < 4; i++)
      af[i] = *(const bf16x8*)&As[(wr + i * 16 + l16) * 32 + quad * 8];
#pragma unroll
    for (int j = 0; j < 4; j++)
      bfr[j] = *(const bf16x8*)&Bs[(wc + j * 16 + l16) * 32 + quad * 8];
#pragma unroll
    for (int i = 0; i < 4; i++)
#pragma unroll
      for (int j = 0; j < 4; j++)
        acc[i][j] = __builtin_amdgcn_mfma_f32_16x16x32_bf16(af[i], bfr[j],
                                                            acc[i][j], 0, 0, 0);
  }

  // C/D layout: col = lane&15, row = quad*4 + reg.
#pragma unroll
  for (int i = 0; i < 4; i++)
#pragma unroll
    for (int j = 0; j < 4; j++)
#pragma unroll
      for (int r = 0; r < 4; r++) {
        int m = m0 + wr + i * 16 + quad * 4 + r;
        int n = n0 + wc + j * 16 + l16;
        float v = acc[i][j][r];
        size_t idx = cbase + (size_t)m * ldc + n;
        if (MODE == 2) {
          ((float*)Cout)[idx] = v * scale;
        } else if (MODE == 3) {
          ((__hip_bfloat16*)Cout)[idx] = __float2bfloat16(v);
        } else {  // MODE 6
          ((float*)Cout)[idx] = resid[idx] + v + bias[m];
        }
      }
}

// ------- row softmax, IN-PLACE: fp32 row -> bf16 row (same storage) -------
__global__ __launch_bounds__(256) void softmax_k(float* __restrict__ S) {
  size_t row = blockIdx.x;
  const float* s = S + row * 4096;
  float v[16];
  float m = -1e30f;
#pragma unroll
  for (int i = 0; i < 16; i++) {
    v[i] = s[threadIdx.x + i * 256];
    m = fmaxf(m, v[i]);
  }
#pragma unroll
  for (int off = 32; off > 0; off >>= 1) m = fmaxf(m, __shfl_xor(m, off));
  __shared__ float red[4];
  __shared__ float red2[4];
  int wid = threadIdx.x >> 6, lane = threadIdx.x & 63;
  if (lane == 0) red[wid] = m;
  __syncthreads();  // also orders: all row loads precede the in-place stores
  m = fmaxf(fmaxf(red[0], red[1]), fmaxf(red[2], red[3]));
  float sum = 0.f;
#pragma unroll
  for (int i = 0; i < 16; i++) {
    v[i] = __expf(v[i] - m);
    sum += v[i];
  }
#pragma unroll
  for (int off = 32; off > 0; off >>= 1) sum += __shfl_xor(sum, off);
  if (lane == 0) red2[wid] = sum;
  __syncthreads();
  sum = red2[0] + red2[1] + red2[2] + red2[3];
  float inv = 1.f / sum;
  __hip_bfloat16* p = (__hip_bfloat16*)S + row * 8192;  // bf16 row stride 8192
#pragma unroll
  for (int i = 0; i < 16; i++)
    p[threadIdx.x + i * 256] = __float2bfloat16(v[i] * inv);
}

// ---- reduce 4 bf16 split-K partials -> obuf bf16 [2][4096][512] ----
__global__ __launch_bounds__(256) void reduce_k(const __hip_bfloat16* __restrict__ part,
                                                __hip_bfloat16* __restrict__ obuf) {
  // per batch: 4096*512 = 2^21 elems; 8 per thread
  size_t i8 = (size_t)blockIdx.x * 256 + threadIdx.x;   // 0 .. 2*2^21/8-1
  size_t perb = (size_t)4096 * 512 / 8;                 // 262144
  size_t b = i8 / perb, r = i8 - b * perb;
  float acc[8] = {};
#pragma unroll
  for (int ks = 0; ks < 4; ks++) {
    bf16x8 v = ((const bf16x8*)part)[(b * 4 + ks) * perb + r];
#pragma unroll
    for (int l = 0; l < 8; l++) acc[l] += (float)v[l];
  }
  bf16x8 o;
#pragma unroll
  for (int l = 0; l < 8; l++) o[l] = (__bf16)acc[l];
  ((bf16x8*)obuf)[b * perb + r] = o;
}

extern "C" void kernel_launch(void* const* d_in, const int* in_sizes, int n_in,
                              void* d_out, int out_size, void* d_ws,
                              size_t ws_size, hipStream_t stream) {
  const float* xp  = (const float*)d_in[0];
  const float* gwp = (const float*)d_in[1];
  const float* gbp = (const float*)d_in[2];
  const float* wqp = (const float*)d_in[3];
  const float* bqp = (const float*)d_in[4];
  const float* wkp = (const float*)d_in[5];
  const float* bkp = (const float*)d_in[6];
  const float* wvp = (const float*)d_in[7];
  const float* bvp = (const float*)d_in[8];
  const float* wop = (const float*)d_in[9];
  const float* bop = (const float*)d_in[10];
  float* outp = (float*)d_out;

  char* w = (char*)d_ws;
  size_t off = 0;
  auto alloc = [&](size_t bytes) {
    void* p = w + off;
    off += (bytes + 255) & ~(size_t)255;
    return p;
  };
  float* stats         = (float*)alloc(64 * 2 * sizeof(float));
  __hip_bfloat16* hf   = (__hip_bfloat16*)alloc((size_t)2 * 4096 * 512 * 2);
  __hip_bfloat16* wqkb = (__hip_bfloat16*)alloc((size_t)1024 * 512 * 2);
  __hip_bfloat16* wvb  = (__hip_bfloat16*)alloc((size_t)512 * 512 * 2);
  __hip_bfloat16* wob  = (__hip_bfloat16*)alloc((size_t)512 * 512 * 2);
  float* bqk           = (float*)alloc(1024 * sizeof(float));
  __hip_bfloat16* qk   = (__hip_bfloat16*)alloc((size_t)2 * 4096 * 1024 * 2);
  __hip_bfloat16* vT   = (__hip_bfloat16*)alloc((size_t)2 * 512 * 4096 * 2);
  __hip_bfloat16* obuf = (__hip_bfloat16*)alloc((size_t)2 * 4096 * 512 * 2);
  __hip_bfloat16* part = (__hip_bfloat16*)alloc((size_t)8 * 4096 * 512 * 2);
  float* Sbuf          = (float*)alloc((size_t)2 * 4096 * 4096 * 4);  // S, then P in-place

  const int NW = 262144;                 // 512*512 weight elems
  const int CVG = (NW + 255) / 256;      // 1024 blocks — round-3 bug was 512

  gn_stats_k<<<64, 256, 0, stream>>>(xp, stats);
  gn_apply_k<<<dim3(8, 64, 2), 256, 0, stream>>>(xp, stats, gwp, gbp, hf);
  cvt_k<<<CVG, 256, 0, stream>>>(wqp, wqkb, NW);
  cvt_k<<<CVG, 256, 0, stream>>>(wkp, wqkb + NW, NW);
  cvt_k<<<CVG, 256, 0, stream>>>(wvp, wvb, NW);
  cvt_k<<<CVG, 256, 0, stream>>>(wop, wob, NW);
  bcat_k<<<4, 256, 0, stream>>>(bqp, bkp, bqk);

  // fused QKV: qk[8192][1024] and vT[2][512][4096]
  qkv_k<<<dim3(12, 64, 1), 256, 0, stream>>>(hf, wqkb, wvb, bqk, bvp, qk, vT);

  // S = Q K^T * scale, both batches (fp32 [2][4096][4096])
  gemm_bt_k<2><<<dim3(32, 32, 2), 256, 0, stream>>>(
      qk, qk + 512, Sbuf, nullptr, nullptr, 512, 1024, 1024, 4096,
      0.044194173824159216f, (long)4096 * 1024, (long)4096 * 1024,
      (long)4096 * 4096, 1);

  // softmax in place: P bf16 rows (stride 8192) over S storage
  softmax_k<<<8192, 256, 0, stream>>>(Sbuf);

  // PV split-K: z=(b,ks), Kc=1024 -> partials [8][4096][512] bf16
  gemm_bt_k<3><<<dim3(4, 32, 8), 256, 0, stream>>>(
      (const __hip_bfloat16*)Sbuf, vT, part, nullptr, nullptr, 1024, 8192, 4096,
      512, 1.f, (long)4096 * 8192, (long)512 * 4096, (long)4096 * 512, 4);

  reduce_k<<<2048, 256, 0, stream>>>(part, obuf);

  // out[b][c][t] = x + Wo*O + bo   (A = Wo, m=c -> coalesced fp32 row store)
  gemm_bt_k<6><<<dim3(32, 4, 2), 256, 0, stream>>>(
      wob, obuf, outp, bop, xp, 512, 512, 512, 4096, 1.f,
      0, (long)4096 * 512, (long)512 * 4096, 1);
}

// Round 5
// 292.138 us; speedup vs baseline: 1.2153x; 1.1503x over previous
//
#include <hip/hip_runtime.h>
#include <hip/hip_bf16.h>

// Problem constants: B=2, C=512, H=W=64 -> N=4096, G=32 (16 ch/group), EPS=1e-6.

typedef float f32x4 __attribute__((ext_vector_type(4)));
typedef __bf16 bf16x8 __attribute__((ext_vector_type(8)));

typedef const __attribute__((address_space(1))) unsigned char* gas_p;
typedef __attribute__((address_space(3))) unsigned char* las_p;

__device__ __forceinline__ void gload_lds16(const void* g, void* l) {
  // async DMA: each lane contributes 16B; LDS dst = wave-uniform base + lane*16
  __builtin_amdgcn_global_load_lds((gas_p)g, (las_p)l, 16, 0, 0);
}

// ---------------- GroupNorm statistics: one block per (b,g) ----------------
__global__ __launch_bounds__(256) void gn_stats_k(const float* __restrict__ x,
                                                  float* __restrict__ stats) {
  int bg = blockIdx.x;
  const float4* p = (const float4*)(x + (size_t)bg * 65536);
  float s = 0.f, s2 = 0.f;
  for (int i = threadIdx.x; i < 16384; i += 256) {
    float4 v = p[i];
    s  += v.x + v.y + v.z + v.w;
    s2 += v.x * v.x + v.y * v.y + v.z * v.z + v.w * v.w;
  }
#pragma unroll
  for (int off = 32; off > 0; off >>= 1) {
    s  += __shfl_xor(s, off);
    s2 += __shfl_xor(s2, off);
  }
  __shared__ float rs[4], rs2[4];
  int wid = threadIdx.x >> 6, lane = threadIdx.x & 63;
  if (lane == 0) { rs[wid] = s; rs2[wid] = s2; }
  __syncthreads();
  if (threadIdx.x == 0) {
    float S  = rs[0] + rs[1] + rs[2] + rs[3];
    float S2 = rs2[0] + rs2[1] + rs2[2] + rs2[3];
    float mean = S * (1.f / 65536.f);
    float var  = S2 * (1.f / 65536.f) - mean * mean;
    stats[bg * 2]     = mean;
    stats[bg * 2 + 1] = rsqrtf(var + 1e-6f);
  }
}

// ------- GroupNorm apply + transpose [b][c][n] -> hf bf16 [b][n][c] --------
__global__ __launch_bounds__(256) void gn_apply_k(const float* __restrict__ x,
                                                  const float* __restrict__ stats,
                                                  const float* __restrict__ gw,
                                                  const float* __restrict__ gb,
                                                  __hip_bfloat16* __restrict__ hf) {
  int c0 = blockIdx.x * 64, n0 = blockIdx.y * 64, b = blockIdx.z;
  __shared__ float tile[64][65];
  int tx = threadIdx.x & 63, ty = threadIdx.x >> 6;
  const float* xb = x + ((size_t)(b * 512 + c0)) * 4096 + n0;
#pragma unroll
  for (int i = 0; i < 64; i += 4) {
    int cl = i + ty;
    int c  = c0 + cl;
    float mean = stats[(b * 32 + (c >> 4)) * 2];
    float rstd = stats[(b * 32 + (c >> 4)) * 2 + 1];
    float v = xb[(size_t)cl * 4096 + tx];
    tile[cl][tx] = (v - mean) * rstd * gw[c] + gb[c];
  }
  __syncthreads();
  __hip_bfloat16* o = hf + ((size_t)(b * 4096 + n0)) * 512 + c0;
#pragma unroll
  for (int i = 0; i < 64; i += 4) {
    int nl = i + ty;
    o[(size_t)nl * 512 + tx] = __float2bfloat16(tile[tx][nl]);
  }
}

// ---------------- fp32 -> bf16 weight conversion ----------------
__global__ __launch_bounds__(256) void cvt_k(const float* __restrict__ w,
                                             __hip_bfloat16* __restrict__ o, int n) {
  int i = blockIdx.x * 256 + threadIdx.x;
  if (i < n) o[i] = __float2bfloat16(w[i]);
}

__global__ __launch_bounds__(256) void bcat_k(const float* __restrict__ bq,
                                              const float* __restrict__ bk,
                                              float* __restrict__ bqk) {
  int i = blockIdx.x * 256 + threadIdx.x;
  if (i < 512) bqk[i] = bq[i];
  else if (i < 1024) bqk[i] = bk[i - 512];
}

// ============ fused QKV (double-buffered DMA): 768 blocks ============
// bx<8 : QK GEMM  qk[t][o] (o<1024) = sum_c hf[t][c]*Wqk[o][c] + bqk[o]
// bx>=8: V GEMM   vT[b][o][t]       = sum_c Wv[o][c]*hf[t][c] + bv[o]
__global__ __launch_bounds__(256, 4) void qkv_k(
    const __hip_bfloat16* __restrict__ hf, const __hip_bfloat16* __restrict__ wqk,
    const __hip_bfloat16* __restrict__ wv, const float* __restrict__ bqk,
    const float* __restrict__ bv, __hip_bfloat16* __restrict__ qk,
    __hip_bfloat16* __restrict__ vT) {
  bool isV = blockIdx.x >= 8;
  int m0 = isV ? (blockIdx.x - 8) * 128 : blockIdx.y * 128;
  int n0 = isV ? blockIdx.y * 128 : blockIdx.x * 128;
  const __hip_bfloat16* A  = isV ? wv : hf;   // [m][512]
  const __hip_bfloat16* Bm = isV ? hf : wqk;  // [n][512]

  __shared__ __hip_bfloat16 As[2 * 4096];
  __shared__ __hip_bfloat16 Bs[2 * 4096];

  int tid  = threadIdx.x;
  int wvx  = tid >> 6, lane = tid & 63;
  int wr   = (wvx >> 1) * 64, wc = (wvx & 1) * 64;
  int quad = lane >> 4, l16 = lane & 15;

  int srow = wvx * 32 + (lane >> 2);
  int scol = (lane & 3) * 8;
  const __hip_bfloat16* gA0 = A  + (size_t)(m0 + srow) * 512 + scol;
  const __hip_bfloat16* gA1 = gA0 + (size_t)16 * 512;
  const __hip_bfloat16* gB0 = Bm + (size_t)(n0 + srow) * 512 + scol;
  const __hip_bfloat16* gB1 = gB0 + (size_t)16 * 512;

  auto stage = [&](int kk, int bsel) {
    int lb = bsel * 4096 + wvx * 1024;
    gload_lds16(gA0 + kk, &As[lb]);
    gload_lds16(gA1 + kk, &As[lb + 512]);
    gload_lds16(gB0 + kk, &Bs[lb]);
    gload_lds16(gB1 + kk, &Bs[lb + 512]);
  };

  f32x4 acc[4][4] = {};
  stage(0, 0);
  for (int kt = 0; kt < 16; kt++) {
    __syncthreads();  // DMA(kt) visible; buf[kt^1] readers (iter kt-1) done
    if (kt + 1 < 16) stage((kt + 1) << 5, (kt + 1) & 1);
    const __hip_bfloat16* Ab = &As[(kt & 1) * 4096];
    const __hip_bfloat16* Bb = &Bs[(kt & 1) * 4096];
    bf16x8 af[4], bfr[4];
#pragma unroll
    for (int i = 0; i < 4; i++)
      af[i] = *(const bf16x8*)&Ab[(wr + i * 16 + l16) * 32 + quad * 8];
#pragma unroll
    for (int j = 0; j < 4; j++)
      bfr[j] = *(const bf16x8*)&Bb[(wc + j * 16 + l16) * 32 + quad * 8];
#pragma unroll
    for (int i = 0; i < 4; i++)
#pragma unroll
      for (int j = 0; j < 4; j++)
        acc[i][j] = __builtin_amdgcn_mfma_f32_16x16x32_bf16(af[i], bfr[j],
                                                            acc[i][j], 0, 0, 0);
  }
#pragma unroll
  for (int i = 0; i < 4; i++)
#pragma unroll
    for (int j = 0; j < 4; j++)
#pragma unroll
      for (int r = 0; r < 4; r++) {
        int m = m0 + wr + i * 16 + quad * 4 + r;
        int n = n0 + wc + j * 16 + l16;
        float v = acc[i][j][r];
        if (!isV) {
          qk[(size_t)m * 1024 + n] = __float2bfloat16(v + bqk[n]);
        } else {
          int b = n >> 12, t = n & 4095;
          vT[((size_t)(b * 512 + m)) * 4096 + t] = __float2bfloat16(v + bv[m]);
        }
      }
}

// ---------------- bf16 GEMM, B^T form, double-buffered DMA ----------------
// MODE 2: out bf16 [m][n] * scale           (QK^T -> S bf16)
// MODE 3: out bf16 [m][n], XCD-swizzled 1-D grid (PV split-K partials)
// MODE 6: out fp32 [m][n] + bias[m] + resid (out-proj)
template <int MODE>
__global__ __launch_bounds__(256, 4) void gemm_bt_k(
    const __hip_bfloat16* __restrict__ A, const __hip_bfloat16* __restrict__ Bm,
    void* __restrict__ Cout, const float* __restrict__ bias,
    const float* __restrict__ resid, int Kc, int lda, int ldb, int ldc,
    float scale, long sAz, long sBz, long sCz, int kspl) {
  int bx, by, bz;
  if (MODE == 3) {
    // 1024 blocks; co-locate the 4 n-tiles of each (m,z) group on one XCD
    int f = blockIdx.x;
    int xcd = f & 7, s = f >> 3;
    bx = s & 3;
    int g = xcd + 8 * (s >> 2);  // 0..255
    by = g & 31;
    bz = g >> 5;
  } else {
    bx = blockIdx.x; by = blockIdx.y; bz = blockIdx.z;
  }
  int bb = bz / kspl, ks = bz - bb * kspl;
  A  += (size_t)bb * sAz + (size_t)ks * Kc;
  Bm += (size_t)bb * sBz + (size_t)ks * Kc;
  size_t cbase = (size_t)bz * sCz;
  int m0 = by * 128, n0 = bx * 128;

  __shared__ __hip_bfloat16 As[2 * 4096];
  __shared__ __hip_bfloat16 Bs[2 * 4096];

  int tid  = threadIdx.x;
  int wv   = tid >> 6, lane = tid & 63;
  int wr   = (wv >> 1) * 64, wc = (wv & 1) * 64;
  int quad = lane >> 4, l16 = lane & 15;

  int srow = wv * 32 + (lane >> 2);
  int scol = (lane & 3) * 8;
  const __hip_bfloat16* gA0 = A  + (size_t)(m0 + srow) * lda + scol;
  const __hip_bfloat16* gA1 = gA0 + (size_t)16 * lda;
  const __hip_bfloat16* gB0 = Bm + (size_t)(n0 + srow) * ldb + scol;
  const __hip_bfloat16* gB1 = gB0 + (size_t)16 * ldb;

  auto stage = [&](int kk, int bsel) {
    int lb = bsel * 4096 + wv * 1024;
    gload_lds16(gA0 + kk, &As[lb]);
    gload_lds16(gA1 + kk, &As[lb + 512]);
    gload_lds16(gB0 + kk, &Bs[lb]);
    gload_lds16(gB1 + kk, &Bs[lb + 512]);
  };

  int KT = Kc >> 5;
  f32x4 acc[4][4] = {};
  stage(0, 0);
  for (int kt = 0; kt < KT; kt++) {
    __syncthreads();
    if (kt + 1 < KT) stage((kt + 1) << 5, (kt + 1) & 1);
    const __hip_bfloat16* Ab = &As[(kt & 1) * 4096];
    const __hip_bfloat16* Bb = &Bs[(kt & 1) * 4096];
    bf16x8 af[4], bfr[4];
#pragma unroll
    for (int i = 0; i < 4; i++)
      af[i] = *(const bf16x8*)&Ab[(wr + i * 16 + l16) * 32 + quad * 8];
#pragma unroll
    for (int j = 0; j < 4; j++)
      bfr[j] = *(const bf16x8*)&Bb[(wc + j * 16 + l16) * 32 + quad * 8];
#pragma unroll
    for (int i = 0; i < 4; i++)
#pragma unroll
      for (int j = 0; j < 4; j++)
        acc[i][j] = __builtin_amdgcn_mfma_f32_16x16x32_bf16(af[i], bfr[j],
                                                            acc[i][j], 0, 0, 0);
  }

  // C/D layout: col = lane&15, row = quad*4 + reg.
#pragma unroll
  for (int i = 0; i < 4; i++)
#pragma unroll
    for (int j = 0; j < 4; j++)
#pragma unroll
      for (int r = 0; r < 4; r++) {
        int m = m0 + wr + i * 16 + quad * 4 + r;
        int n = n0 + wc + j * 16 + l16;
        float v = acc[i][j][r];
        size_t idx = cbase + (size_t)m * ldc + n;
        if (MODE == 2) {
          ((__hip_bfloat16*)Cout)[idx] = __float2bfloat16(v * scale);
        } else if (MODE == 3) {
          ((__hip_bfloat16*)Cout)[idx] = __float2bfloat16(v);
        } else {  // MODE 6
          ((float*)Cout)[idx] = resid[idx] + v + bias[m];
        }
      }
}

// ------- row softmax, IN-PLACE bf16 -> bf16, row stride 4096 -------
__global__ __launch_bounds__(256) void softmax_k(__hip_bfloat16* __restrict__ S) {
  size_t row = blockIdx.x;
  bf16x8* s = (bf16x8*)(S + row * 4096);  // 512 vectors per row
  bf16x8 r0 = s[threadIdx.x];
  bf16x8 r1 = s[threadIdx.x + 256];
  float v[16];
#pragma unroll
  for (int l = 0; l < 8; l++) { v[l] = (float)r0[l]; v[8 + l] = (float)r1[l]; }
  float m = -1e30f;
#pragma unroll
  for (int i = 0; i < 16; i++) m = fmaxf(m, v[i]);
#pragma unroll
  for (int off = 32; off > 0; off >>= 1) m = fmaxf(m, __shfl_xor(m, off));
  __shared__ float red[4], red2[4];
  int wid = threadIdx.x >> 6, lane = threadIdx.x & 63;
  if (lane == 0) red[wid] = m;
  __syncthreads();
  m = fmaxf(fmaxf(red[0], red[1]), fmaxf(red[2], red[3]));
  float sum = 0.f;
#pragma unroll
  for (int i = 0; i < 16; i++) {
    v[i] = __expf(v[i] - m);
    sum += v[i];
  }
#pragma unroll
  for (int off = 32; off > 0; off >>= 1) sum += __shfl_xor(sum, off);
  if (lane == 0) red2[wid] = sum;
  __syncthreads();
  sum = red2[0] + red2[1] + red2[2] + red2[3];
  float inv = 1.f / sum;
  bf16x8 o0, o1;
#pragma unroll
  for (int l = 0; l < 8; l++) {
    o0[l] = (__bf16)(v[l] * inv);
    o1[l] = (__bf16)(v[8 + l] * inv);
  }
  s[threadIdx.x] = o0;
  s[threadIdx.x + 256] = o1;
}

// ---- reduce 4 bf16 split-K partials -> obuf bf16 [2][4096][512] ----
__global__ __launch_bounds__(256) void reduce_k(const __hip_bfloat16* __restrict__ part,
                                                __hip_bfloat16* __restrict__ obuf) {
  size_t i8 = (size_t)blockIdx.x * 256 + threadIdx.x;
  size_t perb = (size_t)4096 * 512 / 8;  // 262144
  size_t b = i8 / perb, r = i8 - b * perb;
  float acc[8] = {};
#pragma unroll
  for (int ks = 0; ks < 4; ks++) {
    bf16x8 v = ((const bf16x8*)part)[(b * 4 + ks) * perb + r];
#pragma unroll
    for (int l = 0; l < 8; l++) acc[l] += (float)v[l];
  }
  bf16x8 o;
#pragma unroll
  for (int l = 0; l < 8; l++) o[l] = (__bf16)acc[l];
  ((bf16x8*)obuf)[b * perb + r] = o;
}

extern "C" void kernel_launch(void* const* d_in, const int* in_sizes, int n_in,
                              void* d_out, int out_size, void* d_ws,
                              size_t ws_size, hipStream_t stream) {
  const float* xp  = (const float*)d_in[0];
  const float* gwp = (const float*)d_in[1];
  const float* gbp = (const float*)d_in[2];
  const float* wqp = (const float*)d_in[3];
  const float* bqp = (const float*)d_in[4];
  const float* wkp = (const float*)d_in[5];
  const float* bkp = (const float*)d_in[6];
  const float* wvp = (const float*)d_in[7];
  const float* bvp = (const float*)d_in[8];
  const float* wop = (const float*)d_in[9];
  const float* bop = (const float*)d_in[10];
  float* outp = (float*)d_out;

  char* w = (char*)d_ws;
  size_t off = 0;
  auto alloc = [&](size_t bytes) {
    void* p = w + off;
    off += (bytes + 255) & ~(size_t)255;
    return p;
  };
  float* stats         = (float*)alloc(64 * 2 * sizeof(float));
  __hip_bfloat16* hf   = (__hip_bfloat16*)alloc((size_t)2 * 4096 * 512 * 2);
  __hip_bfloat16* wqkb = (__hip_bfloat16*)alloc((size_t)1024 * 512 * 2);
  __hip_bfloat16* wvb  = (__hip_bfloat16*)alloc((size_t)512 * 512 * 2);
  __hip_bfloat16* wob  = (__hip_bfloat16*)alloc((size_t)512 * 512 * 2);
  float* bqk           = (float*)alloc(1024 * sizeof(float));
  __hip_bfloat16* qk   = (__hip_bfloat16*)alloc((size_t)2 * 4096 * 1024 * 2);
  __hip_bfloat16* vT   = (__hip_bfloat16*)alloc((size_t)2 * 512 * 4096 * 2);
  __hip_bfloat16* obuf = (__hip_bfloat16*)alloc((size_t)2 * 4096 * 512 * 2);
  __hip_bfloat16* part = (__hip_bfloat16*)alloc((size_t)8 * 4096 * 512 * 2);
  __hip_bfloat16* Sbuf = (__hip_bfloat16*)alloc((size_t)2 * 4096 * 4096 * 2);

  const int NW = 262144;             // 512*512 weight elems
  const int CVG = (NW + 255) / 256;  // 1024 blocks

  gn_stats_k<<<64, 256, 0, stream>>>(xp, stats);
  gn_apply_k<<<dim3(8, 64, 2), 256, 0, stream>>>(xp, stats, gwp, gbp, hf);
  cvt_k<<<CVG, 256, 0, stream>>>(wqp, wqkb, NW);
  cvt_k<<<CVG, 256, 0, stream>>>(wkp, wqkb + NW, NW);
  cvt_k<<<CVG, 256, 0, stream>>>(wvp, wvb, NW);
  cvt_k<<<CVG, 256, 0, stream>>>(wop, wob, NW);
  bcat_k<<<4, 256, 0, stream>>>(bqp, bkp, bqk);

  // fused QKV: qk[8192][1024] and vT[2][512][4096]
  qkv_k<<<dim3(12, 64, 1), 256, 0, stream>>>(hf, wqkb, wvb, bqk, bvp, qk, vT);

  // S = Q K^T * scale, both batches (bf16 [2][4096][4096])
  gemm_bt_k<2><<<dim3(32, 32, 2), 256, 0, stream>>>(
      qk, qk + 512, Sbuf, nullptr, nullptr, 512, 1024, 1024, 4096,
      0.044194173824159216f, (long)4096 * 1024, (long)4096 * 1024,
      (long)4096 * 4096, 1);

  // softmax in place (bf16 rows, stride 4096)
  softmax_k<<<8192, 256, 0, stream>>>(Sbuf);

  // PV split-K (XCD-swizzled 1-D grid): partials [8][4096][512] bf16
  gemm_bt_k<3><<<dim3(1024, 1, 1), 256, 0, stream>>>(
      Sbuf, vT, part, nullptr, nullptr, 1024, 4096, 4096, 512, 1.f,
      (long)4096 * 4096, (long)512 * 4096, (long)4096 * 512, 4);

  reduce_k<<<2048, 256, 0, stream>>>(part, obuf);

  // out[b][c][t] = x + Wo*O + bo   (A = Wo, m=c -> coalesced fp32 row store)
  gemm_bt_k<6><<<dim3(32, 4, 2), 256, 0, stream>>>(
      wob, obuf, outp, bop, xp, 512, 512, 512, 4096, 1.f,
      0, (long)4096 * 512, (long)512 * 4096, 1);
}

// Round 7
// 290.332 us; speedup vs baseline: 1.2229x; 1.0062x over previous
//
#include <hip/hip_runtime.h>
#include <hip/hip_bf16.h>

// Problem constants: B=2, C=512, H=W=64 -> N=4096, G=32 (16 ch/group), EPS=1e-6.

typedef float f32x4 __attribute__((ext_vector_type(4)));
typedef __bf16 bf16x8 __attribute__((ext_vector_type(8)));

typedef const __attribute__((address_space(1))) unsigned char* gas_p;
typedef __attribute__((address_space(3))) unsigned char* las_p;

__device__ __forceinline__ void gload_lds16(const void* g, void* l) {
  // async DMA: each lane contributes 16B; LDS dst = wave-uniform base + lane*16
  __builtin_amdgcn_global_load_lds((gas_p)g, (las_p)l, 16, 0, 0);
}

// ---------------- GroupNorm statistics: one block per (b,g) ----------------
__global__ __launch_bounds__(256) void gn_stats_k(const float* __restrict__ x,
                                                  float* __restrict__ stats) {
  int bg = blockIdx.x;
  const float4* p = (const float4*)(x + (size_t)bg * 65536);
  float s = 0.f, s2 = 0.f;
  for (int i = threadIdx.x; i < 16384; i += 256) {
    float4 v = p[i];
    s  += v.x + v.y + v.z + v.w;
    s2 += v.x * v.x + v.y * v.y + v.z * v.z + v.w * v.w;
  }
#pragma unroll
  for (int off = 32; off > 0; off >>= 1) {
    s  += __shfl_xor(s, off);
    s2 += __shfl_xor(s2, off);
  }
  __shared__ float rs[4], rs2[4];
  int wid = threadIdx.x >> 6, lane = threadIdx.x & 63;
  if (lane == 0) { rs[wid] = s; rs2[wid] = s2; }
  __syncthreads();
  if (threadIdx.x == 0) {
    float S  = rs[0] + rs[1] + rs[2] + rs[3];
    float S2 = rs2[0] + rs2[1] + rs2[2] + rs2[3];
    float mean = S * (1.f / 65536.f);
    float var  = S2 * (1.f / 65536.f) - mean * mean;
    stats[bg * 2]     = mean;
    stats[bg * 2 + 1] = rsqrtf(var + 1e-6f);
  }
}

// ------- GroupNorm apply + transpose [b][c][n] -> hf bf16 [b][n][c] --------
__global__ __launch_bounds__(256) void gn_apply_k(const float* __restrict__ x,
                                                  const float* __restrict__ stats,
                                                  const float* __restrict__ gw,
                                                  const float* __restrict__ gb,
                                                  __hip_bfloat16* __restrict__ hf) {
  int c0 = blockIdx.x * 64, n0 = blockIdx.y * 64, b = blockIdx.z;
  __shared__ float tile[64][65];
  int tx = threadIdx.x & 63, ty = threadIdx.x >> 6;
  const float* xb = x + ((size_t)(b * 512 + c0)) * 4096 + n0;
#pragma unroll
  for (int i = 0; i < 64; i += 4) {
    int cl = i + ty;
    int c  = c0 + cl;
    float mean = stats[(b * 32 + (c >> 4)) * 2];
    float rstd = stats[(b * 32 + (c >> 4)) * 2 + 1];
    float v = xb[(size_t)cl * 4096 + tx];
    tile[cl][tx] = (v - mean) * rstd * gw[c] + gb[c];
  }
  __syncthreads();
  __hip_bfloat16* o = hf + ((size_t)(b * 4096 + n0)) * 512 + c0;
#pragma unroll
  for (int i = 0; i < 64; i += 4) {
    int nl = i + ty;
    o[(size_t)nl * 512 + tx] = __float2bfloat16(tile[tx][nl]);
  }
}

// ---------------- fp32 -> bf16 weight conversion ----------------
__global__ __launch_bounds__(256) void cvt_k(const float* __restrict__ w,
                                             __hip_bfloat16* __restrict__ o, int n) {
  int i = blockIdx.x * 256 + threadIdx.x;
  if (i < n) o[i] = __float2bfloat16(w[i]);
}

__global__ __launch_bounds__(256) void bcat_k(const float* __restrict__ bq,
                                              const float* __restrict__ bk,
                                              float* __restrict__ bqk) {
  int i = blockIdx.x * 256 + threadIdx.x;
  if (i < 512) bqk[i] = bq[i];
  else if (i < 1024) bqk[i] = bk[i - 512];
}

__global__ __launch_bounds__(256) void zero_k(float* __restrict__ p, int n) {
  int i = blockIdx.x * 256 + threadIdx.x;
  if (i < n) p[i] = 0.f;
}

// ============ fused QKV (double-buffered DMA + LDS epilogue) ============
// bx<8 : QK GEMM  qk[t][o] (o<1024) = sum_c hf[t][c]*Wqk[o][c] + bqk[o]
// bx>=8: V GEMM   vT[b][o][t]       = sum_c Wv[o][c]*hf[t][c] + bv[o]
__global__ __launch_bounds__(256, 4) void qkv_k(
    const __hip_bfloat16* __restrict__ hf, const __hip_bfloat16* __restrict__ wqk,
    const __hip_bfloat16* __restrict__ wv, const float* __restrict__ bqk,
    const float* __restrict__ bv, __hip_bfloat16* __restrict__ qk,
    __hip_bfloat16* __restrict__ vT) {
  bool isV = blockIdx.x >= 8;
  int m0 = isV ? (blockIdx.x - 8) * 128 : blockIdx.y * 128;
  int n0 = isV ? blockIdx.y * 128 : blockIdx.x * 128;
  const __hip_bfloat16* A  = isV ? wv : hf;   // [m][512]
  const __hip_bfloat16* Bm = isV ? hf : wqk;  // [n][512]

  __shared__ __align__(16) unsigned char smem[34816];  // dbuf(32K) | epi(34K)
  __hip_bfloat16* As  = (__hip_bfloat16*)smem;
  __hip_bfloat16* Bs  = As + 8192;
  __hip_bfloat16* epi = (__hip_bfloat16*)smem;         // [128][136]

  int tid  = threadIdx.x;
  int wvx  = tid >> 6, lane = tid & 63;
  int wr   = (wvx >> 1) * 64, wc = (wvx & 1) * 64;
  int quad = lane >> 4, l16 = lane & 15;

  int srow = wvx * 32 + (lane >> 2);
  int scol = (lane & 3) * 8;
  const __hip_bfloat16* gA0 = A  + (size_t)(m0 + srow) * 512 + scol;
  const __hip_bfloat16* gA1 = gA0 + (size_t)16 * 512;
  const __hip_bfloat16* gB0 = Bm + (size_t)(n0 + srow) * 512 + scol;
  const __hip_bfloat16* gB1 = gB0 + (size_t)16 * 512;

  auto stage = [&](int kk, int bsel) {
    int lb = bsel * 4096 + wvx * 1024;
    gload_lds16(gA0 + kk, &As[lb]);
    gload_lds16(gA1 + kk, &As[lb + 512]);
    gload_lds16(gB0 + kk, &Bs[lb]);
    gload_lds16(gB1 + kk, &Bs[lb + 512]);
  };

  f32x4 acc[4][4] = {};
  stage(0, 0);
  for (int kt = 0; kt < 16; kt++) {
    __syncthreads();
    if (kt + 1 < 16) stage((kt + 1) << 5, (kt + 1) & 1);
    const __hip_bfloat16* Ab = &As[(kt & 1) * 4096];
    const __hip_bfloat16* Bb = &Bs[(kt & 1) * 4096];
    bf16x8 af[4], bfr[4];
#pragma unroll
    for (int i = 0; i < 4; i++)
      af[i] = *(const bf16x8*)&Ab[(wr + i * 16 + l16) * 32 + quad * 8];
#pragma unroll
    for (int j = 0; j < 4; j++)
      bfr[j] = *(const bf16x8*)&Bb[(wc + j * 16 + l16) * 32 + quad * 8];
#pragma unroll
    for (int i = 0; i < 4; i++)
#pragma unroll
      for (int j = 0; j < 4; j++)
        acc[i][j] = __builtin_amdgcn_mfma_f32_16x16x32_bf16(af[i], bfr[j],
                                                            acc[i][j], 0, 0, 0);
  }

  // ---- epilogue via LDS: C-layout -> row-major coalesced ----
  float bj[4], bm[4][4];
  if (!isV) {
#pragma unroll
    for (int j = 0; j < 4; j++) bj[j] = bqk[n0 + wc + j * 16 + l16];
  } else {
#pragma unroll
    for (int i = 0; i < 4; i++)
#pragma unroll
      for (int r = 0; r < 4; r++)
        bm[i][r] = bv[m0 + wr + i * 16 + quad * 4 + r];
  }
  __syncthreads();  // dbuf fragment reads done before epi overwrite
#pragma unroll
  for (int i = 0; i < 4; i++)
#pragma unroll
    for (int j = 0; j < 4; j++)
#pragma unroll
      for (int r = 0; r < 4; r++) {
        int ml = wr + i * 16 + quad * 4 + r;
        int nl = wc + j * 16 + l16;
        float v = acc[i][j][r] + (isV ? bm[i][r] : bj[j]);
        epi[ml * 136 + nl] = __float2bfloat16(v);
      }
  __syncthreads();
  int mr = tid >> 1, h = tid & 1;
  const __hip_bfloat16* rowp = &epi[mr * 136 + h * 64];
  if (!isV) {
    __hip_bfloat16* o = qk + (size_t)(m0 + mr) * 1024 + n0 + h * 64;
#pragma unroll
    for (int c = 0; c < 8; c++)
      *(uint4*)(o + c * 8) = *(const uint4*)(rowp + c * 8);
  } else {
    int b = (n0 + h * 64) >> 12, t = (n0 + h * 64) & 4095;
    __hip_bfloat16* o = vT + ((size_t)(b * 512 + m0 + mr)) * 4096 + t;
#pragma unroll
    for (int c = 0; c < 8; c++)
      *(uint4*)(o + c * 8) = *(const uint4*)(rowp + c * 8);
  }
}

// ---------------- bf16 GEMM, B^T form, dbuf DMA + LDS epilogue ----------------
// MODE 2: out bf16 expS[m][n] = exp(v*scale); atomicAdd row sums   (QK^T)
// MODE 3: out bf16 [m][n] * (1/rowsum[m]), XCD-swizzled 1-D grid   (PV partials)
// MODE 6: out fp32 [m][n] + bias[m] + resid                        (out-proj)
template <int MODE>
__global__ __launch_bounds__(256, 4) void gemm_bt_k(
    const __hip_bfloat16* __restrict__ A, const __hip_bfloat16* __restrict__ Bm,
    void* __restrict__ Cout, const float* __restrict__ bias,
    const float* __restrict__ resid, float* __restrict__ rowsum, int Kc,
    int lda, int ldb, int ldc, float scale, long sAz, long sBz, long sCz,
    int kspl) {
  int bx, by, bz;
  if (MODE == 3) {
    // 1024 blocks; co-locate the 4 n-tiles of each (m,z) group on one XCD
    int f = blockIdx.x;
    int xcd = f & 7, s = f >> 3;
    bx = s & 3;
    int g = xcd + 8 * (s >> 2);  // 0..255
    by = g & 31;
    bz = g >> 5;
  } else {
    bx = blockIdx.x; by = blockIdx.y; bz = blockIdx.z;
  }
  int bb = bz / kspl, ks = bz - bb * kspl;
  A  += (size_t)bb * sAz + (size_t)ks * Kc;
  Bm += (size_t)bb * sBz + (size_t)ks * Kc;
  size_t cbase = (size_t)bz * sCz;
  int m0 = by * 128, n0 = bx * 128;

  __shared__ __align__(16) unsigned char smem[34816];  // dbuf(32K) | epi(34K)
  __hip_bfloat16* As  = (__hip_bfloat16*)smem;
  __hip_bfloat16* Bs  = As + 8192;
  __hip_bfloat16* epi = (__hip_bfloat16*)smem;         // [128][136]

  int tid  = threadIdx.x;
  int wv   = tid >> 6, lane = tid & 63;
  int wr   = (wv >> 1) * 64, wc = (wv & 1) * 64;
  int quad = lane >> 4, l16 = lane & 15;

  int srow = wv * 32 + (lane >> 2);
  int scol = (lane & 3) * 8;
  const __hip_bfloat16* gA0 = A  + (size_t)(m0 + srow) * lda + scol;
  const __hip_bfloat16* gA1 = gA0 + (size_t)16 * lda;
  const __hip_bfloat16* gB0 = Bm + (size_t)(n0 + srow) * ldb + scol;
  const __hip_bfloat16* gB1 = gB0 + (size_t)16 * ldb;

  auto stage = [&](int kk, int bsel) {
    int lb = bsel * 4096 + wv * 1024;
    gload_lds16(gA0 + kk, &As[lb]);
    gload_lds16(gA1 + kk, &As[lb + 512]);
    gload_lds16(gB0 + kk, &Bs[lb]);
    gload_lds16(gB1 + kk, &Bs[lb + 512]);
  };

  int KT = Kc >> 5;
  f32x4 acc[4][4] = {};
  stage(0, 0);
  for (int kt = 0; kt < KT; kt++) {
    __syncthreads();
    if (kt + 1 < KT) stage((kt + 1) << 5, (kt + 1) & 1);
    const __hip_bfloat16* Ab = &As[(kt & 1) * 4096];
    const __hip_bfloat16* Bb = &Bs[(kt & 1) * 4096];
    bf16x8 af[4], bfr[4];
#pragma unroll
    for (int i = 0; i < 4; i++)
      af[i] = *(const bf16x8*)&Ab[(wr + i * 16 + l16) * 32 + quad * 8];
#pragma unroll
    for (int j = 0; j < 4; j++)
      bfr[j] = *(const bf16x8*)&Bb[(wc + j * 16 + l16) * 32 + quad * 8];
#pragma unroll
    for (int i = 0; i < 4; i++)
#pragma unroll
      for (int j = 0; j < 4; j++)
        acc[i][j] = __builtin_amdgcn_mfma_f32_16x16x32_bf16(af[i], bfr[j],
                                                            acc[i][j], 0, 0, 0);
  }

  // ---- epilogue via LDS ----
  float pre[4][4];  // per-(i,r) row factor / bias
  if (MODE == 3) {
#pragma unroll
    for (int i = 0; i < 4; i++)
#pragma unroll
      for (int r = 0; r < 4; r++)
        pre[i][r] = 1.f / rowsum[bb * 4096 + m0 + wr + i * 16 + quad * 4 + r];
  } else if (MODE == 6) {
#pragma unroll
    for (int i = 0; i < 4; i++)
#pragma unroll
      for (int r = 0; r < 4; r++)
        pre[i][r] = bias[m0 + wr + i * 16 + quad * 4 + r];
  }
  __syncthreads();  // dbuf fragment reads done before epi overwrite
#pragma unroll
  for (int i = 0; i < 4; i++)
#pragma unroll
    for (int j = 0; j < 4; j++)
#pragma unroll
      for (int r = 0; r < 4; r++) {
        int ml = wr + i * 16 + quad * 4 + r;
        int nl = wc + j * 16 + l16;
        float v = acc[i][j][r];
        if (MODE == 2) v = __expf(v * scale);
        else if (MODE == 3) v *= pre[i][r];
        else v += pre[i][r];
        epi[ml * 136 + nl] = __float2bfloat16(v);
      }
  __syncthreads();
  int mr = tid >> 1, h = tid & 1;
  const __hip_bfloat16* rowp = &epi[mr * 136 + h * 64];
  int gm = m0 + mr;
  size_t obase = cbase + (size_t)gm * ldc + n0 + h * 64;
  if (MODE == 2) {
    float s = 0.f;
    __hip_bfloat16* o = (__hip_bfloat16*)Cout + obase;
#pragma unroll
    for (int c = 0; c < 8; c++) {
      bf16x8 val = *(const bf16x8*)(rowp + c * 8);
#pragma unroll
      for (int l = 0; l < 8; l++) s += (float)val[l];
      *(uint4*)(o + c * 8) = *(const uint4*)&val;
    }
    s += __shfl_xor(s, 1);
    if (h == 0) atomicAdd(&rowsum[bb * 4096 + gm], s);
  } else if (MODE == 3) {
    __hip_bfloat16* o = (__hip_bfloat16*)Cout + obase;
#pragma unroll
    for (int c = 0; c < 8; c++)
      *(uint4*)(o + c * 8) = *(const uint4*)(rowp + c * 8);
  } else {  // MODE 6: fp32 out = bf16(v+bias) + resid
    float* o = (float*)Cout;
#pragma unroll
    for (int c = 0; c < 8; c++) {
      bf16x8 val = *(const bf16x8*)(rowp + c * 8);
      size_t idx = obase + c * 8;
      float4 r0 = *(const float4*)&resid[idx];
      float4 r1 = *(const float4*)&resid[idx + 4];
      float4 o0, o1;
      o0.x = r0.x + (float)val[0]; o0.y = r0.y + (float)val[1];
      o0.z = r0.z + (float)val[2]; o0.w = r0.w + (float)val[3];
      o1.x = r1.x + (float)val[4]; o1.y = r1.y + (float)val[5];
      o1.z = r1.z + (float)val[6]; o1.w = r1.w + (float)val[7];
      *(float4*)&o[idx] = o0;
      *(float4*)&o[idx + 4] = o1;
    }
  }
}

// ---- reduce 4 bf16 split-K partials -> obuf bf16 [2][4096][512] ----
__global__ __launch_bounds__(256) void reduce_k(const __hip_bfloat16* __restrict__ part,
                                                __hip_bfloat16* __restrict__ obuf) {
  size_t i8 = (size_t)blockIdx.x * 256 + threadIdx.x;
  size_t perb = (size_t)4096 * 512 / 8;  // 262144
  size_t b = i8 / perb, r = i8 - b * perb;
  float acc[8] = {};
#pragma unroll
  for (int ks = 0; ks < 4; ks++) {
    bf16x8 v = ((const bf16x8*)part)[(b * 4 + ks) * perb + r];
#pragma unroll
    for (int l = 0; l < 8; l++) acc[l] += (float)v[l];
  }
  bf16x8 o;
#pragma unroll
  for (int l = 0; l < 8; l++) o[l] = (__bf16)acc[l];
  ((bf16x8*)obuf)[b * perb + r] = o;
}

extern "C" void kernel_launch(void* const* d_in, const int* in_sizes, int n_in,
                              void* d_out, int out_size, void* d_ws,
                              size_t ws_size, hipStream_t stream) {
  const float* xp  = (const float*)d_in[0];
  const float* gwp = (const float*)d_in[1];
  const float* gbp = (const float*)d_in[2];
  const float* wqp = (const float*)d_in[3];
  const float* bqp = (const float*)d_in[4];
  const float* wkp = (const float*)d_in[5];
  const float* bkp = (const float*)d_in[6];
  const float* wvp = (const float*)d_in[7];
  const float* bvp = (const float*)d_in[8];
  const float* wop = (const float*)d_in[9];
  const float* bop = (const float*)d_in[10];
  float* outp = (float*)d_out;

  char* w = (char*)d_ws;
  size_t off = 0;
  auto alloc = [&](size_t bytes) {
    void* p = w + off;
    off += (bytes + 255) & ~(size_t)255;
    return p;
  };
  float* stats         = (float*)alloc(64 * 2 * sizeof(float));
  __hip_bfloat16* hf   = (__hip_bfloat16*)alloc((size_t)2 * 4096 * 512 * 2);
  __hip_bfloat16* wqkb = (__hip_bfloat16*)alloc((size_t)1024 * 512 * 2);
  __hip_bfloat16* wvb  = (__hip_bfloat16*)alloc((size_t)512 * 512 * 2);
  __hip_bfloat16* wob  = (__hip_bfloat16*)alloc((size_t)512 * 512 * 2);
  float* bqk           = (float*)alloc(1024 * sizeof(float));
  float* rowsum        = (float*)alloc(8192 * sizeof(float));
  __hip_bfloat16* qk   = (__hip_bfloat16*)alloc((size_t)2 * 4096 * 1024 * 2);
  __hip_bfloat16* vT   = (__hip_bfloat16*)alloc((size_t)2 * 512 * 4096 * 2);
  __hip_bfloat16* obuf = (__hip_bfloat16*)alloc((size_t)2 * 4096 * 512 * 2);
  __hip_bfloat16* part = (__hip_bfloat16*)alloc((size_t)8 * 4096 * 512 * 2);
  __hip_bfloat16* Sbuf = (__hip_bfloat16*)alloc((size_t)2 * 4096 * 4096 * 2);

  const int NW = 262144;             // 512*512 weight elems
  const int CVG = (NW + 255) / 256;  // 1024 blocks

  gn_stats_k<<<64, 256, 0, stream>>>(xp, stats);
  gn_apply_k<<<dim3(8, 64, 2), 256, 0, stream>>>(xp, stats, gwp, gbp, hf);
  cvt_k<<<CVG, 256, 0, stream>>>(wqp, wqkb, NW);
  cvt_k<<<CVG, 256, 0, stream>>>(wkp, wqkb + NW, NW);
  cvt_k<<<CVG, 256, 0, stream>>>(wvp, wvb, NW);
  cvt_k<<<CVG, 256, 0, stream>>>(wop, wob, NW);
  bcat_k<<<4, 256, 0, stream>>>(bqp, bkp, bqk);
  zero_k<<<32, 256, 0, stream>>>(rowsum, 8192);

  // fused QKV: qk[8192][1024] and vT[2][512][4096]
  qkv_k<<<dim3(12, 64, 1), 256, 0, stream>>>(hf, wqkb, wvb, bqk, bvp, qk, vT);

  // expS = exp(Q K^T * scale), both batches (bf16), + rowsum atomics
  gemm_bt_k<2><<<dim3(32, 32, 2), 256, 0, stream>>>(
      qk, qk + 512, Sbuf, nullptr, nullptr, rowsum, 512, 1024, 1024, 4096,
      0.044194173824159216f, (long)4096 * 1024, (long)4096 * 1024,
      (long)4096 * 4096, 1);

  // PV split-K on expS, normalized by 1/rowsum in epilogue
  gemm_bt_k<3><<<dim3(1024, 1, 1), 256, 0, stream>>>(
      Sbuf, vT, part, nullptr, nullptr, rowsum, 1024, 4096, 4096, 512, 1.f,
      (long)4096 * 4096, (long)512 * 4096, (long)4096 * 512, 4);

  reduce_k<<<2048, 256, 0, stream>>>(part, obuf);

  // out[b][c][t] = x + Wo*O + bo
  gemm_bt_k<6><<<dim3(32, 4, 2), 256, 0, stream>>>(
      wob, obuf, outp, bop, xp, nullptr, 512, 512, 512, 4096, 1.f,
      0, (long)4096 * 512, (long)512 * 4096, 1);
}

// Round 8
// 286.707 us; speedup vs baseline: 1.2384x; 1.0126x over previous
//
#include <hip/hip_runtime.h>
#include <hip/hip_bf16.h>

// Problem constants: B=2, C=512, H=W=64 -> N=4096, G=32 (16 ch/group), EPS=1e-6.

typedef float f32x4 __attribute__((ext_vector_type(4)));
typedef __bf16 bf16x8 __attribute__((ext_vector_type(8)));

typedef const __attribute__((address_space(1))) unsigned char* gas_p;
typedef __attribute__((address_space(3))) unsigned char* las_p;

__device__ __forceinline__ void gload_lds16(const void* g, void* l) {
  // async DMA: each lane contributes 16B; LDS dst = wave-uniform base + lane*16
  __builtin_amdgcn_global_load_lds((gas_p)g, (las_p)l, 16, 0, 0);
}

// ---------------- GroupNorm statistics: one block per (b,g) ----------------
__global__ __launch_bounds__(256) void gn_stats_k(const float* __restrict__ x,
                                                  float* __restrict__ stats) {
  int bg = blockIdx.x;
  const float4* p = (const float4*)(x + (size_t)bg * 65536);
  float s = 0.f, s2 = 0.f;
  for (int i = threadIdx.x; i < 16384; i += 256) {
    float4 v = p[i];
    s  += v.x + v.y + v.z + v.w;
    s2 += v.x * v.x + v.y * v.y + v.z * v.z + v.w * v.w;
  }
#pragma unroll
  for (int off = 32; off > 0; off >>= 1) {
    s  += __shfl_xor(s, off);
    s2 += __shfl_xor(s2, off);
  }
  __shared__ float rs[4], rs2[4];
  int wid = threadIdx.x >> 6, lane = threadIdx.x & 63;
  if (lane == 0) { rs[wid] = s; rs2[wid] = s2; }
  __syncthreads();
  if (threadIdx.x == 0) {
    float S  = rs[0] + rs[1] + rs[2] + rs[3];
    float S2 = rs2[0] + rs2[1] + rs2[2] + rs2[3];
    float mean = S * (1.f / 65536.f);
    float var  = S2 * (1.f / 65536.f) - mean * mean;
    stats[bg * 2]     = mean;
    stats[bg * 2 + 1] = rsqrtf(var + 1e-6f);
  }
}

// ------- GroupNorm apply + transpose [b][c][n] -> hf bf16 [b][n][c] --------
__global__ __launch_bounds__(256) void gn_apply_k(const float* __restrict__ x,
                                                  const float* __restrict__ stats,
                                                  const float* __restrict__ gw,
                                                  const float* __restrict__ gb,
                                                  __hip_bfloat16* __restrict__ hf) {
  int c0 = blockIdx.x * 64, n0 = blockIdx.y * 64, b = blockIdx.z;
  __shared__ float tile[64][65];
  int tx = threadIdx.x & 63, ty = threadIdx.x >> 6;
  const float* xb = x + ((size_t)(b * 512 + c0)) * 4096 + n0;
#pragma unroll
  for (int i = 0; i < 64; i += 4) {
    int cl = i + ty;
    int c  = c0 + cl;
    float mean = stats[(b * 32 + (c >> 4)) * 2];
    float rstd = stats[(b * 32 + (c >> 4)) * 2 + 1];
    float v = xb[(size_t)cl * 4096 + tx];
    tile[cl][tx] = (v - mean) * rstd * gw[c] + gb[c];
  }
  __syncthreads();
  __hip_bfloat16* o = hf + ((size_t)(b * 4096 + n0)) * 512 + c0;
#pragma unroll
  for (int i = 0; i < 64; i += 4) {
    int nl = i + ty;
    o[(size_t)nl * 512 + tx] = __float2bfloat16(tile[tx][nl]);
  }
}

// ---------------- fp32 -> bf16 weight conversion ----------------
__global__ __launch_bounds__(256) void cvt_k(const float* __restrict__ w,
                                             __hip_bfloat16* __restrict__ o, int n) {
  int i = blockIdx.x * 256 + threadIdx.x;
  if (i < n) o[i] = __float2bfloat16(w[i]);
}

__global__ __launch_bounds__(256) void bcat_k(const float* __restrict__ bq,
                                              const float* __restrict__ bk,
                                              float* __restrict__ bqk) {
  int i = blockIdx.x * 256 + threadIdx.x;
  if (i < 512) bqk[i] = bq[i];
  else if (i < 1024) bqk[i] = bk[i - 512];
}

// ---- fold 32 per-n-tile row-sum partials into rowsum[8192] ----
__global__ __launch_bounds__(256) void sum32_k(const float* __restrict__ psums,
                                               float* __restrict__ rowsum) {
  int i = blockIdx.x * 256 + threadIdx.x;  // 0..8191
  float s = 0.f;
#pragma unroll
  for (int j = 0; j < 32; j++) s += psums[(size_t)j * 8192 + i];
  rowsum[i] = s;
}

// ============ fused QKV (double-buffered DMA + LDS epilogue) ============
// bx<8 : QK GEMM  qk[t][o] (o<1024) = sum_c hf[t][c]*Wqk[o][c] + bqk[o]
// bx>=8: V GEMM   vT[b][o][t]       = sum_c Wv[o][c]*hf[t][c] + bv[o]
__global__ __launch_bounds__(256, 4) void qkv_k(
    const __hip_bfloat16* __restrict__ hf, const __hip_bfloat16* __restrict__ wqk,
    const __hip_bfloat16* __restrict__ wv, const float* __restrict__ bqk,
    const float* __restrict__ bv, __hip_bfloat16* __restrict__ qk,
    __hip_bfloat16* __restrict__ vT) {
  bool isV = blockIdx.x >= 8;
  int m0 = isV ? (blockIdx.x - 8) * 128 : blockIdx.y * 128;
  int n0 = isV ? blockIdx.y * 128 : blockIdx.x * 128;
  const __hip_bfloat16* A  = isV ? wv : hf;   // [m][512]
  const __hip_bfloat16* Bm = isV ? hf : wqk;  // [n][512]

  __shared__ __align__(16) unsigned char smem[34816];  // dbuf(32K) | epi(34K)
  __hip_bfloat16* As  = (__hip_bfloat16*)smem;
  __hip_bfloat16* Bs  = As + 8192;
  __hip_bfloat16* epi = (__hip_bfloat16*)smem;         // [128][136]

  int tid  = threadIdx.x;
  int wvx  = tid >> 6, lane = tid & 63;
  int wr   = (wvx >> 1) * 64, wc = (wvx & 1) * 64;
  int quad = lane >> 4, l16 = lane & 15;

  int srow = wvx * 32 + (lane >> 2);
  int scol = (lane & 3) * 8;
  const __hip_bfloat16* gA0 = A  + (size_t)(m0 + srow) * 512 + scol;
  const __hip_bfloat16* gA1 = gA0 + (size_t)16 * 512;
  const __hip_bfloat16* gB0 = Bm + (size_t)(n0 + srow) * 512 + scol;
  const __hip_bfloat16* gB1 = gB0 + (size_t)16 * 512;

  auto stage = [&](int kk, int bsel) {
    int lb = bsel * 4096 + wvx * 1024;
    gload_lds16(gA0 + kk, &As[lb]);
    gload_lds16(gA1 + kk, &As[lb + 512]);
    gload_lds16(gB0 + kk, &Bs[lb]);
    gload_lds16(gB1 + kk, &Bs[lb + 512]);
  };

  f32x4 acc[4][4] = {};
  stage(0, 0);
  for (int kt = 0; kt < 16; kt++) {
    __syncthreads();
    if (kt + 1 < 16) stage((kt + 1) << 5, (kt + 1) & 1);
    const __hip_bfloat16* Ab = &As[(kt & 1) * 4096];
    const __hip_bfloat16* Bb = &Bs[(kt & 1) * 4096];
    bf16x8 af[4], bfr[4];
#pragma unroll
    for (int i = 0; i < 4; i++)
      af[i] = *(const bf16x8*)&Ab[(wr + i * 16 + l16) * 32 + quad * 8];
#pragma unroll
    for (int j = 0; j < 4; j++)
      bfr[j] = *(const bf16x8*)&Bb[(wc + j * 16 + l16) * 32 + quad * 8];
#pragma unroll
    for (int i = 0; i < 4; i++)
#pragma unroll
      for (int j = 0; j < 4; j++)
        acc[i][j] = __builtin_amdgcn_mfma_f32_16x16x32_bf16(af[i], bfr[j],
                                                            acc[i][j], 0, 0, 0);
  }

  // ---- epilogue via LDS: C-layout -> row-major coalesced ----
  float bj[4], bm[4][4];
  if (!isV) {
#pragma unroll
    for (int j = 0; j < 4; j++) bj[j] = bqk[n0 + wc + j * 16 + l16];
  } else {
#pragma unroll
    for (int i = 0; i < 4; i++)
#pragma unroll
      for (int r = 0; r < 4; r++)
        bm[i][r] = bv[m0 + wr + i * 16 + quad * 4 + r];
  }
  __syncthreads();  // dbuf fragment reads done before epi overwrite
#pragma unroll
  for (int i = 0; i < 4; i++)
#pragma unroll
    for (int j = 0; j < 4; j++)
#pragma unroll
      for (int r = 0; r < 4; r++) {
        int ml = wr + i * 16 + quad * 4 + r;
        int nl = wc + j * 16 + l16;
        float v = acc[i][j][r] + (isV ? bm[i][r] : bj[j]);
        epi[ml * 136 + nl] = __float2bfloat16(v);
      }
  __syncthreads();
  int mr = tid >> 1, h = tid & 1;
  const __hip_bfloat16* rowp = &epi[mr * 136 + h * 64];
  if (!isV) {
    __hip_bfloat16* o = qk + (size_t)(m0 + mr) * 1024 + n0 + h * 64;
#pragma unroll
    for (int c = 0; c < 8; c++)
      *(uint4*)(o + c * 8) = *(const uint4*)(rowp + c * 8);
  } else {
    int b = (n0 + h * 64) >> 12, t = (n0 + h * 64) & 4095;
    __hip_bfloat16* o = vT + ((size_t)(b * 512 + m0 + mr)) * 4096 + t;
#pragma unroll
    for (int c = 0; c < 8; c++)
      *(uint4*)(o + c * 8) = *(const uint4*)(rowp + c * 8);
  }
}

// ---------------- bf16 GEMM, B^T form, dbuf DMA ----------------
// MODE 2: expS[m][n]=exp(v*scale) direct bf16 stores; block row-sums ->
//         psums[bx][bb*4096+m] (atomic-free; `rowsum` arg = psums here)
// MODE 3: out bf16 [m][n] * (1/rowsum[m]), XCD-swizzled 1-D grid, LDS epi
// MODE 6: out fp32 [m][n] + bias[m] + resid, LDS epi
template <int MODE>
__global__ __launch_bounds__(256, 4) void gemm_bt_k(
    const __hip_bfloat16* __restrict__ A, const __hip_bfloat16* __restrict__ Bm,
    void* __restrict__ Cout, const float* __restrict__ bias,
    const float* __restrict__ resid, float* __restrict__ rowsum, int Kc,
    int lda, int ldb, int ldc, float scale, long sAz, long sBz, long sCz,
    int kspl) {
  int bx, by, bz;
  if (MODE == 3) {
    // 1024 blocks; co-locate the 4 n-tiles of each (m,z) group on one XCD
    int f = blockIdx.x;
    int xcd = f & 7, s = f >> 3;
    bx = s & 3;
    int g = xcd + 8 * (s >> 2);  // 0..255
    by = g & 31;
    bz = g >> 5;
  } else {
    bx = blockIdx.x; by = blockIdx.y; bz = blockIdx.z;
  }
  int bb = bz / kspl, ks = bz - bb * kspl;
  A  += (size_t)bb * sAz + (size_t)ks * Kc;
  Bm += (size_t)bb * sBz + (size_t)ks * Kc;
  size_t cbase = (size_t)bz * sCz;
  int m0 = by * 128, n0 = bx * 128;

  __shared__ __align__(16) unsigned char smem[34816];  // dbuf(32K) | epi / psum2
  __hip_bfloat16* As  = (__hip_bfloat16*)smem;
  __hip_bfloat16* Bs  = As + 8192;
  __hip_bfloat16* epi = (__hip_bfloat16*)smem;         // [128][136] (MODE 3/6)
  float* psum2 = (float*)(smem + 32768);               // [2][128]   (MODE 2)

  int tid  = threadIdx.x;
  int wv   = tid >> 6, lane = tid & 63;
  int wr   = (wv >> 1) * 64, wc = (wv & 1) * 64;
  int quad = lane >> 4, l16 = lane & 15;

  int srow = wv * 32 + (lane >> 2);
  int scol = (lane & 3) * 8;
  const __hip_bfloat16* gA0 = A  + (size_t)(m0 + srow) * lda + scol;
  const __hip_bfloat16* gA1 = gA0 + (size_t)16 * lda;
  const __hip_bfloat16* gB0 = Bm + (size_t)(n0 + srow) * ldb + scol;
  const __hip_bfloat16* gB1 = gB0 + (size_t)16 * ldb;

  auto stage = [&](int kk, int bsel) {
    int lb = bsel * 4096 + wv * 1024;
    gload_lds16(gA0 + kk, &As[lb]);
    gload_lds16(gA1 + kk, &As[lb + 512]);
    gload_lds16(gB0 + kk, &Bs[lb]);
    gload_lds16(gB1 + kk, &Bs[lb + 512]);
  };

  int KT = Kc >> 5;
  f32x4 acc[4][4] = {};
  stage(0, 0);
  for (int kt = 0; kt < KT; kt++) {
    __syncthreads();
    if (kt + 1 < KT) stage((kt + 1) << 5, (kt + 1) & 1);
    const __hip_bfloat16* Ab = &As[(kt & 1) * 4096];
    const __hip_bfloat16* Bb = &Bs[(kt & 1) * 4096];
    bf16x8 af[4], bfr[4];
#pragma unroll
    for (int i = 0; i < 4; i++)
      af[i] = *(const bf16x8*)&Ab[(wr + i * 16 + l16) * 32 + quad * 8];
#pragma unroll
    for (int j = 0; j < 4; j++)
      bfr[j] = *(const bf16x8*)&Bb[(wc + j * 16 + l16) * 32 + quad * 8];
#pragma unroll
    for (int i = 0; i < 4; i++)
#pragma unroll
      for (int j = 0; j < 4; j++)
        acc[i][j] = __builtin_amdgcn_mfma_f32_16x16x32_bf16(af[i], bfr[j],
                                                            acc[i][j], 0, 0, 0);
  }

  if (MODE == 2) {
    // direct scattered stores (round-5 style) + register row-sum reduction
    float s[4][4];
#pragma unroll
    for (int i = 0; i < 4; i++)
#pragma unroll
      for (int r = 0; r < 4; r++) s[i][r] = 0.f;
    __hip_bfloat16* o = (__hip_bfloat16*)Cout;
#pragma unroll
    for (int i = 0; i < 4; i++)
#pragma unroll
      for (int j = 0; j < 4; j++)
#pragma unroll
        for (int r = 0; r < 4; r++) {
          int m = m0 + wr + i * 16 + quad * 4 + r;
          int n = n0 + wc + j * 16 + l16;
          float v = __expf(acc[i][j][r] * scale);
          o[cbase + (size_t)m * ldc + n] = __float2bfloat16(v);
          s[i][r] += v;
        }
    // reduce across the 16 l16 lanes (bits 0..3 of lane id)
#pragma unroll
    for (int off = 1; off < 16; off <<= 1)
#pragma unroll
      for (int i = 0; i < 4; i++)
#pragma unroll
        for (int r = 0; r < 4; r++) s[i][r] += __shfl_xor(s[i][r], off);
    if (l16 == 0) {
#pragma unroll
      for (int i = 0; i < 4; i++)
#pragma unroll
        for (int r = 0; r < 4; r++)
          psum2[(wv & 1) * 128 + wr + i * 16 + quad * 4 + r] = s[i][r];
    }
    __syncthreads();
    if (tid < 128) {
      float v = psum2[tid] + psum2[128 + tid];
      rowsum[(size_t)bx * 8192 + bb * 4096 + m0 + tid] = v;  // psums slot
    }
    return;
  }

  // ---- MODE 3 / 6: epilogue via LDS ----
  float pre[4][4];
  if (MODE == 3) {
#pragma unroll
    for (int i = 0; i < 4; i++)
#pragma unroll
      for (int r = 0; r < 4; r++)
        pre[i][r] = 1.f / rowsum[bb * 4096 + m0 + wr + i * 16 + quad * 4 + r];
  } else {
#pragma unroll
    for (int i = 0; i < 4; i++)
#pragma unroll
      for (int r = 0; r < 4; r++)
        pre[i][r] = bias[m0 + wr + i * 16 + quad * 4 + r];
  }
  __syncthreads();  // dbuf fragment reads done before epi overwrite
#pragma unroll
  for (int i = 0; i < 4; i++)
#pragma unroll
    for (int j = 0; j < 4; j++)
#pragma unroll
      for (int r = 0; r < 4; r++) {
        int ml = wr + i * 16 + quad * 4 + r;
        int nl = wc + j * 16 + l16;
        float v = acc[i][j][r];
        if (MODE == 3) v *= pre[i][r];
        else v += pre[i][r];
        epi[ml * 136 + nl] = __float2bfloat16(v);
      }
  __syncthreads();
  int mr = tid >> 1, h = tid & 1;
  const __hip_bfloat16* rowp = &epi[mr * 136 + h * 64];
  size_t obase = cbase + (size_t)(m0 + mr) * ldc + n0 + h * 64;
  if (MODE == 3) {
    __hip_bfloat16* o = (__hip_bfloat16*)Cout + obase;
#pragma unroll
    for (int c = 0; c < 8; c++)
      *(uint4*)(o + c * 8) = *(const uint4*)(rowp + c * 8);
  } else {  // MODE 6: fp32 out = bf16(v+bias) + resid
    float* o = (float*)Cout;
#pragma unroll
    for (int c = 0; c < 8; c++) {
      bf16x8 val = *(const bf16x8*)(rowp + c * 8);
      size_t idx = obase + c * 8;
      float4 r0 = *(const float4*)&resid[idx];
      float4 r1 = *(const float4*)&resid[idx + 4];
      float4 o0, o1;
      o0.x = r0.x + (float)val[0]; o0.y = r0.y + (float)val[1];
      o0.z = r0.z + (float)val[2]; o0.w = r0.w + (float)val[3];
      o1.x = r1.x + (float)val[4]; o1.y = r1.y + (float)val[5];
      o1.z = r1.z + (float)val[6]; o1.w = r1.w + (float)val[7];
      *(float4*)&o[idx] = o0;
      *(float4*)&o[idx + 4] = o1;
    }
  }
}

// ---- reduce 4 bf16 split-K partials -> obuf bf16 [2][4096][512] ----
__global__ __launch_bounds__(256) void reduce_k(const __hip_bfloat16* __restrict__ part,
                                                __hip_bfloat16* __restrict__ obuf) {
  size_t i8 = (size_t)blockIdx.x * 256 + threadIdx.x;
  size_t perb = (size_t)4096 * 512 / 8;  // 262144
  size_t b = i8 / perb, r = i8 - b * perb;
  float acc[8] = {};
#pragma unroll
  for (int ks = 0; ks < 4; ks++) {
    bf16x8 v = ((const bf16x8*)part)[(b * 4 + ks) * perb + r];
#pragma unroll
    for (int l = 0; l < 8; l++) acc[l] += (float)v[l];
  }
  bf16x8 o;
#pragma unroll
  for (int l = 0; l < 8; l++) o[l] = (__bf16)acc[l];
  ((bf16x8*)obuf)[b * perb + r] = o;
}

extern "C" void kernel_launch(void* const* d_in, const int* in_sizes, int n_in,
                              void* d_out, int out_size, void* d_ws,
                              size_t ws_size, hipStream_t stream) {
  const float* xp  = (const float*)d_in[0];
  const float* gwp = (const float*)d_in[1];
  const float* gbp = (const float*)d_in[2];
  const float* wqp = (const float*)d_in[3];
  const float* bqp = (const float*)d_in[4];
  const float* wkp = (const float*)d_in[5];
  const float* bkp = (const float*)d_in[6];
  const float* wvp = (const float*)d_in[7];
  const float* bvp = (const float*)d_in[8];
  const float* wop = (const float*)d_in[9];
  const float* bop = (const float*)d_in[10];
  float* outp = (float*)d_out;

  char* w = (char*)d_ws;
  size_t off = 0;
  auto alloc = [&](size_t bytes) {
    void* p = w + off;
    off += (bytes + 255) & ~(size_t)255;
    return p;
  };
  float* stats         = (float*)alloc(64 * 2 * sizeof(float));
  __hip_bfloat16* hf   = (__hip_bfloat16*)alloc((size_t)2 * 4096 * 512 * 2);
  __hip_bfloat16* wqkb = (__hip_bfloat16*)alloc((size_t)1024 * 512 * 2);
  __hip_bfloat16* wvb  = (__hip_bfloat16*)alloc((size_t)512 * 512 * 2);
  __hip_bfloat16* wob  = (__hip_bfloat16*)alloc((size_t)512 * 512 * 2);
  float* bqk           = (float*)alloc(1024 * sizeof(float));
  float* rowsum        = (float*)alloc(8192 * sizeof(float));
  float* psums         = (float*)alloc((size_t)32 * 8192 * sizeof(float));
  __hip_bfloat16* qk   = (__hip_bfloat16*)alloc((size_t)2 * 4096 * 1024 * 2);
  __hip_bfloat16* vT   = (__hip_bfloat16*)alloc((size_t)2 * 512 * 4096 * 2);
  __hip_bfloat16* obuf = (__hip_bfloat16*)alloc((size_t)2 * 4096 * 512 * 2);
  __hip_bfloat16* part = (__hip_bfloat16*)alloc((size_t)8 * 4096 * 512 * 2);
  __hip_bfloat16* Sbuf = (__hip_bfloat16*)alloc((size_t)2 * 4096 * 4096 * 2);

  const int NW = 262144;             // 512*512 weight elems
  const int CVG = (NW + 255) / 256;  // 1024 blocks

  gn_stats_k<<<64, 256, 0, stream>>>(xp, stats);
  gn_apply_k<<<dim3(8, 64, 2), 256, 0, stream>>>(xp, stats, gwp, gbp, hf);
  cvt_k<<<CVG, 256, 0, stream>>>(wqp, wqkb, NW);
  cvt_k<<<CVG, 256, 0, stream>>>(wkp, wqkb + NW, NW);
  cvt_k<<<CVG, 256, 0, stream>>>(wvp, wvb, NW);
  cvt_k<<<CVG, 256, 0, stream>>>(wop, wob, NW);
  bcat_k<<<4, 256, 0, stream>>>(bqp, bkp, bqk);

  // fused QKV: qk[8192][1024] and vT[2][512][4096]
  qkv_k<<<dim3(12, 64, 1), 256, 0, stream>>>(hf, wqkb, wvb, bqk, bvp, qk, vT);

  // expS = exp(Q K^T * scale), both batches (bf16) + per-n-tile row sums
  gemm_bt_k<2><<<dim3(32, 32, 2), 256, 0, stream>>>(
      qk, qk + 512, Sbuf, nullptr, nullptr, psums, 512, 1024, 1024, 4096,
      0.044194173824159216f, (long)4096 * 1024, (long)4096 * 1024,
      (long)4096 * 4096, 1);

  // fold 32 partial sums -> rowsum[8192]
  sum32_k<<<32, 256, 0, stream>>>(psums, rowsum);

  // PV split-K on expS, normalized by 1/rowsum in epilogue
  gemm_bt_k<3><<<dim3(1024, 1, 1), 256, 0, stream>>>(
      Sbuf, vT, part, nullptr, nullptr, rowsum, 1024, 4096, 4096, 512, 1.f,
      (long)4096 * 4096, (long)512 * 4096, (long)4096 * 512, 4);

  reduce_k<<<2048, 256, 0, stream>>>(part, obuf);

  // out[b][c][t] = x + Wo*O + bo
  gemm_bt_k<6><<<dim3(32, 4, 2), 256, 0, stream>>>(
      wob, obuf, outp, bop, xp, nullptr, 512, 512, 512, 4096, 1.f,
      0, (long)4096 * 512, (long)512 * 4096, 1);
}

// Round 9
// 270.014 us; speedup vs baseline: 1.3149x; 1.0618x over previous
//
#include <hip/hip_runtime.h>
#include <hip/hip_bf16.h>

// Problem constants: B=2, C=512, H=W=64 -> N=4096, G=32 (16 ch/group), EPS=1e-6.

typedef float f32x4 __attribute__((ext_vector_type(4)));
typedef __bf16 bf16x8 __attribute__((ext_vector_type(8)));

typedef const __attribute__((address_space(1))) unsigned char* gas_p;
typedef __attribute__((address_space(3))) unsigned char* las_p;

__device__ __forceinline__ void gload_lds16(const void* g, void* l) {
  // async DMA: each lane contributes 16B; LDS dst = wave-uniform base + lane*16
  __builtin_amdgcn_global_load_lds((gas_p)g, (las_p)l, 16, 0, 0);
}

// ====== prelude: weight cvt (4x1024 blocks) | gn_stats (64) | bcat (1) ======
__global__ __launch_bounds__(256) void prelude_k(
    const float* __restrict__ wq, const float* __restrict__ wk,
    const float* __restrict__ wv, const float* __restrict__ wo,
    __hip_bfloat16* __restrict__ wqkb, __hip_bfloat16* __restrict__ wvb,
    __hip_bfloat16* __restrict__ wob, const float* __restrict__ bq,
    const float* __restrict__ bk, float* __restrict__ bqk,
    const float* __restrict__ x, float* __restrict__ stats) {
  int bid = blockIdx.x;
  if (bid < 4096) {
    const float* src;
    __hip_bfloat16* dst;
    if (bid < 1024)      { src = wq; dst = wqkb; }
    else if (bid < 2048) { src = wk; dst = wqkb + 262144; }
    else if (bid < 3072) { src = wv; dst = wvb; }
    else                 { src = wo; dst = wob; }
    int i = (bid & 1023) * 256 + threadIdx.x;  // 1024*256 = 262144 = 512*512
    dst[i] = __float2bfloat16(src[i]);
    return;
  }
  if (bid < 4160) {  // gn_stats: one block per (b,g)
    int bg = bid - 4096;
    const float4* p = (const float4*)(x + (size_t)bg * 65536);
    float s = 0.f, s2 = 0.f;
    for (int i = threadIdx.x; i < 16384; i += 256) {
      float4 v = p[i];
      s  += v.x + v.y + v.z + v.w;
      s2 += v.x * v.x + v.y * v.y + v.z * v.z + v.w * v.w;
    }
#pragma unroll
    for (int off = 32; off > 0; off >>= 1) {
      s  += __shfl_xor(s, off);
      s2 += __shfl_xor(s2, off);
    }
    __shared__ float rs[4], rs2[4];
    int wid = threadIdx.x >> 6, lane = threadIdx.x & 63;
    if (lane == 0) { rs[wid] = s; rs2[wid] = s2; }
    __syncthreads();
    if (threadIdx.x == 0) {
      float S  = rs[0] + rs[1] + rs[2] + rs[3];
      float S2 = rs2[0] + rs2[1] + rs2[2] + rs2[3];
      float mean = S * (1.f / 65536.f);
      float var  = S2 * (1.f / 65536.f) - mean * mean;
      stats[bg * 2]     = mean;
      stats[bg * 2 + 1] = rsqrtf(var + 1e-6f);
    }
    return;
  }
  // bcat
  for (int j = threadIdx.x; j < 1024; j += 256)
    bqk[j] = (j < 512) ? bq[j] : bk[j - 512];
}

// ------- GroupNorm apply + transpose [b][c][n] -> hf bf16 [b][n][c] --------
__global__ __launch_bounds__(256) void gn_apply_k(const float* __restrict__ x,
                                                  const float* __restrict__ stats,
                                                  const float* __restrict__ gw,
                                                  const float* __restrict__ gb,
                                                  __hip_bfloat16* __restrict__ hf) {
  int c0 = blockIdx.x * 64, n0 = blockIdx.y * 64, b = blockIdx.z;
  __shared__ float tile[64][65];
  int tx = threadIdx.x & 63, ty = threadIdx.x >> 6;
  const float* xb = x + ((size_t)(b * 512 + c0)) * 4096 + n0;
#pragma unroll
  for (int i = 0; i < 64; i += 4) {
    int cl = i + ty;
    int c  = c0 + cl;
    float mean = stats[(b * 32 + (c >> 4)) * 2];
    float rstd = stats[(b * 32 + (c >> 4)) * 2 + 1];
    float v = xb[(size_t)cl * 4096 + tx];
    tile[cl][tx] = (v - mean) * rstd * gw[c] + gb[c];
  }
  __syncthreads();
  __hip_bfloat16* o = hf + ((size_t)(b * 4096 + n0)) * 512 + c0;
#pragma unroll
  for (int i = 0; i < 64; i += 4) {
    int nl = i + ty;
    o[(size_t)nl * 512 + tx] = __float2bfloat16(tile[tx][nl]);
  }
}

// ---- fold 32 per-n-tile row-sum partials into rowsum[8192] ----
__global__ __launch_bounds__(256) void sum32_k(const float* __restrict__ psums,
                                               float* __restrict__ rowsum) {
  int i = blockIdx.x * 256 + threadIdx.x;  // 0..8191
  float s = 0.f;
#pragma unroll
  for (int j = 0; j < 32; j++) s += psums[(size_t)j * 8192 + i];
  rowsum[i] = s;
}

// ============ fused QKV (double-buffered DMA + LDS epilogue) ============
// bx<8 : QK GEMM  qk[t][o] (o<1024) = sum_c hf[t][c]*Wqk[o][c] + bqk[o]
// bx>=8: V GEMM   vT[b][o][t]       = sum_c Wv[o][c]*hf[t][c] + bv[o]
__global__ __launch_bounds__(256, 4) void qkv_k(
    const __hip_bfloat16* __restrict__ hf, const __hip_bfloat16* __restrict__ wqk,
    const __hip_bfloat16* __restrict__ wv, const float* __restrict__ bqk,
    const float* __restrict__ bv, __hip_bfloat16* __restrict__ qk,
    __hip_bfloat16* __restrict__ vT) {
  bool isV = blockIdx.x >= 8;
  int m0 = isV ? (blockIdx.x - 8) * 128 : blockIdx.y * 128;
  int n0 = isV ? blockIdx.y * 128 : blockIdx.x * 128;
  const __hip_bfloat16* A  = isV ? wv : hf;   // [m][512]
  const __hip_bfloat16* Bm = isV ? hf : wqk;  // [n][512]

  __shared__ __align__(16) unsigned char smem[34816];  // dbuf(32K) | epi(34K)
  __hip_bfloat16* As  = (__hip_bfloat16*)smem;
  __hip_bfloat16* Bs  = As + 8192;
  __hip_bfloat16* epi = (__hip_bfloat16*)smem;         // [128][136]

  int tid  = threadIdx.x;
  int wvx  = tid >> 6, lane = tid & 63;
  int wr   = (wvx >> 1) * 64, wc = (wvx & 1) * 64;
  int quad = lane >> 4, l16 = lane & 15;

  int srow = wvx * 32 + (lane >> 2);
  int scol = (lane & 3) * 8;
  const __hip_bfloat16* gA0 = A  + (size_t)(m0 + srow) * 512 + scol;
  const __hip_bfloat16* gA1 = gA0 + (size_t)16 * 512;
  const __hip_bfloat16* gB0 = Bm + (size_t)(n0 + srow) * 512 + scol;
  const __hip_bfloat16* gB1 = gB0 + (size_t)16 * 512;

  auto stage = [&](int kk, int bsel) {
    int lb = bsel * 4096 + wvx * 1024;
    gload_lds16(gA0 + kk, &As[lb]);
    gload_lds16(gA1 + kk, &As[lb + 512]);
    gload_lds16(gB0 + kk, &Bs[lb]);
    gload_lds16(gB1 + kk, &Bs[lb + 512]);
  };

  f32x4 acc[4][4] = {};
  stage(0, 0);
  for (int kt = 0; kt < 16; kt++) {
    __syncthreads();
    if (kt + 1 < 16) stage((kt + 1) << 5, (kt + 1) & 1);
    const __hip_bfloat16* Ab = &As[(kt & 1) * 4096];
    const __hip_bfloat16* Bb = &Bs[(kt & 1) * 4096];
    bf16x8 af[4], bfr[4];
#pragma unroll
    for (int i = 0; i < 4; i++)
      af[i] = *(const bf16x8*)&Ab[(wr + i * 16 + l16) * 32 + quad * 8];
#pragma unroll
    for (int j = 0; j < 4; j++)
      bfr[j] = *(const bf16x8*)&Bb[(wc + j * 16 + l16) * 32 + quad * 8];
#pragma unroll
    for (int i = 0; i < 4; i++)
#pragma unroll
      for (int j = 0; j < 4; j++)
        acc[i][j] = __builtin_amdgcn_mfma_f32_16x16x32_bf16(af[i], bfr[j],
                                                            acc[i][j], 0, 0, 0);
  }

  // ---- epilogue via LDS: C-layout -> row-major coalesced ----
  float bj[4], bm[4][4];
  if (!isV) {
#pragma unroll
    for (int j = 0; j < 4; j++) bj[j] = bqk[n0 + wc + j * 16 + l16];
  } else {
#pragma unroll
    for (int i = 0; i < 4; i++)
#pragma unroll
      for (int r = 0; r < 4; r++)
        bm[i][r] = bv[m0 + wr + i * 16 + quad * 4 + r];
  }
  __syncthreads();  // dbuf fragment reads done before epi overwrite
#pragma unroll
  for (int i = 0; i < 4; i++)
#pragma unroll
    for (int j = 0; j < 4; j++)
#pragma unroll
      for (int r = 0; r < 4; r++) {
        int ml = wr + i * 16 + quad * 4 + r;
        int nl = wc + j * 16 + l16;
        float v = acc[i][j][r] + (isV ? bm[i][r] : bj[j]);
        epi[ml * 136 + nl] = __float2bfloat16(v);
      }
  __syncthreads();
  int mr = tid >> 1, h = tid & 1;
  const __hip_bfloat16* rowp = &epi[mr * 136 + h * 64];
  if (!isV) {
    __hip_bfloat16* o = qk + (size_t)(m0 + mr) * 1024 + n0 + h * 64;
#pragma unroll
    for (int c = 0; c < 8; c++)
      *(uint4*)(o + c * 8) = *(const uint4*)(rowp + c * 8);
  } else {
    int b = (n0 + h * 64) >> 12, t = (n0 + h * 64) & 4095;
    __hip_bfloat16* o = vT + ((size_t)(b * 512 + m0 + mr)) * 4096 + t;
#pragma unroll
    for (int c = 0; c < 8; c++)
      *(uint4*)(o + c * 8) = *(const uint4*)(rowp + c * 8);
  }
}

// ---------------- bf16 GEMM, B^T form, dbuf DMA ----------------
// MODE 2: expS[m][n]=exp(v*scale) direct bf16 stores; block row-sums ->
//         psums[bx][bb*4096+m] (atomic-free; `rowsum` arg = psums here)
// MODE 3: out bf16 raw [m][n] partials, XCD-swizzled 1-D grid, LDS epi
// MODE 6: out fp32 [m][n] + bias[m] + resid, LDS epi
template <int MODE>
__global__ __launch_bounds__(256, 4) void gemm_bt_k(
    const __hip_bfloat16* __restrict__ A, const __hip_bfloat16* __restrict__ Bm,
    void* __restrict__ Cout, const float* __restrict__ bias,
    const float* __restrict__ resid, float* __restrict__ rowsum, int Kc,
    int lda, int ldb, int ldc, float scale, long sAz, long sBz, long sCz,
    int kspl) {
  int bx, by, bz;
  if (MODE == 3) {
    // co-locate the 4 n-tiles of each (m,z) group on one XCD
    int f = blockIdx.x;
    int xcd = f & 7, s = f >> 3;
    bx = s & 3;
    int g = xcd + 8 * (s >> 2);
    by = g & 31;
    bz = g >> 5;
  } else {
    bx = blockIdx.x; by = blockIdx.y; bz = blockIdx.z;
  }
  int bb = bz / kspl, ks = bz - bb * kspl;
  A  += (size_t)bb * sAz + (size_t)ks * Kc;
  Bm += (size_t)bb * sBz + (size_t)ks * Kc;
  size_t cbase = (size_t)bz * sCz;
  int m0 = by * 128, n0 = bx * 128;

  __shared__ __align__(16) unsigned char smem[34816];  // dbuf(32K) | epi / psum2
  __hip_bfloat16* As  = (__hip_bfloat16*)smem;
  __hip_bfloat16* Bs  = As + 8192;
  __hip_bfloat16* epi = (__hip_bfloat16*)smem;         // [128][136] (MODE 3/6)
  float* psum2 = (float*)(smem + 32768);               // [2][128]   (MODE 2)

  int tid  = threadIdx.x;
  int wv   = tid >> 6, lane = tid & 63;
  int wr   = (wv >> 1) * 64, wc = (wv & 1) * 64;
  int quad = lane >> 4, l16 = lane & 15;

  int srow = wv * 32 + (lane >> 2);
  int scol = (lane & 3) * 8;
  const __hip_bfloat16* gA0 = A  + (size_t)(m0 + srow) * lda + scol;
  const __hip_bfloat16* gA1 = gA0 + (size_t)16 * lda;
  const __hip_bfloat16* gB0 = Bm + (size_t)(n0 + srow) * ldb + scol;
  const __hip_bfloat16* gB1 = gB0 + (size_t)16 * ldb;

  auto stage = [&](int kk, int bsel) {
    int lb = bsel * 4096 + wv * 1024;
    gload_lds16(gA0 + kk, &As[lb]);
    gload_lds16(gA1 + kk, &As[lb + 512]);
    gload_lds16(gB0 + kk, &Bs[lb]);
    gload_lds16(gB1 + kk, &Bs[lb + 512]);
  };

  int KT = Kc >> 5;
  f32x4 acc[4][4] = {};
  stage(0, 0);
  for (int kt = 0; kt < KT; kt++) {
    __syncthreads();
    if (kt + 1 < KT) stage((kt + 1) << 5, (kt + 1) & 1);
    const __hip_bfloat16* Ab = &As[(kt & 1) * 4096];
    const __hip_bfloat16* Bb = &Bs[(kt & 1) * 4096];
    bf16x8 af[4], bfr[4];
#pragma unroll
    for (int i = 0; i < 4; i++)
      af[i] = *(const bf16x8*)&Ab[(wr + i * 16 + l16) * 32 + quad * 8];
#pragma unroll
    for (int j = 0; j < 4; j++)
      bfr[j] = *(const bf16x8*)&Bb[(wc + j * 16 + l16) * 32 + quad * 8];
#pragma unroll
    for (int i = 0; i < 4; i++)
#pragma unroll
      for (int j = 0; j < 4; j++)
        acc[i][j] = __builtin_amdgcn_mfma_f32_16x16x32_bf16(af[i], bfr[j],
                                                            acc[i][j], 0, 0, 0);
  }

  if (MODE == 2) {
    // direct scattered stores + register row-sum reduction (atomic-free)
    float s[4][4];
#pragma unroll
    for (int i = 0; i < 4; i++)
#pragma unroll
      for (int r = 0; r < 4; r++) s[i][r] = 0.f;
    __hip_bfloat16* o = (__hip_bfloat16*)Cout;
#pragma unroll
    for (int i = 0; i < 4; i++)
#pragma unroll
      for (int j = 0; j < 4; j++)
#pragma unroll
        for (int r = 0; r < 4; r++) {
          int m = m0 + wr + i * 16 + quad * 4 + r;
          int n = n0 + wc + j * 16 + l16;
          float v = __expf(acc[i][j][r] * scale);
          o[cbase + (size_t)m * ldc + n] = __float2bfloat16(v);
          s[i][r] += v;
        }
#pragma unroll
    for (int off = 1; off < 16; off <<= 1)
#pragma unroll
      for (int i = 0; i < 4; i++)
#pragma unroll
        for (int r = 0; r < 4; r++) s[i][r] += __shfl_xor(s[i][r], off);
    if (l16 == 0) {
#pragma unroll
      for (int i = 0; i < 4; i++)
#pragma unroll
        for (int r = 0; r < 4; r++)
          psum2[(wv & 1) * 128 + wr + i * 16 + quad * 4 + r] = s[i][r];
    }
    __syncthreads();
    if (tid < 128) {
      float v = psum2[tid] + psum2[128 + tid];
      rowsum[(size_t)bx * 8192 + bb * 4096 + m0 + tid] = v;  // psums slot
    }
    return;
  }

  // ---- MODE 3 / 6: epilogue via LDS ----
  float pre[4][4];
  if (MODE == 6) {
#pragma unroll
    for (int i = 0; i < 4; i++)
#pragma unroll
      for (int r = 0; r < 4; r++)
        pre[i][r] = bias[m0 + wr + i * 16 + quad * 4 + r];
  }
  __syncthreads();  // dbuf fragment reads done before epi overwrite
#pragma unroll
  for (int i = 0; i < 4; i++)
#pragma unroll
    for (int j = 0; j < 4; j++)
#pragma unroll
      for (int r = 0; r < 4; r++) {
        int ml = wr + i * 16 + quad * 4 + r;
        int nl = wc + j * 16 + l16;
        float v = acc[i][j][r];
        if (MODE == 6) v += pre[i][r];
        epi[ml * 136 + nl] = __float2bfloat16(v);
      }
  __syncthreads();
  int mr = tid >> 1, h = tid & 1;
  const __hip_bfloat16* rowp = &epi[mr * 136 + h * 64];
  size_t obase = cbase + (size_t)(m0 + mr) * ldc + n0 + h * 64;
  if (MODE == 3) {
    __hip_bfloat16* o = (__hip_bfloat16*)Cout + obase;
#pragma unroll
    for (int c = 0; c < 8; c++)
      *(uint4*)(o + c * 8) = *(const uint4*)(rowp + c * 8);
  } else {  // MODE 6: fp32 out = bf16(v+bias) + resid
    float* o = (float*)Cout;
#pragma unroll
    for (int c = 0; c < 8; c++) {
      bf16x8 val = *(const bf16x8*)(rowp + c * 8);
      size_t idx = obase + c * 8;
      float4 r0 = *(const float4*)&resid[idx];
      float4 r1 = *(const float4*)&resid[idx + 4];
      float4 o0, o1;
      o0.x = r0.x + (float)val[0]; o0.y = r0.y + (float)val[1];
      o0.z = r0.z + (float)val[2]; o0.w = r0.w + (float)val[3];
      o1.x = r1.x + (float)val[4]; o1.y = r1.y + (float)val[5];
      o1.z = r1.z + (float)val[6]; o1.w = r1.w + (float)val[7];
      *(float4*)&o[idx] = o0;
      *(float4*)&o[idx + 4] = o1;
    }
  }
}

// ---- reduce 2 bf16 split-K partials, normalize by 1/rowsum -> obuf bf16 ----
__global__ __launch_bounds__(256) void reduce_k(const __hip_bfloat16* __restrict__ part,
                                                const float* __restrict__ rowsum,
                                                __hip_bfloat16* __restrict__ obuf) {
  size_t i8 = (size_t)blockIdx.x * 256 + threadIdx.x;
  size_t perb = (size_t)4096 * 512 / 8;  // 262144 vectors per batch
  size_t b = i8 / perb, r = i8 - b * perb;
  float inv = 1.f / rowsum[b * 4096 + (r >> 6)];  // t = r*8/512
  float acc[8] = {};
#pragma unroll
  for (int ks = 0; ks < 2; ks++) {
    bf16x8 v = ((const bf16x8*)part)[(b * 2 + ks) * perb + r];
#pragma unroll
    for (int l = 0; l < 8; l++) acc[l] += (float)v[l];
  }
  bf16x8 o;
#pragma unroll
  for (int l = 0; l < 8; l++) o[l] = (__bf16)(acc[l] * inv);
  ((bf16x8*)obuf)[b * perb + r] = o;
}

extern "C" void kernel_launch(void* const* d_in, const int* in_sizes, int n_in,
                              void* d_out, int out_size, void* d_ws,
                              size_t ws_size, hipStream_t stream) {
  const float* xp  = (const float*)d_in[0];
  const float* gwp = (const float*)d_in[1];
  const float* gbp = (const float*)d_in[2];
  const float* wqp = (const float*)d_in[3];
  const float* bqp = (const float*)d_in[4];
  const float* wkp = (const float*)d_in[5];
  const float* bkp = (const float*)d_in[6];
  const float* wvp = (const float*)d_in[7];
  const float* bvp = (const float*)d_in[8];
  const float* wop = (const float*)d_in[9];
  const float* bop = (const float*)d_in[10];
  float* outp = (float*)d_out;

  char* w = (char*)d_ws;
  size_t off = 0;
  auto alloc = [&](size_t bytes) {
    void* p = w + off;
    off += (bytes + 255) & ~(size_t)255;
    return p;
  };
  float* stats         = (float*)alloc(64 * 2 * sizeof(float));
  __hip_bfloat16* hf   = (__hip_bfloat16*)alloc((size_t)2 * 4096 * 512 * 2);
  __hip_bfloat16* wqkb = (__hip_bfloat16*)alloc((size_t)1024 * 512 * 2);
  __hip_bfloat16* wvb  = (__hip_bfloat16*)alloc((size_t)512 * 512 * 2);
  __hip_bfloat16* wob  = (__hip_bfloat16*)alloc((size_t)512 * 512 * 2);
  float* bqk           = (float*)alloc(1024 * sizeof(float));
  float* rowsum        = (float*)alloc(8192 * sizeof(float));
  float* psums         = (float*)alloc((size_t)32 * 8192 * sizeof(float));
  __hip_bfloat16* qk   = (__hip_bfloat16*)alloc((size_t)2 * 4096 * 1024 * 2);
  __hip_bfloat16* vT   = (__hip_bfloat16*)alloc((size_t)2 * 512 * 4096 * 2);
  __hip_bfloat16* obuf = (__hip_bfloat16*)alloc((size_t)2 * 4096 * 512 * 2);
  __hip_bfloat16* part = (__hip_bfloat16*)alloc((size_t)4 * 4096 * 512 * 2);
  __hip_bfloat16* Sbuf = (__hip_bfloat16*)alloc((size_t)2 * 4096 * 4096 * 2);

  // prelude: 4096 cvt blocks + 64 gn_stats blocks + 1 bcat block
  prelude_k<<<4161, 256, 0, stream>>>(wqp, wkp, wvp, wop, wqkb, wvb, wob,
                                      bqp, bkp, bqk, xp, stats);

  gn_apply_k<<<dim3(8, 64, 2), 256, 0, stream>>>(xp, stats, gwp, gbp, hf);

  // fused QKV: qk[8192][1024] and vT[2][512][4096]
  qkv_k<<<dim3(12, 64, 1), 256, 0, stream>>>(hf, wqkb, wvb, bqk, bvp, qk, vT);

  // expS = exp(Q K^T * scale), both batches (bf16) + per-n-tile row sums
  gemm_bt_k<2><<<dim3(32, 32, 2), 256, 0, stream>>>(
      qk, qk + 512, Sbuf, nullptr, nullptr, psums, 512, 1024, 1024, 4096,
      0.044194173824159216f, (long)4096 * 1024, (long)4096 * 1024,
      (long)4096 * 4096, 1);

  // fold 32 partial sums -> rowsum[8192]
  sum32_k<<<32, 256, 0, stream>>>(psums, rowsum);

  // PV split-K (kspl=2, Kc=2048, XCD-swizzled 512-block grid):
  // raw partials [4][4096][512] bf16
  gemm_bt_k<3><<<dim3(512, 1, 1), 256, 0, stream>>>(
      Sbuf, vT, part, nullptr, nullptr, nullptr, 2048, 4096, 4096, 512, 1.f,
      (long)4096 * 4096, (long)512 * 4096, (long)4096 * 512, 2);

  // sum partials + normalize by 1/rowsum -> obuf
  reduce_k<<<2048, 256, 0, stream>>>(part, rowsum, obuf);

  // out[b][c][t] = x + Wo*O + bo
  gemm_bt_k<6><<<dim3(32, 4, 2), 256, 0, stream>>>(
      wob, obuf, outp, bop, xp, nullptr, 512, 512, 512, 4096, 1.f,
      0, (long)4096 * 512, (long)512 * 4096, 1);
}

// Round 10
// 269.219 us; speedup vs baseline: 1.3188x; 1.0030x over previous
//
#include <hip/hip_runtime.h>
#include <hip/hip_bf16.h>

// Problem constants: B=2, C=512, H=W=64 -> N=4096, G=32 (16 ch/group), EPS=1e-6.

typedef float f32x4 __attribute__((ext_vector_type(4)));
typedef __bf16 bf16x8 __attribute__((ext_vector_type(8)));

typedef const __attribute__((address_space(1))) unsigned char* gas_p;
typedef __attribute__((address_space(3))) unsigned char* las_p;

__device__ __forceinline__ void gload_lds16(const void* g, void* l) {
  // async DMA: each lane contributes 16B; LDS dst = wave-uniform base + lane*16
  __builtin_amdgcn_global_load_lds((gas_p)g, (las_p)l, 16, 0, 0);
}

// ====== prelude: weight cvt (4x1024 blocks) | gn_stats (64) | bcat (1) ======
__global__ __launch_bounds__(256) void prelude_k(
    const float* __restrict__ wq, const float* __restrict__ wk,
    const float* __restrict__ wv, const float* __restrict__ wo,
    __hip_bfloat16* __restrict__ wqkb, __hip_bfloat16* __restrict__ wvb,
    __hip_bfloat16* __restrict__ wob, const float* __restrict__ bq,
    const float* __restrict__ bk, float* __restrict__ bqk,
    const float* __restrict__ x, float* __restrict__ stats) {
  int bid = blockIdx.x;
  if (bid < 4096) {
    const float* src;
    __hip_bfloat16* dst;
    if (bid < 1024)      { src = wq; dst = wqkb; }
    else if (bid < 2048) { src = wk; dst = wqkb + 262144; }
    else if (bid < 3072) { src = wv; dst = wvb; }
    else                 { src = wo; dst = wob; }
    int i = (bid & 1023) * 256 + threadIdx.x;  // 1024*256 = 262144 = 512*512
    dst[i] = __float2bfloat16(src[i]);
    return;
  }
  if (bid < 4160) {  // gn_stats: one block per (b,g)
    int bg = bid - 4096;
    const float4* p = (const float4*)(x + (size_t)bg * 65536);
    float s = 0.f, s2 = 0.f;
    for (int i = threadIdx.x; i < 16384; i += 256) {
      float4 v = p[i];
      s  += v.x + v.y + v.z + v.w;
      s2 += v.x * v.x + v.y * v.y + v.z * v.z + v.w * v.w;
    }
#pragma unroll
    for (int off = 32; off > 0; off >>= 1) {
      s  += __shfl_xor(s, off);
      s2 += __shfl_xor(s2, off);
    }
    __shared__ float rs[4], rs2[4];
    int wid = threadIdx.x >> 6, lane = threadIdx.x & 63;
    if (lane == 0) { rs[wid] = s; rs2[wid] = s2; }
    __syncthreads();
    if (threadIdx.x == 0) {
      float S  = rs[0] + rs[1] + rs[2] + rs[3];
      float S2 = rs2[0] + rs2[1] + rs2[2] + rs2[3];
      float mean = S * (1.f / 65536.f);
      float var  = S2 * (1.f / 65536.f) - mean * mean;
      stats[bg * 2]     = mean;
      stats[bg * 2 + 1] = rsqrtf(var + 1e-6f);
    }
    return;
  }
  // bcat
  for (int j = threadIdx.x; j < 1024; j += 256)
    bqk[j] = (j < 512) ? bq[j] : bk[j - 512];
}

// ------- GroupNorm apply + transpose [b][c][n] -> hf bf16 [b][n][c] --------
__global__ __launch_bounds__(256) void gn_apply_k(const float* __restrict__ x,
                                                  const float* __restrict__ stats,
                                                  const float* __restrict__ gw,
                                                  const float* __restrict__ gb,
                                                  __hip_bfloat16* __restrict__ hf) {
  int c0 = blockIdx.x * 64, n0 = blockIdx.y * 64, b = blockIdx.z;
  __shared__ float tile[64][65];
  int tx = threadIdx.x & 63, ty = threadIdx.x >> 6;
  const float* xb = x + ((size_t)(b * 512 + c0)) * 4096 + n0;
#pragma unroll
  for (int i = 0; i < 64; i += 4) {
    int cl = i + ty;
    int c  = c0 + cl;
    float mean = stats[(b * 32 + (c >> 4)) * 2];
    float rstd = stats[(b * 32 + (c >> 4)) * 2 + 1];
    float v = xb[(size_t)cl * 4096 + tx];
    tile[cl][tx] = (v - mean) * rstd * gw[c] + gb[c];
  }
  __syncthreads();
  __hip_bfloat16* o = hf + ((size_t)(b * 4096 + n0)) * 512 + c0;
#pragma unroll
  for (int i = 0; i < 64; i += 4) {
    int nl = i + ty;
    o[(size_t)nl * 512 + tx] = __float2bfloat16(tile[tx][nl]);
  }
}

// ============ fused QKV (double-buffered DMA + LDS epilogue) ============
// bx<8 : QK GEMM  qk[t][o] (o<1024) = sum_c hf[t][c]*Wqk[o][c] + bqk[o]
// bx>=8: V GEMM   vT[b][o][t]       = sum_c Wv[o][c]*hf[t][c] + bv[o]
__global__ __launch_bounds__(256, 4) void qkv_k(
    const __hip_bfloat16* __restrict__ hf, const __hip_bfloat16* __restrict__ wqk,
    const __hip_bfloat16* __restrict__ wv, const float* __restrict__ bqk,
    const float* __restrict__ bv, __hip_bfloat16* __restrict__ qk,
    __hip_bfloat16* __restrict__ vT) {
  bool isV = blockIdx.x >= 8;
  int m0 = isV ? (blockIdx.x - 8) * 128 : blockIdx.y * 128;
  int n0 = isV ? blockIdx.y * 128 : blockIdx.x * 128;
  const __hip_bfloat16* A  = isV ? wv : hf;   // [m][512]
  const __hip_bfloat16* Bm = isV ? hf : wqk;  // [n][512]

  __shared__ __align__(16) unsigned char smem[34816];  // dbuf(32K) | epi(34K)
  __hip_bfloat16* As  = (__hip_bfloat16*)smem;
  __hip_bfloat16* Bs  = As + 8192;
  __hip_bfloat16* epi = (__hip_bfloat16*)smem;         // [128][136]

  int tid  = threadIdx.x;
  int wvx  = tid >> 6, lane = tid & 63;
  int wr   = (wvx >> 1) * 64, wc = (wvx & 1) * 64;
  int quad = lane >> 4, l16 = lane & 15;

  int srow = wvx * 32 + (lane >> 2);
  int scol = (lane & 3) * 8;
  const __hip_bfloat16* gA0 = A  + (size_t)(m0 + srow) * 512 + scol;
  const __hip_bfloat16* gA1 = gA0 + (size_t)16 * 512;
  const __hip_bfloat16* gB0 = Bm + (size_t)(n0 + srow) * 512 + scol;
  const __hip_bfloat16* gB1 = gB0 + (size_t)16 * 512;

  auto stage = [&](int kk, int bsel) {
    int lb = bsel * 4096 + wvx * 1024;
    gload_lds16(gA0 + kk, &As[lb]);
    gload_lds16(gA1 + kk, &As[lb + 512]);
    gload_lds16(gB0 + kk, &Bs[lb]);
    gload_lds16(gB1 + kk, &Bs[lb + 512]);
  };

  f32x4 acc[4][4] = {};
  stage(0, 0);
  for (int kt = 0; kt < 16; kt++) {
    __syncthreads();
    if (kt + 1 < 16) stage((kt + 1) << 5, (kt + 1) & 1);
    const __hip_bfloat16* Ab = &As[(kt & 1) * 4096];
    const __hip_bfloat16* Bb = &Bs[(kt & 1) * 4096];
    bf16x8 af[4], bfr[4];
#pragma unroll
    for (int i = 0; i < 4; i++)
      af[i] = *(const bf16x8*)&Ab[(wr + i * 16 + l16) * 32 + quad * 8];
#pragma unroll
    for (int j = 0; j < 4; j++)
      bfr[j] = *(const bf16x8*)&Bb[(wc + j * 16 + l16) * 32 + quad * 8];
#pragma unroll
    for (int i = 0; i < 4; i++)
#pragma unroll
      for (int j = 0; j < 4; j++)
        acc[i][j] = __builtin_amdgcn_mfma_f32_16x16x32_bf16(af[i], bfr[j],
                                                            acc[i][j], 0, 0, 0);
  }

  // ---- epilogue via LDS: C-layout -> row-major coalesced ----
  float bj[4], bm[4][4];
  if (!isV) {
#pragma unroll
    for (int j = 0; j < 4; j++) bj[j] = bqk[n0 + wc + j * 16 + l16];
  } else {
#pragma unroll
    for (int i = 0; i < 4; i++)
#pragma unroll
      for (int r = 0; r < 4; r++)
        bm[i][r] = bv[m0 + wr + i * 16 + quad * 4 + r];
  }
  __syncthreads();  // dbuf fragment reads done before epi overwrite
#pragma unroll
  for (int i = 0; i < 4; i++)
#pragma unroll
    for (int j = 0; j < 4; j++)
#pragma unroll
      for (int r = 0; r < 4; r++) {
        int ml = wr + i * 16 + quad * 4 + r;
        int nl = wc + j * 16 + l16;
        float v = acc[i][j][r] + (isV ? bm[i][r] : bj[j]);
        epi[ml * 136 + nl] = __float2bfloat16(v);
      }
  __syncthreads();
  int mr = tid >> 1, h = tid & 1;
  const __hip_bfloat16* rowp = &epi[mr * 136 + h * 64];
  if (!isV) {
    __hip_bfloat16* o = qk + (size_t)(m0 + mr) * 1024 + n0 + h * 64;
#pragma unroll
    for (int c = 0; c < 8; c++)
      *(uint4*)(o + c * 8) = *(const uint4*)(rowp + c * 8);
  } else {
    int b = (n0 + h * 64) >> 12, t = (n0 + h * 64) & 4095;
    __hip_bfloat16* o = vT + ((size_t)(b * 512 + m0 + mr)) * 4096 + t;
#pragma unroll
    for (int c = 0; c < 8; c++)
      *(uint4*)(o + c * 8) = *(const uint4*)(rowp + c * 8);
  }
}

// ---------------- bf16 GEMM, B^T form, dbuf DMA + LDS epilogue -------------
// MODE 2: expS[m][n]=exp(v*scale), coalesced bf16 stores; atomic-free row
//         sums -> psums[bx][bb*4096+m]  (`rowsum` arg = psums)
// MODE 6: out fp32 [m][n] + bias[m] + resid
template <int MODE>
__global__ __launch_bounds__(256, 4) void gemm_bt_k(
    const __hip_bfloat16* __restrict__ A, const __hip_bfloat16* __restrict__ Bm,
    void* __restrict__ Cout, const float* __restrict__ bias,
    const float* __restrict__ resid, float* __restrict__ rowsum, int Kc,
    int lda, int ldb, int ldc, float scale, long sAz, long sBz, long sCz,
    int kspl) {
  int bx = blockIdx.x, by = blockIdx.y, bz = blockIdx.z;
  int bb = bz / kspl, ks = bz - bb * kspl;
  A  += (size_t)bb * sAz + (size_t)ks * Kc;
  Bm += (size_t)bb * sBz + (size_t)ks * Kc;
  size_t cbase = (size_t)bz * sCz;
  int m0 = by * 128, n0 = bx * 128;

  __shared__ __align__(16) unsigned char smem[34816];  // dbuf(32K) | epi(34K)
  __hip_bfloat16* As  = (__hip_bfloat16*)smem;
  __hip_bfloat16* Bs  = As + 8192;
  __hip_bfloat16* epi = (__hip_bfloat16*)smem;         // [128][136]

  int tid  = threadIdx.x;
  int wv   = tid >> 6, lane = tid & 63;
  int wr   = (wv >> 1) * 64, wc = (wv & 1) * 64;
  int quad = lane >> 4, l16 = lane & 15;

  int srow = wv * 32 + (lane >> 2);
  int scol = (lane & 3) * 8;
  const __hip_bfloat16* gA0 = A  + (size_t)(m0 + srow) * lda + scol;
  const __hip_bfloat16* gA1 = gA0 + (size_t)16 * lda;
  const __hip_bfloat16* gB0 = Bm + (size_t)(n0 + srow) * ldb + scol;
  const __hip_bfloat16* gB1 = gB0 + (size_t)16 * ldb;

  auto stage = [&](int kk, int bsel) {
    int lb = bsel * 4096 + wv * 1024;
    gload_lds16(gA0 + kk, &As[lb]);
    gload_lds16(gA1 + kk, &As[lb + 512]);
    gload_lds16(gB0 + kk, &Bs[lb]);
    gload_lds16(gB1 + kk, &Bs[lb + 512]);
  };

  int KT = Kc >> 5;
  f32x4 acc[4][4] = {};
  stage(0, 0);
  for (int kt = 0; kt < KT; kt++) {
    __syncthreads();
    if (kt + 1 < KT) stage((kt + 1) << 5, (kt + 1) & 1);
    const __hip_bfloat16* Ab = &As[(kt & 1) * 4096];
    const __hip_bfloat16* Bb = &Bs[(kt & 1) * 4096];
    bf16x8 af[4], bfr[4];
#pragma unroll
    for (int i = 0; i < 4; i++)
      af[i] = *(const bf16x8*)&Ab[(wr + i * 16 + l16) * 32 + quad * 8];
#pragma unroll
    for (int j = 0; j < 4; j++)
      bfr[j] = *(const bf16x8*)&Bb[(wc + j * 16 + l16) * 32 + quad * 8];
#pragma unroll
    for (int i = 0; i < 4; i++)
#pragma unroll
      for (int j = 0; j < 4; j++)
        acc[i][j] = __builtin_amdgcn_mfma_f32_16x16x32_bf16(af[i], bfr[j],
                                                            acc[i][j], 0, 0, 0);
  }

  // ---- epilogue via LDS ----
  float pre[4][4];
  if (MODE == 6) {
#pragma unroll
    for (int i = 0; i < 4; i++)
#pragma unroll
      for (int r = 0; r < 4; r++)
        pre[i][r] = bias[m0 + wr + i * 16 + quad * 4 + r];
  }
  __syncthreads();  // dbuf fragment reads done before epi overwrite
#pragma unroll
  for (int i = 0; i < 4; i++)
#pragma unroll
    for (int j = 0; j < 4; j++)
#pragma unroll
      for (int r = 0; r < 4; r++) {
        int ml = wr + i * 16 + quad * 4 + r;
        int nl = wc + j * 16 + l16;
        float v = acc[i][j][r];
        if (MODE == 2) v = __expf(v * scale);
        else v += pre[i][r];
        epi[ml * 136 + nl] = __float2bfloat16(v);
      }
  __syncthreads();
  int mr = tid >> 1, h = tid & 1;
  const __hip_bfloat16* rowp = &epi[mr * 136 + h * 64];
  size_t obase = cbase + (size_t)(m0 + mr) * ldc + n0 + h * 64;
  if (MODE == 2) {
    float s = 0.f;
    __hip_bfloat16* o = (__hip_bfloat16*)Cout + obase;
#pragma unroll
    for (int c = 0; c < 8; c++) {
      bf16x8 val = *(const bf16x8*)(rowp + c * 8);
#pragma unroll
      for (int l = 0; l < 8; l++) s += (float)val[l];
      *(uint4*)(o + c * 8) = *(const uint4*)&val;
    }
    s += __shfl_xor(s, 1);  // combine the two column-halves of the row
    if (h == 0) rowsum[(size_t)bx * 8192 + bb * 4096 + m0 + mr] = s;
  } else {  // MODE 6: fp32 out = bf16(v+bias) + resid
    float* o = (float*)Cout;
#pragma unroll
    for (int c = 0; c < 8; c++) {
      bf16x8 val = *(const bf16x8*)(rowp + c * 8);
      size_t idx = obase + c * 8;
      float4 r0 = *(const float4*)&resid[idx];
      float4 r1 = *(const float4*)&resid[idx + 4];
      float4 o0, o1;
      o0.x = r0.x + (float)val[0]; o0.y = r0.y + (float)val[1];
      o0.z = r0.z + (float)val[2]; o0.w = r0.w + (float)val[3];
      o1.x = r1.x + (float)val[4]; o1.y = r1.y + (float)val[5];
      o1.z = r1.z + (float)val[6]; o1.w = r1.w + (float)val[7];
      *(float4*)&o[idx] = o0;
      *(float4*)&o[idx + 4] = o1;
    }
  }
}

// ============ PV split-K: BK=64 staging, XOR-swizzled LDS ============
// part[bz][m][c] = sum_{k in ks half} expS[bb][m][k] * vT[bb][c][k]
__global__ __launch_bounds__(256, 2) void pv_k(
    const __hip_bfloat16* __restrict__ P, const __hip_bfloat16* __restrict__ vT,
    __hip_bfloat16* __restrict__ part) {
  // 512 blocks; co-locate the 4 c-tiles of each (m,bz) group on one XCD
  int f = blockIdx.x;
  int xcd = f & 7, s = f >> 3;
  int bx = s & 3;
  int g = xcd + 8 * (s >> 2);     // 0..127
  int by = g & 31, bz = g >> 5;   // bz = bb*2+ks
  int bb = bz >> 1, ks = bz & 1;
  const __hip_bfloat16* A = P  + (size_t)bb * 4096 * 4096 + (size_t)ks * 2048;
  const __hip_bfloat16* B = vT + (size_t)bb * 512 * 4096 + (size_t)ks * 2048;
  size_t cbase = (size_t)bz * 4096 * 512;
  int m0 = by * 128, n0 = bx * 128;

  __shared__ __align__(16) unsigned char smem[65536];  // dbuf 64K; epi overlaps
  __hip_bfloat16* As  = (__hip_bfloat16*)smem;          // 2 x [128][64]
  __hip_bfloat16* Bs  = (__hip_bfloat16*)(smem + 32768);
  __hip_bfloat16* epi = (__hip_bfloat16*)smem;          // [128][136]

  int tid = threadIdx.x, wv = tid >> 6, lane = tid & 63;
  int wr = (wv >> 1) * 64, wc = (wv & 1) * 64;
  int quad = lane >> 4, l16 = lane & 15;

  // DMA: inst covers 8 rows x 128B; lane l -> row l>>3, swizzled chunk
  // (l&7)^(l>>3). LDS[r][x] = G[r][x ^ (r&7)] so b128 frag reads are 2-way.
  int srow = wv * 32 + (lane >> 3);
  int scol = ((lane & 7) ^ (lane >> 3)) * 8;
  const __hip_bfloat16* gA = A + (size_t)(m0 + srow) * 4096 + scol;
  const __hip_bfloat16* gB = B + (size_t)(n0 + srow) * 4096 + scol;

  auto stage = [&](int kk, int bsel) {
    __hip_bfloat16* la = &As[bsel * 8192 + wv * 2048];
    __hip_bfloat16* lb = &Bs[bsel * 8192 + wv * 2048];
#pragma unroll
    for (int c = 0; c < 4; c++) {
      gload_lds16(gA + kk + (size_t)(c * 8) * 4096, la + c * 512);
      gload_lds16(gB + kk + (size_t)(c * 8) * 4096, lb + c * 512);
    }
  };

  f32x4 acc[4][4] = {};
  stage(0, 0);
  for (int kt = 0; kt < 32; kt++) {
    __syncthreads();
    if (kt + 1 < 32) stage((kt + 1) << 6, (kt + 1) & 1);
    const __hip_bfloat16* Ab = &As[(kt & 1) * 8192];
    const __hip_bfloat16* Bb = &Bs[(kt & 1) * 8192];
#pragma unroll
    for (int ksub = 0; ksub < 2; ksub++) {
      bf16x8 af[4], bfr[4];
#pragma unroll
      for (int i = 0; i < 4; i++) {
        int r = wr + i * 16 + l16;
        af[i] = *(const bf16x8*)&Ab[r * 64 + ((ksub * 4 + quad) ^ (r & 7)) * 8];
      }
#pragma unroll
      for (int j = 0; j < 4; j++) {
        int r = wc + j * 16 + l16;
        bfr[j] = *(const bf16x8*)&Bb[r * 64 + ((ksub * 4 + quad) ^ (r & 7)) * 8];
      }
#pragma unroll
      for (int i = 0; i < 4; i++)
#pragma unroll
        for (int j = 0; j < 4; j++)
          acc[i][j] = __builtin_amdgcn_mfma_f32_16x16x32_bf16(af[i], bfr[j],
                                                              acc[i][j], 0, 0, 0);
    }
  }

  __syncthreads();
#pragma unroll
  for (int i = 0; i < 4; i++)
#pragma unroll
    for (int j = 0; j < 4; j++)
#pragma unroll
      for (int r = 0; r < 4; r++)
        epi[(wr + i * 16 + quad * 4 + r) * 136 + wc + j * 16 + l16] =
            __float2bfloat16(acc[i][j][r]);
  __syncthreads();
  int mr = tid >> 1, h = tid & 1;
  const __hip_bfloat16* rowp = &epi[mr * 136 + h * 64];
  __hip_bfloat16* o = part + cbase + (size_t)(m0 + mr) * 512 + n0 + h * 64;
#pragma unroll
  for (int c = 0; c < 8; c++)
    *(uint4*)(o + c * 8) = *(const uint4*)(rowp + c * 8);
}

// ---- reduce 2 partials, fold 32 psums -> rowsum, normalize -> obuf ----
__global__ __launch_bounds__(256) void reduce_k(
    const __hip_bfloat16* __restrict__ part, const float* __restrict__ psums,
    __hip_bfloat16* __restrict__ obuf) {
  size_t i8 = (size_t)blockIdx.x * 256 + threadIdx.x;
  size_t perb = (size_t)4096 * 512 / 8;  // 262144 vectors per batch
  size_t b = i8 / perb, r = i8 - b * perb;
  int t = (int)(r >> 6);                 // token row (64 vectors per row)
  int lane = threadIdx.x & 63;
  // all 64 lanes of a warp share t; lanes load the 32 per-n-tile partial sums
  float ps = psums[(size_t)(lane & 31) * 8192 + b * 4096 + t];
#pragma unroll
  for (int off = 1; off < 32; off <<= 1) ps += __shfl_xor(ps, off);
  float inv = 1.f / ps;
  float acc[8] = {};
#pragma unroll
  for (int ks = 0; ks < 2; ks++) {
    bf16x8 v = ((const bf16x8*)part)[(b * 2 + ks) * perb + r];
#pragma unroll
    for (int l = 0; l < 8; l++) acc[l] += (float)v[l];
  }
  bf16x8 o;
#pragma unroll
  for (int l = 0; l < 8; l++) o[l] = (__bf16)(acc[l] * inv);
  ((bf16x8*)obuf)[b * perb + r] = o;
}

extern "C" void kernel_launch(void* const* d_in, const int* in_sizes, int n_in,
                              void* d_out, int out_size, void* d_ws,
                              size_t ws_size, hipStream_t stream) {
  const float* xp  = (const float*)d_in[0];
  const float* gwp = (const float*)d_in[1];
  const float* gbp = (const float*)d_in[2];
  const float* wqp = (const float*)d_in[3];
  const float* bqp = (const float*)d_in[4];
  const float* wkp = (const float*)d_in[5];
  const float* bkp = (const float*)d_in[6];
  const float* wvp = (const float*)d_in[7];
  const float* bvp = (const float*)d_in[8];
  const float* wop = (const float*)d_in[9];
  const float* bop = (const float*)d_in[10];
  float* outp = (float*)d_out;

  char* w = (char*)d_ws;
  size_t off = 0;
  auto alloc = [&](size_t bytes) {
    void* p = w + off;
    off += (bytes + 255) & ~(size_t)255;
    return p;
  };
  float* stats         = (float*)alloc(64 * 2 * sizeof(float));
  __hip_bfloat16* hf   = (__hip_bfloat16*)alloc((size_t)2 * 4096 * 512 * 2);
  __hip_bfloat16* wqkb = (__hip_bfloat16*)alloc((size_t)1024 * 512 * 2);
  __hip_bfloat16* wvb  = (__hip_bfloat16*)alloc((size_t)512 * 512 * 2);
  __hip_bfloat16* wob  = (__hip_bfloat16*)alloc((size_t)512 * 512 * 2);
  float* bqk           = (float*)alloc(1024 * sizeof(float));
  float* psums         = (float*)alloc((size_t)32 * 8192 * sizeof(float));
  __hip_bfloat16* qk   = (__hip_bfloat16*)alloc((size_t)2 * 4096 * 1024 * 2);
  __hip_bfloat16* vT   = (__hip_bfloat16*)alloc((size_t)2 * 512 * 4096 * 2);
  __hip_bfloat16* obuf = (__hip_bfloat16*)alloc((size_t)2 * 4096 * 512 * 2);
  __hip_bfloat16* part = (__hip_bfloat16*)alloc((size_t)4 * 4096 * 512 * 2);
  __hip_bfloat16* Sbuf = (__hip_bfloat16*)alloc((size_t)2 * 4096 * 4096 * 2);

  // prelude: 4096 cvt blocks + 64 gn_stats blocks + 1 bcat block
  prelude_k<<<4161, 256, 0, stream>>>(wqp, wkp, wvp, wop, wqkb, wvb, wob,
                                      bqp, bkp, bqk, xp, stats);

  gn_apply_k<<<dim3(8, 64, 2), 256, 0, stream>>>(xp, stats, gwp, gbp, hf);

  // fused QKV: qk[8192][1024] and vT[2][512][4096]
  qkv_k<<<dim3(12, 64, 1), 256, 0, stream>>>(hf, wqkb, wvb, bqk, bvp, qk, vT);

  // expS = exp(Q K^T * scale), both batches (bf16) + per-n-tile row sums
  gemm_bt_k<2><<<dim3(32, 32, 2), 256, 0, stream>>>(
      qk, qk + 512, Sbuf, nullptr, nullptr, psums, 512, 1024, 1024, 4096,
      0.044194173824159216f, (long)4096 * 1024, (long)4096 * 1024,
      (long)4096 * 4096, 1);

  // PV split-K (kspl=2, BK=64, XCD-swizzled): raw partials [4][4096][512]
  pv_k<<<512, 256, 0, stream>>>(Sbuf, vT, part);

  // sum partials + fold psums + normalize -> obuf
  reduce_k<<<2048, 256, 0, stream>>>(part, psums, obuf);

  // out[b][c][t] = x + Wo*O + bo
  gemm_bt_k<6><<<dim3(32, 4, 2), 256, 0, stream>>>(
      wob, obuf, outp, bop, xp, nullptr, 512, 512, 512, 4096, 1.f,
      0, (long)4096 * 512, (long)512 * 4096, 1);
}

// Round 11
// 252.648 us; speedup vs baseline: 1.4053x; 1.0656x over previous
//
#include <hip/hip_runtime.h>
#include <hip/hip_bf16.h>

// Problem constants: B=2, C=512, H=W=64 -> N=4096, G=32 (16 ch/group), EPS=1e-6.

typedef float f32x4 __attribute__((ext_vector_type(4)));
typedef __bf16 bf16x8 __attribute__((ext_vector_type(8)));

typedef const __attribute__((address_space(1))) unsigned char* gas_p;
typedef __attribute__((address_space(3))) unsigned char* las_p;

__device__ __forceinline__ void gload_lds16(const void* g, void* l) {
  // async DMA: each lane contributes 16B; LDS dst = wave-uniform base + lane*16
  __builtin_amdgcn_global_load_lds((gas_p)g, (las_p)l, 16, 0, 0);
}

// ====== prelude: weight cvt (4x1024 blocks) | gn_stats (64) | bcat (1) ======
__global__ __launch_bounds__(256) void prelude_k(
    const float* __restrict__ wq, const float* __restrict__ wk,
    const float* __restrict__ wv, const float* __restrict__ wo,
    __hip_bfloat16* __restrict__ wqkb, __hip_bfloat16* __restrict__ wvb,
    __hip_bfloat16* __restrict__ wob, const float* __restrict__ bq,
    const float* __restrict__ bk, float* __restrict__ bqk,
    const float* __restrict__ x, float* __restrict__ stats) {
  int bid = blockIdx.x;
  if (bid < 4096) {
    const float* src;
    __hip_bfloat16* dst;
    if (bid < 1024)      { src = wq; dst = wqkb; }
    else if (bid < 2048) { src = wk; dst = wqkb + 262144; }
    else if (bid < 3072) { src = wv; dst = wvb; }
    else                 { src = wo; dst = wob; }
    int i = (bid & 1023) * 256 + threadIdx.x;  // 1024*256 = 262144 = 512*512
    dst[i] = __float2bfloat16(src[i]);
    return;
  }
  if (bid < 4160) {  // gn_stats: one block per (b,g)
    int bg = bid - 4096;
    const float4* p = (const float4*)(x + (size_t)bg * 65536);
    float s = 0.f, s2 = 0.f;
    for (int i = threadIdx.x; i < 16384; i += 256) {
      float4 v = p[i];
      s  += v.x + v.y + v.z + v.w;
      s2 += v.x * v.x + v.y * v.y + v.z * v.z + v.w * v.w;
    }
#pragma unroll
    for (int off = 32; off > 0; off >>= 1) {
      s  += __shfl_xor(s, off);
      s2 += __shfl_xor(s2, off);
    }
    __shared__ float rs[4], rs2[4];
    int wid = threadIdx.x >> 6, lane = threadIdx.x & 63;
    if (lane == 0) { rs[wid] = s; rs2[wid] = s2; }
    __syncthreads();
    if (threadIdx.x == 0) {
      float S  = rs[0] + rs[1] + rs[2] + rs[3];
      float S2 = rs2[0] + rs2[1] + rs2[2] + rs2[3];
      float mean = S * (1.f / 65536.f);
      float var  = S2 * (1.f / 65536.f) - mean * mean;
      stats[bg * 2]     = mean;
      stats[bg * 2 + 1] = rsqrtf(var + 1e-6f);
    }
    return;
  }
  // bcat
  for (int j = threadIdx.x; j < 1024; j += 256)
    bqk[j] = (j < 512) ? bq[j] : bk[j - 512];
}

// ------- GroupNorm apply + transpose, vectorized: x fp32 -> hf bf16 [b][n][c]
__global__ __launch_bounds__(256) void gn_apply_k(const float* __restrict__ x,
                                                  const float* __restrict__ stats,
                                                  const float* __restrict__ gw,
                                                  const float* __restrict__ gb,
                                                  __hip_bfloat16* __restrict__ hf) {
  int c0 = blockIdx.x * 64, n0 = blockIdx.y * 64, b = blockIdx.z;
  __shared__ float tile[64][65];
  int tid = threadIdx.x;
  int cl = tid >> 2, q = tid & 3;
  int c = c0 + cl;
  float mean = stats[(b * 32 + (c >> 4)) * 2];
  float rstd = stats[(b * 32 + (c >> 4)) * 2 + 1];
  float sc = rstd * gw[c];
  float sh = gb[c] - mean * sc;
  const float* xr = x + ((size_t)(b * 512 + c0 + cl)) * 4096 + n0 + q * 16;
#pragma unroll
  for (int j = 0; j < 4; j++) {
    float4 v = *(const float4*)(xr + 4 * j);
    int n = q * 16 + 4 * j;
    tile[cl][n]     = v.x * sc + sh;
    tile[cl][n + 1] = v.y * sc + sh;
    tile[cl][n + 2] = v.z * sc + sh;
    tile[cl][n + 3] = v.w * sc + sh;
  }
  __syncthreads();
  int nl = tid >> 2, ch = q * 16;
  bf16x8 o0, o1;
#pragma unroll
  for (int l = 0; l < 8; l++) {
    o0[l] = (__bf16)tile[ch + l][nl];
    o1[l] = (__bf16)tile[ch + 8 + l][nl];
  }
  __hip_bfloat16* op = hf + ((size_t)(b * 4096 + n0 + nl)) * 512 + c0 + ch;
  *(uint4*)op = *(uint4*)&o0;
  *(uint4*)(op + 8) = *(uint4*)&o1;
}

// ============ fused QKV (double-buffered DMA + LDS epilogue) ============
// bx<8 : QK GEMM  qk[t][o] (o<1024) = sum_c hf[t][c]*Wqk[o][c] + bqk[o]
// bx>=8: V GEMM   vT[b][o][t]       = sum_c Wv[o][c]*hf[t][c] + bv[o]
__global__ __launch_bounds__(256, 4) void qkv_k(
    const __hip_bfloat16* __restrict__ hf, const __hip_bfloat16* __restrict__ wqk,
    const __hip_bfloat16* __restrict__ wv, const float* __restrict__ bqk,
    const float* __restrict__ bv, __hip_bfloat16* __restrict__ qk,
    __hip_bfloat16* __restrict__ vT) {
  bool isV = blockIdx.x >= 8;
  int m0 = isV ? (blockIdx.x - 8) * 128 : blockIdx.y * 128;
  int n0 = isV ? blockIdx.y * 128 : blockIdx.x * 128;
  const __hip_bfloat16* A  = isV ? wv : hf;   // [m][512]
  const __hip_bfloat16* Bm = isV ? hf : wqk;  // [n][512]

  __shared__ __align__(16) unsigned char smem[34816];  // dbuf(32K) | epi(34K)
  __hip_bfloat16* As  = (__hip_bfloat16*)smem;
  __hip_bfloat16* Bs  = As + 8192;
  __hip_bfloat16* epi = (__hip_bfloat16*)smem;         // [128][136]

  int tid  = threadIdx.x;
  int wvx  = tid >> 6, lane = tid & 63;
  int wr   = (wvx >> 1) * 64, wc = (wvx & 1) * 64;
  int quad = lane >> 4, l16 = lane & 15;

  int srow = wvx * 32 + (lane >> 2);
  int scol = (lane & 3) * 8;
  const __hip_bfloat16* gA0 = A  + (size_t)(m0 + srow) * 512 + scol;
  const __hip_bfloat16* gA1 = gA0 + (size_t)16 * 512;
  const __hip_bfloat16* gB0 = Bm + (size_t)(n0 + srow) * 512 + scol;
  const __hip_bfloat16* gB1 = gB0 + (size_t)16 * 512;

  auto stage = [&](int kk, int bsel) {
    int lb = bsel * 4096 + wvx * 1024;
    gload_lds16(gA0 + kk, &As[lb]);
    gload_lds16(gA1 + kk, &As[lb + 512]);
    gload_lds16(gB0 + kk, &Bs[lb]);
    gload_lds16(gB1 + kk, &Bs[lb + 512]);
  };

  f32x4 acc[4][4] = {};
  stage(0, 0);
  for (int kt = 0; kt < 16; kt++) {
    __syncthreads();
    if (kt + 1 < 16) stage((kt + 1) << 5, (kt + 1) & 1);
    const __hip_bfloat16* Ab = &As[(kt & 1) * 4096];
    const __hip_bfloat16* Bb = &Bs[(kt & 1) * 4096];
    bf16x8 af[4], bfr[4];
#pragma unroll
    for (int i = 0; i < 4; i++)
      af[i] = *(const bf16x8*)&Ab[(wr + i * 16 + l16) * 32 + quad * 8];
#pragma unroll
    for (int j = 0; j < 4; j++)
      bfr[j] = *(const bf16x8*)&Bb[(wc + j * 16 + l16) * 32 + quad * 8];
#pragma unroll
    for (int i = 0; i < 4; i++)
#pragma unroll
      for (int j = 0; j < 4; j++)
        acc[i][j] = __builtin_amdgcn_mfma_f32_16x16x32_bf16(af[i], bfr[j],
                                                            acc[i][j], 0, 0, 0);
  }

  // ---- epilogue via LDS: C-layout -> row-major coalesced ----
  float bj[4], bm[4][4];
  if (!isV) {
#pragma unroll
    for (int j = 0; j < 4; j++) bj[j] = bqk[n0 + wc + j * 16 + l16];
  } else {
#pragma unroll
    for (int i = 0; i < 4; i++)
#pragma unroll
      for (int r = 0; r < 4; r++)
        bm[i][r] = bv[m0 + wr + i * 16 + quad * 4 + r];
  }
  __syncthreads();  // dbuf fragment reads done before epi overwrite
#pragma unroll
  for (int i = 0; i < 4; i++)
#pragma unroll
    for (int j = 0; j < 4; j++)
#pragma unroll
      for (int r = 0; r < 4; r++) {
        int ml = wr + i * 16 + quad * 4 + r;
        int nl = wc + j * 16 + l16;
        float v = acc[i][j][r] + (isV ? bm[i][r] : bj[j]);
        epi[ml * 136 + nl] = __float2bfloat16(v);
      }
  __syncthreads();
  int mr = tid >> 1, h = tid & 1;
  const __hip_bfloat16* rowp = &epi[mr * 136 + h * 64];
  if (!isV) {
    __hip_bfloat16* o = qk + (size_t)(m0 + mr) * 1024 + n0 + h * 64;
#pragma unroll
    for (int c = 0; c < 8; c++)
      *(uint4*)(o + c * 8) = *(const uint4*)(rowp + c * 8);
  } else {
    int b = (n0 + h * 64) >> 12, t = (n0 + h * 64) & 4095;
    __hip_bfloat16* o = vT + ((size_t)(b * 512 + m0 + mr)) * 4096 + t;
#pragma unroll
    for (int c = 0; c < 8; c++)
      *(uint4*)(o + c * 8) = *(const uint4*)(rowp + c * 8);
  }
}

// ---------------- bf16 GEMM, B^T form, dbuf DMA ----------------
// MODE 2: expS[m][n]=exp(v*scale) direct bf16 stores; atomic-free row sums
//         -> psums[bx][bb*4096+m]  (`rowsum` arg = psums)
// MODE 6: out fp32 [m][n] + bias[m] + resid, LDS epilogue
template <int MODE>
__global__ __launch_bounds__(256, 4) void gemm_bt_k(
    const __hip_bfloat16* __restrict__ A, const __hip_bfloat16* __restrict__ Bm,
    void* __restrict__ Cout, const float* __restrict__ bias,
    const float* __restrict__ resid, float* __restrict__ rowsum, int Kc,
    int lda, int ldb, int ldc, float scale, long sAz, long sBz, long sCz,
    int kspl) {
  int bx = blockIdx.x, by = blockIdx.y, bz = blockIdx.z;
  int bb = bz / kspl, ks = bz - bb * kspl;
  A  += (size_t)bb * sAz + (size_t)ks * Kc;
  Bm += (size_t)bb * sBz + (size_t)ks * Kc;
  size_t cbase = (size_t)bz * sCz;
  int m0 = by * 128, n0 = bx * 128;

  __shared__ __align__(16) unsigned char smem[34816];  // dbuf(32K) | epi / psum2
  __hip_bfloat16* As  = (__hip_bfloat16*)smem;
  __hip_bfloat16* Bs  = As + 8192;
  __hip_bfloat16* epi = (__hip_bfloat16*)smem;         // [128][136] (MODE 6)
  float* psum2 = (float*)(smem + 32768);               // [2][128]   (MODE 2)

  int tid  = threadIdx.x;
  int wv   = tid >> 6, lane = tid & 63;
  int wr   = (wv >> 1) * 64, wc = (wv & 1) * 64;
  int quad = lane >> 4, l16 = lane & 15;

  int srow = wv * 32 + (lane >> 2);
  int scol = (lane & 3) * 8;
  const __hip_bfloat16* gA0 = A  + (size_t)(m0 + srow) * lda + scol;
  const __hip_bfloat16* gA1 = gA0 + (size_t)16 * lda;
  const __hip_bfloat16* gB0 = Bm + (size_t)(n0 + srow) * ldb + scol;
  const __hip_bfloat16* gB1 = gB0 + (size_t)16 * ldb;

  auto stage = [&](int kk, int bsel) {
    int lb = bsel * 4096 + wv * 1024;
    gload_lds16(gA0 + kk, &As[lb]);
    gload_lds16(gA1 + kk, &As[lb + 512]);
    gload_lds16(gB0 + kk, &Bs[lb]);
    gload_lds16(gB1 + kk, &Bs[lb + 512]);
  };

  int KT = Kc >> 5;
  f32x4 acc[4][4] = {};
  stage(0, 0);
  for (int kt = 0; kt < KT; kt++) {
    __syncthreads();
    if (kt + 1 < KT) stage((kt + 1) << 5, (kt + 1) & 1);
    const __hip_bfloat16* Ab = &As[(kt & 1) * 4096];
    const __hip_bfloat16* Bb = &Bs[(kt & 1) * 4096];
    bf16x8 af[4], bfr[4];
#pragma unroll
    for (int i = 0; i < 4; i++)
      af[i] = *(const bf16x8*)&Ab[(wr + i * 16 + l16) * 32 + quad * 8];
#pragma unroll
    for (int j = 0; j < 4; j++)
      bfr[j] = *(const bf16x8*)&Bb[(wc + j * 16 + l16) * 32 + quad * 8];
#pragma unroll
    for (int i = 0; i < 4; i++)
#pragma unroll
      for (int j = 0; j < 4; j++)
        acc[i][j] = __builtin_amdgcn_mfma_f32_16x16x32_bf16(af[i], bfr[j],
                                                            acc[i][j], 0, 0, 0);
  }

  if (MODE == 2) {
    // direct scattered stores + register row-sum reduction (round-9 path:
    // measured 58.8 us vs 65.6 for LDS-staged epilogue)
    float s[4][4];
#pragma unroll
    for (int i = 0; i < 4; i++)
#pragma unroll
      for (int r = 0; r < 4; r++) s[i][r] = 0.f;
    __hip_bfloat16* o = (__hip_bfloat16*)Cout;
#pragma unroll
    for (int i = 0; i < 4; i++)
#pragma unroll
      for (int j = 0; j < 4; j++)
#pragma unroll
        for (int r = 0; r < 4; r++) {
          int m = m0 + wr + i * 16 + quad * 4 + r;
          int n = n0 + wc + j * 16 + l16;
          float v = __expf(acc[i][j][r] * scale);
          o[cbase + (size_t)m * ldc + n] = __float2bfloat16(v);
          s[i][r] += v;
        }
#pragma unroll
    for (int off = 1; off < 16; off <<= 1)
#pragma unroll
      for (int i = 0; i < 4; i++)
#pragma unroll
        for (int r = 0; r < 4; r++) s[i][r] += __shfl_xor(s[i][r], off);
    if (l16 == 0) {
#pragma unroll
      for (int i = 0; i < 4; i++)
#pragma unroll
        for (int r = 0; r < 4; r++)
          psum2[(wv & 1) * 128 + wr + i * 16 + quad * 4 + r] = s[i][r];
    }
    __syncthreads();
    if (tid < 128) {
      float v = psum2[tid] + psum2[128 + tid];
      rowsum[(size_t)bx * 8192 + bb * 4096 + m0 + tid] = v;  // psums slot
    }
    return;
  }

  // ---- MODE 6: epilogue via LDS ----
  float pre[4][4];
#pragma unroll
  for (int i = 0; i < 4; i++)
#pragma unroll
    for (int r = 0; r < 4; r++)
      pre[i][r] = bias[m0 + wr + i * 16 + quad * 4 + r];
  __syncthreads();  // dbuf fragment reads done before epi overwrite
#pragma unroll
  for (int i = 0; i < 4; i++)
#pragma unroll
    for (int j = 0; j < 4; j++)
#pragma unroll
      for (int r = 0; r < 4; r++) {
        int ml = wr + i * 16 + quad * 4 + r;
        int nl = wc + j * 16 + l16;
        epi[ml * 136 + nl] = __float2bfloat16(acc[i][j][r] + pre[i][r]);
      }
  __syncthreads();
  int mr = tid >> 1, h = tid & 1;
  const __hip_bfloat16* rowp = &epi[mr * 136 + h * 64];
  size_t obase = cbase + (size_t)(m0 + mr) * ldc + n0 + h * 64;
  float* o = (float*)Cout;
#pragma unroll
  for (int c = 0; c < 8; c++) {
    bf16x8 val = *(const bf16x8*)(rowp + c * 8);
    size_t idx = obase + c * 8;
    float4 r0 = *(const float4*)&resid[idx];
    float4 r1 = *(const float4*)&resid[idx + 4];
    float4 o0, o1;
    o0.x = r0.x + (float)val[0]; o0.y = r0.y + (float)val[1];
    o0.z = r0.z + (float)val[2]; o0.w = r0.w + (float)val[3];
    o1.x = r1.x + (float)val[4]; o1.y = r1.y + (float)val[5];
    o1.z = r1.z + (float)val[6]; o1.w = r1.w + (float)val[7];
    *(float4*)&o[idx] = o0;
    *(float4*)&o[idx + 4] = o1;
  }
}

// ============ PV split-K: BK=64 staging, XOR-swizzled LDS ============
// part[bz][m][c] = sum_{k in ks half} expS[bb][m][k] * vT[bb][c][k]
__global__ __launch_bounds__(256, 2) void pv_k(
    const __hip_bfloat16* __restrict__ P, const __hip_bfloat16* __restrict__ vT,
    __hip_bfloat16* __restrict__ part) {
  // 512 blocks; co-locate the 4 c-tiles of each (m,bz) group on one XCD
  int f = blockIdx.x;
  int xcd = f & 7, s = f >> 3;
  int bx = s & 3;
  int g = xcd + 8 * (s >> 2);     // 0..127
  int by = g & 31, bz = g >> 5;   // bz = bb*2+ks
  int bb = bz >> 1, ks = bz & 1;
  const __hip_bfloat16* A = P  + (size_t)bb * 4096 * 4096 + (size_t)ks * 2048;
  const __hip_bfloat16* B = vT + (size_t)bb * 512 * 4096 + (size_t)ks * 2048;
  size_t cbase = (size_t)bz * 4096 * 512;
  int m0 = by * 128, n0 = bx * 128;

  __shared__ __align__(16) unsigned char smem[65536];  // dbuf 64K; epi overlaps
  __hip_bfloat16* As  = (__hip_bfloat16*)smem;          // 2 x [128][64]
  __hip_bfloat16* Bs  = (__hip_bfloat16*)(smem + 32768);
  __hip_bfloat16* epi = (__hip_bfloat16*)smem;          // [128][136]

  int tid = threadIdx.x, wv = tid >> 6, lane = tid & 63;
  int wr = (wv >> 1) * 64, wc = (wv & 1) * 64;
  int quad = lane >> 4, l16 = lane & 15;

  // DMA: inst covers 8 rows x 128B; lane l -> row l>>3, swizzled chunk
  // (l&7)^(l>>3). LDS[r][x] = G[r][x ^ (r&7)] so b128 frag reads are 2-way.
  int srow = wv * 32 + (lane >> 3);
  int scol = ((lane & 7) ^ (lane >> 3)) * 8;
  const __hip_bfloat16* gA = A + (size_t)(m0 + srow) * 4096 + scol;
  const __hip_bfloat16* gB = B + (size_t)(n0 + srow) * 4096 + scol;

  auto stage = [&](int kk, int bsel) {
    __hip_bfloat16* la = &As[bsel * 8192 + wv * 2048];
    __hip_bfloat16* lb = &Bs[bsel * 8192 + wv * 2048];
#pragma unroll
    for (int c = 0; c < 4; c++) {
      gload_lds16(gA + kk + (size_t)(c * 8) * 4096, la + c * 512);
      gload_lds16(gB + kk + (size_t)(c * 8) * 4096, lb + c * 512);
    }
  };

  f32x4 acc[4][4] = {};
  stage(0, 0);
  for (int kt = 0; kt < 32; kt++) {
    __syncthreads();
    if (kt + 1 < 32) stage((kt + 1) << 6, (kt + 1) & 1);
    const __hip_bfloat16* Ab = &As[(kt & 1) * 8192];
    const __hip_bfloat16* Bb = &Bs[(kt & 1) * 8192];
#pragma unroll
    for (int ksub = 0; ksub < 2; ksub++) {
      bf16x8 af[4], bfr[4];
#pragma unroll
      for (int i = 0; i < 4; i++) {
        int r = wr + i * 16 + l16;
        af[i] = *(const bf16x8*)&Ab[r * 64 + ((ksub * 4 + quad) ^ (r & 7)) * 8];
      }
#pragma unroll
      for (int j = 0; j < 4; j++) {
        int r = wc + j * 16 + l16;
        bfr[j] = *(const bf16x8*)&Bb[r * 64 + ((ksub * 4 + quad) ^ (r & 7)) * 8];
      }
#pragma unroll
      for (int i = 0; i < 4; i++)
#pragma unroll
        for (int j = 0; j < 4; j++)
          acc[i][j] = __builtin_amdgcn_mfma_f32_16x16x32_bf16(af[i], bfr[j],
                                                              acc[i][j], 0, 0, 0);
    }
  }

  __syncthreads();
#pragma unroll
  for (int i = 0; i < 4; i++)
#pragma unroll
    for (int j = 0; j < 4; j++)
#pragma unroll
      for (int r = 0; r < 4; r++)
        epi[(wr + i * 16 + quad * 4 + r) * 136 + wc + j * 16 + l16] =
            __float2bfloat16(acc[i][j][r]);
  __syncthreads();
  int mr = tid >> 1, h = tid & 1;
  const __hip_bfloat16* rowp = &epi[mr * 136 + h * 64];
  __hip_bfloat16* o = part + cbase + (size_t)(m0 + mr) * 512 + n0 + h * 64;
#pragma unroll
  for (int c = 0; c < 8; c++)
    *(uint4*)(o + c * 8) = *(const uint4*)(rowp + c * 8);
}

// ---- reduce 2 partials, fold 32 psums -> rowsum, normalize -> obuf ----
__global__ __launch_bounds__(256) void reduce_k(
    const __hip_bfloat16* __restrict__ part, const float* __restrict__ psums,
    __hip_bfloat16* __restrict__ obuf) {
  size_t i8 = (size_t)blockIdx.x * 256 + threadIdx.x;
  size_t perb = (size_t)4096 * 512 / 8;  // 262144 vectors per batch
  size_t b = i8 / perb, r = i8 - b * perb;
  int t = (int)(r >> 6);                 // token row (64 vectors per row)
  int lane = threadIdx.x & 63;
  // all 64 lanes of a warp share t; lanes load the 32 per-n-tile partial sums
  float ps = psums[(size_t)(lane & 31) * 8192 + b * 4096 + t];
#pragma unroll
  for (int off = 1; off < 32; off <<= 1) ps += __shfl_xor(ps, off);
  float inv = 1.f / ps;
  float acc[8] = {};
#pragma unroll
  for (int ks = 0; ks < 2; ks++) {
    bf16x8 v = ((const bf16x8*)part)[(b * 2 + ks) * perb + r];
#pragma unroll
    for (int l = 0; l < 8; l++) acc[l] += (float)v[l];
  }
  bf16x8 o;
#pragma unroll
  for (int l = 0; l < 8; l++) o[l] = (__bf16)(acc[l] * inv);
  ((bf16x8*)obuf)[b * perb + r] = o;
}

extern "C" void kernel_launch(void* const* d_in, const int* in_sizes, int n_in,
                              void* d_out, int out_size, void* d_ws,
                              size_t ws_size, hipStream_t stream) {
  const float* xp  = (const float*)d_in[0];
  const float* gwp = (const float*)d_in[1];
  const float* gbp = (const float*)d_in[2];
  const float* wqp = (const float*)d_in[3];
  const float* bqp = (const float*)d_in[4];
  const float* wkp = (const float*)d_in[5];
  const float* bkp = (const float*)d_in[6];
  const float* wvp = (const float*)d_in[7];
  const float* bvp = (const float*)d_in[8];
  const float* wop = (const float*)d_in[9];
  const float* bop = (const float*)d_in[10];
  float* outp = (float*)d_out;

  char* w = (char*)d_ws;
  size_t off = 0;
  auto alloc = [&](size_t bytes) {
    void* p = w + off;
    off += (bytes + 255) & ~(size_t)255;
    return p;
  };
  float* stats         = (float*)alloc(64 * 2 * sizeof(float));
  __hip_bfloat16* hf   = (__hip_bfloat16*)alloc((size_t)2 * 4096 * 512 * 2);
  __hip_bfloat16* wqkb = (__hip_bfloat16*)alloc((size_t)1024 * 512 * 2);
  __hip_bfloat16* wvb  = (__hip_bfloat16*)alloc((size_t)512 * 512 * 2);
  __hip_bfloat16* wob  = (__hip_bfloat16*)alloc((size_t)512 * 512 * 2);
  float* bqk           = (float*)alloc(1024 * sizeof(float));
  float* psums         = (float*)alloc((size_t)32 * 8192 * sizeof(float));
  __hip_bfloat16* qk   = (__hip_bfloat16*)alloc((size_t)2 * 4096 * 1024 * 2);
  __hip_bfloat16* vT   = (__hip_bfloat16*)alloc((size_t)2 * 512 * 4096 * 2);
  __hip_bfloat16* obuf = (__hip_bfloat16*)alloc((size_t)2 * 4096 * 512 * 2);
  __hip_bfloat16* part = (__hip_bfloat16*)alloc((size_t)4 * 4096 * 512 * 2);
  __hip_bfloat16* Sbuf = (__hip_bfloat16*)alloc((size_t)2 * 4096 * 4096 * 2);

  // prelude: 4096 cvt blocks + 64 gn_stats blocks + 1 bcat block
  prelude_k<<<4161, 256, 0, stream>>>(wqp, wkp, wvp, wop, wqkb, wvb, wob,
                                      bqp, bkp, bqk, xp, stats);

  gn_apply_k<<<dim3(8, 64, 2), 256, 0, stream>>>(xp, stats, gwp, gbp, hf);

  // fused QKV: qk[8192][1024] and vT[2][512][4096]
  qkv_k<<<dim3(12, 64, 1), 256, 0, stream>>>(hf, wqkb, wvb, bqk, bvp, qk, vT);

  // expS = exp(Q K^T * scale), both batches (bf16) + per-n-tile row sums
  gemm_bt_k<2><<<dim3(32, 32, 2), 256, 0, stream>>>(
      qk, qk + 512, Sbuf, nullptr, nullptr, psums, 512, 1024, 1024, 4096,
      0.044194173824159216f, (long)4096 * 1024, (long)4096 * 1024,
      (long)4096 * 4096, 1);

  // PV split-K (kspl=2, BK=64, XCD-swizzled): raw partials [4][4096][512]
  pv_k<<<512, 256, 0, stream>>>(Sbuf, vT, part);

  // sum partials + fold psums + normalize -> obuf
  reduce_k<<<2048, 256, 0, stream>>>(part, psums, obuf);

  // out[b][c][t] = x + Wo*O + bo
  gemm_bt_k<6><<<dim3(32, 4, 2), 256, 0, stream>>>(
      wob, obuf, outp, bop, xp, nullptr, 512, 512, 512, 4096, 1.f,
      0, (long)4096 * 512, (long)512 * 4096, 1);
}

// Round 12
// 251.599 us; speedup vs baseline: 1.4112x; 1.0042x over previous
//
#include <hip/hip_runtime.h>
#include <hip/hip_bf16.h>

// Problem constants: B=2, C=512, H=W=64 -> N=4096, G=32 (16 ch/group), EPS=1e-6.

typedef float f32x4 __attribute__((ext_vector_type(4)));
typedef __bf16 bf16x8 __attribute__((ext_vector_type(8)));

typedef const __attribute__((address_space(1))) unsigned char* gas_p;
typedef __attribute__((address_space(3))) unsigned char* las_p;

__device__ __forceinline__ void gload_lds16(const void* g, void* l) {
  // async DMA: each lane contributes 16B; LDS dst = wave-uniform base + lane*16
  __builtin_amdgcn_global_load_lds((gas_p)g, (las_p)l, 16, 0, 0);
}

// ====== prelude: weight cvt (4x1024 blocks) | gn_stats (64) | bcat (1) ======
__global__ __launch_bounds__(256) void prelude_k(
    const float* __restrict__ wq, const float* __restrict__ wk,
    const float* __restrict__ wv, const float* __restrict__ wo,
    __hip_bfloat16* __restrict__ wqkb, __hip_bfloat16* __restrict__ wvb,
    __hip_bfloat16* __restrict__ wob, const float* __restrict__ bq,
    const float* __restrict__ bk, float* __restrict__ bqk,
    const float* __restrict__ x, float* __restrict__ stats) {
  int bid = blockIdx.x;
  if (bid < 4096) {
    const float* src;
    __hip_bfloat16* dst;
    if (bid < 1024)      { src = wq; dst = wqkb; }
    else if (bid < 2048) { src = wk; dst = wqkb + 262144; }
    else if (bid < 3072) { src = wv; dst = wvb; }
    else                 { src = wo; dst = wob; }
    int i = (bid & 1023) * 256 + threadIdx.x;  // 1024*256 = 262144 = 512*512
    dst[i] = __float2bfloat16(src[i]);
    return;
  }
  if (bid < 4160) {  // gn_stats: one block per (b,g)
    int bg = bid - 4096;
    const float4* p = (const float4*)(x + (size_t)bg * 65536);
    float s = 0.f, s2 = 0.f;
    for (int i = threadIdx.x; i < 16384; i += 256) {
      float4 v = p[i];
      s  += v.x + v.y + v.z + v.w;
      s2 += v.x * v.x + v.y * v.y + v.z * v.z + v.w * v.w;
    }
#pragma unroll
    for (int off = 32; off > 0; off >>= 1) {
      s  += __shfl_xor(s, off);
      s2 += __shfl_xor(s2, off);
    }
    __shared__ float rs[4], rs2[4];
    int wid = threadIdx.x >> 6, lane = threadIdx.x & 63;
    if (lane == 0) { rs[wid] = s; rs2[wid] = s2; }
    __syncthreads();
    if (threadIdx.x == 0) {
      float S  = rs[0] + rs[1] + rs[2] + rs[3];
      float S2 = rs2[0] + rs2[1] + rs2[2] + rs2[3];
      float mean = S * (1.f / 65536.f);
      float var  = S2 * (1.f / 65536.f) - mean * mean;
      stats[bg * 2]     = mean;
      stats[bg * 2 + 1] = rsqrtf(var + 1e-6f);
    }
    return;
  }
  // bcat
  for (int j = threadIdx.x; j < 1024; j += 256)
    bqk[j] = (j < 512) ? bq[j] : bk[j - 512];
}

// ------- GroupNorm apply + transpose, vectorized: x fp32 -> hf bf16 [b][n][c]
__global__ __launch_bounds__(256) void gn_apply_k(const float* __restrict__ x,
                                                  const float* __restrict__ stats,
                                                  const float* __restrict__ gw,
                                                  const float* __restrict__ gb,
                                                  __hip_bfloat16* __restrict__ hf) {
  int c0 = blockIdx.x * 64, n0 = blockIdx.y * 64, b = blockIdx.z;
  __shared__ float tile[64][65];
  int tid = threadIdx.x;
  int cl = tid >> 2, q = tid & 3;
  int c = c0 + cl;
  float mean = stats[(b * 32 + (c >> 4)) * 2];
  float rstd = stats[(b * 32 + (c >> 4)) * 2 + 1];
  float sc = rstd * gw[c];
  float sh = gb[c] - mean * sc;
  const float* xr = x + ((size_t)(b * 512 + c0 + cl)) * 4096 + n0 + q * 16;
#pragma unroll
  for (int j = 0; j < 4; j++) {
    float4 v = *(const float4*)(xr + 4 * j);
    int n = q * 16 + 4 * j;
    tile[cl][n]     = v.x * sc + sh;
    tile[cl][n + 1] = v.y * sc + sh;
    tile[cl][n + 2] = v.z * sc + sh;
    tile[cl][n + 3] = v.w * sc + sh;
  }
  __syncthreads();
  int nl = tid >> 2, ch = q * 16;
  bf16x8 o0, o1;
#pragma unroll
  for (int l = 0; l < 8; l++) {
    o0[l] = (__bf16)tile[ch + l][nl];
    o1[l] = (__bf16)tile[ch + 8 + l][nl];
  }
  __hip_bfloat16* op = hf + ((size_t)(b * 4096 + n0 + nl)) * 512 + c0 + ch;
  *(uint4*)op = *(uint4*)&o0;
  *(uint4*)(op + 8) = *(uint4*)&o1;
}

// ============ fused QKV (double-buffered DMA + LDS epilogue) ============
// bx<8 : QK GEMM  qk[t][o] (o<1024) = sum_c hf[t][c]*Wqk[o][c] + bqk[o]
// bx>=8: V GEMM   vT[b][o][t]       = sum_c Wv[o][c]*hf[t][c] + bv[o]
__global__ __launch_bounds__(256, 4) void qkv_k(
    const __hip_bfloat16* __restrict__ hf, const __hip_bfloat16* __restrict__ wqk,
    const __hip_bfloat16* __restrict__ wv, const float* __restrict__ bqk,
    const float* __restrict__ bv, __hip_bfloat16* __restrict__ qk,
    __hip_bfloat16* __restrict__ vT) {
  bool isV = blockIdx.x >= 8;
  int m0 = isV ? (blockIdx.x - 8) * 128 : blockIdx.y * 128;
  int n0 = isV ? blockIdx.y * 128 : blockIdx.x * 128;
  const __hip_bfloat16* A  = isV ? wv : hf;   // [m][512]
  const __hip_bfloat16* Bm = isV ? hf : wqk;  // [n][512]

  __shared__ __align__(16) unsigned char smem[34816];  // dbuf(32K) | epi(34K)
  __hip_bfloat16* As  = (__hip_bfloat16*)smem;
  __hip_bfloat16* Bs  = As + 8192;
  __hip_bfloat16* epi = (__hip_bfloat16*)smem;         // [128][136]

  int tid  = threadIdx.x;
  int wvx  = tid >> 6, lane = tid & 63;
  int wr   = (wvx >> 1) * 64, wc = (wvx & 1) * 64;
  int quad = lane >> 4, l16 = lane & 15;

  int srow = wvx * 32 + (lane >> 2);
  int scol = (lane & 3) * 8;
  const __hip_bfloat16* gA0 = A  + (size_t)(m0 + srow) * 512 + scol;
  const __hip_bfloat16* gA1 = gA0 + (size_t)16 * 512;
  const __hip_bfloat16* gB0 = Bm + (size_t)(n0 + srow) * 512 + scol;
  const __hip_bfloat16* gB1 = gB0 + (size_t)16 * 512;

  auto stage = [&](int kk, int bsel) {
    int lb = bsel * 4096 + wvx * 1024;
    gload_lds16(gA0 + kk, &As[lb]);
    gload_lds16(gA1 + kk, &As[lb + 512]);
    gload_lds16(gB0 + kk, &Bs[lb]);
    gload_lds16(gB1 + kk, &Bs[lb + 512]);
  };

  f32x4 acc[4][4] = {};
  stage(0, 0);
  for (int kt = 0; kt < 16; kt++) {
    __syncthreads();
    if (kt + 1 < 16) stage((kt + 1) << 5, (kt + 1) & 1);
    const __hip_bfloat16* Ab = &As[(kt & 1) * 4096];
    const __hip_bfloat16* Bb = &Bs[(kt & 1) * 4096];
    bf16x8 af[4], bfr[4];
#pragma unroll
    for (int i = 0; i < 4; i++)
      af[i] = *(const bf16x8*)&Ab[(wr + i * 16 + l16) * 32 + quad * 8];
#pragma unroll
    for (int j = 0; j < 4; j++)
      bfr[j] = *(const bf16x8*)&Bb[(wc + j * 16 + l16) * 32 + quad * 8];
#pragma unroll
    for (int i = 0; i < 4; i++)
#pragma unroll
      for (int j = 0; j < 4; j++)
        acc[i][j] = __builtin_amdgcn_mfma_f32_16x16x32_bf16(af[i], bfr[j],
                                                            acc[i][j], 0, 0, 0);
  }

  // ---- epilogue via LDS: C-layout -> row-major coalesced ----
  float bj[4], bm[4][4];
  if (!isV) {
#pragma unroll
    for (int j = 0; j < 4; j++) bj[j] = bqk[n0 + wc + j * 16 + l16];
  } else {
#pragma unroll
    for (int i = 0; i < 4; i++)
#pragma unroll
      for (int r = 0; r < 4; r++)
        bm[i][r] = bv[m0 + wr + i * 16 + quad * 4 + r];
  }
  __syncthreads();  // dbuf fragment reads done before epi overwrite
#pragma unroll
  for (int i = 0; i < 4; i++)
#pragma unroll
    for (int j = 0; j < 4; j++)
#pragma unroll
      for (int r = 0; r < 4; r++) {
        int ml = wr + i * 16 + quad * 4 + r;
        int nl = wc + j * 16 + l16;
        float v = acc[i][j][r] + (isV ? bm[i][r] : bj[j]);
        epi[ml * 136 + nl] = __float2bfloat16(v);
      }
  __syncthreads();
  int mr = tid >> 1, h = tid & 1;
  const __hip_bfloat16* rowp = &epi[mr * 136 + h * 64];
  if (!isV) {
    __hip_bfloat16* o = qk + (size_t)(m0 + mr) * 1024 + n0 + h * 64;
#pragma unroll
    for (int c = 0; c < 8; c++)
      *(uint4*)(o + c * 8) = *(const uint4*)(rowp + c * 8);
  } else {
    int b = (n0 + h * 64) >> 12, t = (n0 + h * 64) & 4095;
    __hip_bfloat16* o = vT + ((size_t)(b * 512 + m0 + mr)) * 4096 + t;
#pragma unroll
    for (int c = 0; c < 8; c++)
      *(uint4*)(o + c * 8) = *(const uint4*)(rowp + c * 8);
  }
}

// ------------- QK^T GEMM: expS + atomic-free row sums (round-9 path) -------
__global__ __launch_bounds__(256, 4) void qkexp_k(
    const __hip_bfloat16* __restrict__ A, const __hip_bfloat16* __restrict__ Bm,
    __hip_bfloat16* __restrict__ Cout, float* __restrict__ psums) {
  int bx = blockIdx.x, by = blockIdx.y, bb = blockIdx.z;
  const float scale = 0.044194173824159216f;
  A  += (size_t)bb * 4096 * 1024;
  Bm += (size_t)bb * 4096 * 1024 + 512;
  size_t cbase = (size_t)bb * 4096 * 4096;
  int m0 = by * 128, n0 = bx * 128;

  __shared__ __align__(16) unsigned char smem[33792];  // dbuf(32K) | psum2(1K)
  __hip_bfloat16* As  = (__hip_bfloat16*)smem;
  __hip_bfloat16* Bs  = As + 8192;
  float* psum2 = (float*)(smem + 32768);               // [2][128]

  int tid  = threadIdx.x;
  int wv   = tid >> 6, lane = tid & 63;
  int wr   = (wv >> 1) * 64, wc = (wv & 1) * 64;
  int quad = lane >> 4, l16 = lane & 15;

  int srow = wv * 32 + (lane >> 2);
  int scol = (lane & 3) * 8;
  const __hip_bfloat16* gA0 = A  + (size_t)(m0 + srow) * 1024 + scol;
  const __hip_bfloat16* gA1 = gA0 + (size_t)16 * 1024;
  const __hip_bfloat16* gB0 = Bm + (size_t)(n0 + srow) * 1024 + scol;
  const __hip_bfloat16* gB1 = gB0 + (size_t)16 * 1024;

  auto stage = [&](int kk, int bsel) {
    int lb = bsel * 4096 + wv * 1024;
    gload_lds16(gA0 + kk, &As[lb]);
    gload_lds16(gA1 + kk, &As[lb + 512]);
    gload_lds16(gB0 + kk, &Bs[lb]);
    gload_lds16(gB1 + kk, &Bs[lb + 512]);
  };

  f32x4 acc[4][4] = {};
  stage(0, 0);
  for (int kt = 0; kt < 16; kt++) {
    __syncthreads();
    if (kt + 1 < 16) stage((kt + 1) << 5, (kt + 1) & 1);
    const __hip_bfloat16* Ab = &As[(kt & 1) * 4096];
    const __hip_bfloat16* Bb = &Bs[(kt & 1) * 4096];
    bf16x8 af[4], bfr[4];
#pragma unroll
    for (int i = 0; i < 4; i++)
      af[i] = *(const bf16x8*)&Ab[(wr + i * 16 + l16) * 32 + quad * 8];
#pragma unroll
    for (int j = 0; j < 4; j++)
      bfr[j] = *(const bf16x8*)&Bb[(wc + j * 16 + l16) * 32 + quad * 8];
#pragma unroll
    for (int i = 0; i < 4; i++)
#pragma unroll
      for (int j = 0; j < 4; j++)
        acc[i][j] = __builtin_amdgcn_mfma_f32_16x16x32_bf16(af[i], bfr[j],
                                                            acc[i][j], 0, 0, 0);
  }

  // direct scattered stores + register row-sum reduction (measured 57-59 us;
  // LDS-staged variant measured 65.6 us -> keep direct)
  float s[4][4];
#pragma unroll
  for (int i = 0; i < 4; i++)
#pragma unroll
    for (int r = 0; r < 4; r++) s[i][r] = 0.f;
#pragma unroll
  for (int i = 0; i < 4; i++)
#pragma unroll
    for (int j = 0; j < 4; j++)
#pragma unroll
      for (int r = 0; r < 4; r++) {
        int m = m0 + wr + i * 16 + quad * 4 + r;
        int n = n0 + wc + j * 16 + l16;
        float v = __expf(acc[i][j][r] * scale);
        Cout[cbase + (size_t)m * 4096 + n] = __float2bfloat16(v);
        s[i][r] += v;
      }
#pragma unroll
  for (int off = 1; off < 16; off <<= 1)
#pragma unroll
    for (int i = 0; i < 4; i++)
#pragma unroll
      for (int r = 0; r < 4; r++) s[i][r] += __shfl_xor(s[i][r], off);
  if (l16 == 0) {
#pragma unroll
    for (int i = 0; i < 4; i++)
#pragma unroll
      for (int r = 0; r < 4; r++)
        psum2[(wv & 1) * 128 + wr + i * 16 + quad * 4 + r] = s[i][r];
  }
  __syncthreads();
  if (tid < 128)
    psums[(size_t)bx * 8192 + bb * 4096 + m0 + tid] =
        psum2[tid] + psum2[128 + tid];
}

// ============ PV split-K: BK=64 staging, XOR-swizzled LDS ============
// part[bz][m][c] = sum_{k in ks half} expS[bb][m][k] * vT[bb][c][k]
__global__ __launch_bounds__(256, 2) void pv_k(
    const __hip_bfloat16* __restrict__ P, const __hip_bfloat16* __restrict__ vT,
    __hip_bfloat16* __restrict__ part) {
  // 512 blocks; co-locate the 4 c-tiles of each (m,bz) group on one XCD
  int f = blockIdx.x;
  int xcd = f & 7, s = f >> 3;
  int bx = s & 3;
  int g = xcd + 8 * (s >> 2);     // 0..127
  int by = g & 31, bz = g >> 5;   // bz = bb*2+ks
  int bb = bz >> 1, ks = bz & 1;
  const __hip_bfloat16* A = P  + (size_t)bb * 4096 * 4096 + (size_t)ks * 2048;
  const __hip_bfloat16* B = vT + (size_t)bb * 512 * 4096 + (size_t)ks * 2048;
  size_t cbase = (size_t)bz * 4096 * 512;
  int m0 = by * 128, n0 = bx * 128;

  __shared__ __align__(16) unsigned char smem[65536];  // dbuf 64K; epi overlaps
  __hip_bfloat16* As  = (__hip_bfloat16*)smem;          // 2 x [128][64]
  __hip_bfloat16* Bs  = (__hip_bfloat16*)(smem + 32768);
  __hip_bfloat16* epi = (__hip_bfloat16*)smem;          // [128][136]

  int tid = threadIdx.x, wv = tid >> 6, lane = tid & 63;
  int wr = (wv >> 1) * 64, wc = (wv & 1) * 64;
  int quad = lane >> 4, l16 = lane & 15;

  // DMA: inst covers 8 rows x 128B; lane l -> row l>>3, swizzled chunk
  // (l&7)^(l>>3). LDS[r][x] = G[r][x ^ (r&7)] so b128 frag reads are 2-way.
  int srow = wv * 32 + (lane >> 3);
  int scol = ((lane & 7) ^ (lane >> 3)) * 8;
  const __hip_bfloat16* gA = A + (size_t)(m0 + srow) * 4096 + scol;
  const __hip_bfloat16* gB = B + (size_t)(n0 + srow) * 4096 + scol;

  auto stage = [&](int kk, int bsel) {
    __hip_bfloat16* la = &As[bsel * 8192 + wv * 2048];
    __hip_bfloat16* lb = &Bs[bsel * 8192 + wv * 2048];
#pragma unroll
    for (int c = 0; c < 4; c++) {
      gload_lds16(gA + kk + (size_t)(c * 8) * 4096, la + c * 512);
      gload_lds16(gB + kk + (size_t)(c * 8) * 4096, lb + c * 512);
    }
  };

  f32x4 acc[4][4] = {};
  stage(0, 0);
  for (int kt = 0; kt < 32; kt++) {
    __syncthreads();
    if (kt + 1 < 32) stage((kt + 1) << 6, (kt + 1) & 1);
    const __hip_bfloat16* Ab = &As[(kt & 1) * 8192];
    const __hip_bfloat16* Bb = &Bs[(kt & 1) * 8192];
#pragma unroll
    for (int ksub = 0; ksub < 2; ksub++) {
      bf16x8 af[4], bfr[4];
#pragma unroll
      for (int i = 0; i < 4; i++) {
        int r = wr + i * 16 + l16;
        af[i] = *(const bf16x8*)&Ab[r * 64 + ((ksub * 4 + quad) ^ (r & 7)) * 8];
      }
#pragma unroll
      for (int j = 0; j < 4; j++) {
        int r = wc + j * 16 + l16;
        bfr[j] = *(const bf16x8*)&Bb[r * 64 + ((ksub * 4 + quad) ^ (r & 7)) * 8];
      }
#pragma unroll
      for (int i = 0; i < 4; i++)
#pragma unroll
        for (int j = 0; j < 4; j++)
          acc[i][j] = __builtin_amdgcn_mfma_f32_16x16x32_bf16(af[i], bfr[j],
                                                              acc[i][j], 0, 0, 0);
    }
  }

  __syncthreads();
#pragma unroll
  for (int i = 0; i < 4; i++)
#pragma unroll
    for (int j = 0; j < 4; j++)
#pragma unroll
      for (int r = 0; r < 4; r++)
        epi[(wr + i * 16 + quad * 4 + r) * 136 + wc + j * 16 + l16] =
            __float2bfloat16(acc[i][j][r]);
  __syncthreads();
  int mr = tid >> 1, h = tid & 1;
  const __hip_bfloat16* rowp = &epi[mr * 136 + h * 64];
  __hip_bfloat16* o = part + cbase + (size_t)(m0 + mr) * 512 + n0 + h * 64;
#pragma unroll
  for (int c = 0; c < 8; c++)
    *(uint4*)(o + c * 8) = *(const uint4*)(rowp + c * 8);
}

// ---- reduce 2 partials, fold 32 psums -> rowsum, normalize -> obuf ----
__global__ __launch_bounds__(256) void reduce_k(
    const __hip_bfloat16* __restrict__ part, const float* __restrict__ psums,
    __hip_bfloat16* __restrict__ obuf) {
  size_t i8 = (size_t)blockIdx.x * 256 + threadIdx.x;
  size_t perb = (size_t)4096 * 512 / 8;  // 262144 vectors per batch
  size_t b = i8 / perb, r = i8 - b * perb;
  int t = (int)(r >> 6);                 // token row (64 vectors per row)
  int lane = threadIdx.x & 63;
  float ps = psums[(size_t)(lane & 31) * 8192 + b * 4096 + t];
#pragma unroll
  for (int off = 1; off < 32; off <<= 1) ps += __shfl_xor(ps, off);
  float inv = 1.f / ps;
  float acc[8] = {};
#pragma unroll
  for (int ks = 0; ks < 2; ks++) {
    bf16x8 v = ((const bf16x8*)part)[(b * 2 + ks) * perb + r];
#pragma unroll
    for (int l = 0; l < 8; l++) acc[l] += (float)v[l];
  }
  bf16x8 o;
#pragma unroll
  for (int l = 0; l < 8; l++) o[l] = (__bf16)(acc[l] * inv);
  ((bf16x8*)obuf)[b * perb + r] = o;
}

// ====== out-proj, 64x128 tiles (512 blocks = 2/CU vs old 256 = 1/CU) ======
// out[b][c][t] = x[b][c][t] + bf16(sum_o Wo[c][o]*obuf[b][t][o] + bo[c])
__global__ __launch_bounds__(256, 2) void oproj_k(
    const __hip_bfloat16* __restrict__ Wo, const __hip_bfloat16* __restrict__ O,
    float* __restrict__ out, const float* __restrict__ bias,
    const float* __restrict__ resid) {
  int m0 = blockIdx.y * 64, n0 = blockIdx.x * 128, bb = blockIdx.z;
  O += (size_t)bb * 4096 * 512;
  size_t cbase = (size_t)bb * 512 * 4096;

  __shared__ __align__(16) unsigned char smem[24576];  // A 2x4K | B 2x8K; epi
  __hip_bfloat16* As  = (__hip_bfloat16*)smem;          // 2 x [64][32]
  __hip_bfloat16* Bs  = As + 4096;                      // 2 x [128][32]
  __hip_bfloat16* epi = (__hip_bfloat16*)smem;          // [64][136] = 17.4K

  int tid = threadIdx.x, wv = tid >> 6, lane = tid & 63;
  int wr = (wv >> 1) * 32, wc = (wv & 1) * 64;
  int quad = lane >> 4, l16 = lane & 15;

  int lr = lane >> 2, scol = (lane & 3) * 8;
  const __hip_bfloat16* gA  = Wo + (size_t)(m0 + wv * 16 + lr) * 512 + scol;
  const __hip_bfloat16* gB0 = O  + (size_t)(n0 + wv * 32 + lr) * 512 + scol;
  const __hip_bfloat16* gB1 = gB0 + (size_t)16 * 512;

  auto stage = [&](int kk, int bsel) {
    gload_lds16(gA + kk, &As[bsel * 2048 + wv * 512]);
    gload_lds16(gB0 + kk, &Bs[bsel * 4096 + wv * 1024]);
    gload_lds16(gB1 + kk, &Bs[bsel * 4096 + wv * 1024 + 512]);
  };

  f32x4 acc[2][4] = {};
  stage(0, 0);
  for (int kt = 0; kt < 16; kt++) {
    __syncthreads();
    if (kt + 1 < 16) stage((kt + 1) << 5, (kt + 1) & 1);
    const __hip_bfloat16* Ab = &As[(kt & 1) * 2048];
    const __hip_bfloat16* Bb = &Bs[(kt & 1) * 4096];
    bf16x8 af[2], bfr[4];
#pragma unroll
    for (int i = 0; i < 2; i++)
      af[i] = *(const bf16x8*)&Ab[(wr + i * 16 + l16) * 32 + quad * 8];
#pragma unroll
    for (int j = 0; j < 4; j++)
      bfr[j] = *(const bf16x8*)&Bb[(wc + j * 16 + l16) * 32 + quad * 8];
#pragma unroll
    for (int i = 0; i < 2; i++)
#pragma unroll
      for (int j = 0; j < 4; j++)
        acc[i][j] = __builtin_amdgcn_mfma_f32_16x16x32_bf16(af[i], bfr[j],
                                                            acc[i][j], 0, 0, 0);
  }

  float pre[2][4];
#pragma unroll
  for (int i = 0; i < 2; i++)
#pragma unroll
    for (int r = 0; r < 4; r++)
      pre[i][r] = bias[m0 + wr + i * 16 + quad * 4 + r];
  __syncthreads();
#pragma unroll
  for (int i = 0; i < 2; i++)
#pragma unroll
    for (int j = 0; j < 4; j++)
#pragma unroll
      for (int r = 0; r < 4; r++)
        epi[(wr + i * 16 + quad * 4 + r) * 136 + wc + j * 16 + l16] =
            __float2bfloat16(acc[i][j][r] + pre[i][r]);
  __syncthreads();
  int mr = tid >> 2, seg = tid & 3;  // 4 threads/row, 32 elems each
  const __hip_bfloat16* rowp = &epi[mr * 136 + seg * 32];
  size_t obase = cbase + (size_t)(m0 + mr) * 4096 + n0 + seg * 32;
#pragma unroll
  for (int c = 0; c < 4; c++) {
    bf16x8 val = *(const bf16x8*)(rowp + c * 8);
    size_t idx = obase + c * 8;
    float4 r0 = *(const float4*)&resid[idx];
    float4 r1 = *(const float4*)&resid[idx + 4];
    float4 o0, o1;
    o0.x = r0.x + (float)val[0]; o0.y = r0.y + (float)val[1];
    o0.z = r0.z + (float)val[2]; o0.w = r0.w + (float)val[3];
    o1.x = r1.x + (float)val[4]; o1.y = r1.y + (float)val[5];
    o1.z = r1.z + (float)val[6]; o1.w = r1.w + (float)val[7];
    *(float4*)&out[idx] = o0;
    *(float4*)&out[idx + 4] = o1;
  }
}

extern "C" void kernel_launch(void* const* d_in, const int* in_sizes, int n_in,
                              void* d_out, int out_size, void* d_ws,
                              size_t ws_size, hipStream_t stream) {
  const float* xp  = (const float*)d_in[0];
  const float* gwp = (const float*)d_in[1];
  const float* gbp = (const float*)d_in[2];
  const float* wqp = (const float*)d_in[3];
  const float* bqp = (const float*)d_in[4];
  const float* wkp = (const float*)d_in[5];
  const float* bkp = (const float*)d_in[6];
  const float* wvp = (const float*)d_in[7];
  const float* bvp = (const float*)d_in[8];
  const float* wop = (const float*)d_in[9];
  const float* bop = (const float*)d_in[10];
  float* outp = (float*)d_out;

  char* w = (char*)d_ws;
  size_t off = 0;
  auto alloc = [&](size_t bytes) {
    void* p = w + off;
    off += (bytes + 255) & ~(size_t)255;
    return p;
  };
  float* stats         = (float*)alloc(64 * 2 * sizeof(float));
  __hip_bfloat16* hf   = (__hip_bfloat16*)alloc((size_t)2 * 4096 * 512 * 2);
  __hip_bfloat16* wqkb = (__hip_bfloat16*)alloc((size_t)1024 * 512 * 2);
  __hip_bfloat16* wvb  = (__hip_bfloat16*)alloc((size_t)512 * 512 * 2);
  __hip_bfloat16* wob  = (__hip_bfloat16*)alloc((size_t)512 * 512 * 2);
  float* bqk           = (float*)alloc(1024 * sizeof(float));
  float* psums         = (float*)alloc((size_t)32 * 8192 * sizeof(float));
  __hip_bfloat16* qk   = (__hip_bfloat16*)alloc((size_t)2 * 4096 * 1024 * 2);
  __hip_bfloat16* vT   = (__hip_bfloat16*)alloc((size_t)2 * 512 * 4096 * 2);
  __hip_bfloat16* obuf = (__hip_bfloat16*)alloc((size_t)2 * 4096 * 512 * 2);
  __hip_bfloat16* part = (__hip_bfloat16*)alloc((size_t)4 * 4096 * 512 * 2);
  __hip_bfloat16* Sbuf = (__hip_bfloat16*)alloc((size_t)2 * 4096 * 4096 * 2);

  // prelude: 4096 cvt blocks + 64 gn_stats blocks + 1 bcat block
  prelude_k<<<4161, 256, 0, stream>>>(wqp, wkp, wvp, wop, wqkb, wvb, wob,
                                      bqp, bkp, bqk, xp, stats);

  gn_apply_k<<<dim3(8, 64, 2), 256, 0, stream>>>(xp, stats, gwp, gbp, hf);

  // fused QKV: qk[8192][1024] and vT[2][512][4096]
  qkv_k<<<dim3(12, 64, 1), 256, 0, stream>>>(hf, wqkb, wvb, bqk, bvp, qk, vT);

  // expS = exp(Q K^T * scale), both batches (bf16) + per-n-tile row sums
  qkexp_k<<<dim3(32, 32, 2), 256, 0, stream>>>(qk, qk, Sbuf, psums);

  // PV split-K (kspl=2, BK=64, XCD-swizzled): raw partials [4][4096][512]
  pv_k<<<512, 256, 0, stream>>>(Sbuf, vT, part);

  // sum partials + fold psums + normalize -> obuf
  reduce_k<<<2048, 256, 0, stream>>>(part, psums, obuf);

  // out[b][c][t] = x + Wo*O + bo  (64x128 tiles, 512 blocks)
  oproj_k<<<dim3(32, 8, 2), 256, 0, stream>>>(wob, obuf, outp, bop, xp);
}